// Round 5
// baseline (6623.418 us; speedup 1.0000x reference)
//
#include <hip/hip_runtime.h>
#include <hip/hip_bf16.h>
#include <math.h>

#define TAU 6.283185307179586f
#define NK 576                    // matrix dimension (K always exact: 18*32)
#define NPAD 640                  // padded row count for 128-row tiles
#define PLN ((size_t)NPAD * NK)   // elems per padded plane = 368640
#define SETSTR ((size_t)4 * PLN)  // elems per 4-plane split set
#define MAPSZ 102400              // 16*16*20*20
#define KOUT 416                  // padded K for output gemm (13*32)
#define XPL ((size_t)8192 * KOUT)
#define MPL ((size_t)4096 * KOUT)

typedef __attribute__((ext_vector_type(8))) short short8;
typedef __attribute__((ext_vector_type(4))) float f32x4;

__device__ inline void bsplit(float v, __hip_bfloat16& h, __hip_bfloat16& l) {
  h = __float2bfloat16(v);
  l = __float2bfloat16(v - __bfloat162float(h));
}
__device__ inline short braw(__hip_bfloat16 b) { return *reinterpret_cast<short*>(&b); }

__device__ inline void gld16(const void* g, const void* l) {
  __builtin_amdgcn_global_load_lds((const __attribute__((address_space(1))) unsigned*)g,
                                   (__attribute__((address_space(3))) unsigned*)l, 16, 0, 0);
}

#define MFMA16(a, b, c) __builtin_amdgcn_mfma_f32_16x16x32_bf16(a, b, c, 0, 0, 0)

// ---------------- Stage 1: signal -> spectrum ----------------
__device__ inline void dft24(const float2* in, float2* out, int t, float sgn, bool firstAxis) {
  int r = t / 24, c = t % 24;
  int kk = firstAxis ? r : c;
  float2 acc = make_float2(0.f, 0.f);
  for (int n = 0; n < 24; ++n) {
    float ang = sgn * (TAU / 24.f) * (float)((kk * n) % 24);
    float s, co;
    sincosf(ang, &s, &co);
    float2 v = firstAxis ? in[n * 24 + c] : in[r * 24 + n];
    acc.x += v.x * co - v.y * s;
    acc.y += v.x * s + v.y * co;
  }
  out[t] = acc;
}

__global__ void spectrum_kernel(const float* __restrict__ sig, float2* __restrict__ spec) {
  __shared__ float2 b0[576];
  __shared__ float2 b1[576];
  int f = blockIdx.x;
  int t = threadIdx.x;
  int r = t / 24, c = t % 24;
  b0[t] = make_float2(sig[f * 576 + t], 0.f);
  __syncthreads();
  dft24(b0, b1, t, -1.f, false); __syncthreads();
  dft24(b1, b0, t, -1.f, true);  __syncthreads();
  {
    int p2 = (r + 12) % 24 - 11;
    int q2 = (c + 12) % 24 - 11;
    float rr = (float)(1 + p2 * p2 + q2 * q2) * 5.f;
    float2 v = b0[t];
    b0[t] = make_float2(v.x / rr, v.y / rr);
  }
  __syncthreads();
  dft24(b0, b1, t, +1.f, false); __syncthreads();
  dft24(b1, b0, t, +1.f, true);  __syncthreads();
  {
    float winr = 0.5f * (1.f - cosf(TAU * (float)r / 24.f));
    float winc = 0.5f * (1.f - cosf(TAU * (float)c / 24.f));
    float w = winr * winc * (1.f / 576.f);
    float2 v = b0[t];
    b0[t] = make_float2(v.x * w, v.y * w);
  }
  __syncthreads();
  dft24(b0, b1, t, -1.f, false); __syncthreads();
  dft24(b1, b0, t, -1.f, true);  __syncthreads();
  int p = (r + 12) % 24, q = (c + 12) % 24;
  spec[f * 576 + p * 24 + q] = b0[t];
}

// ---------------- Stage 2: build split B and X0 = I + B/5 ----------------
__global__ void buildBX(const float2* __restrict__ spec, __hip_bfloat16* __restrict__ B,
                        __hip_bfloat16* __restrict__ X0, int c0, float scale) {
  int idx = blockIdx.x * 256 + threadIdx.x;   // 0..331775 (row*576+col, row<576)
  int cl = blockIdx.y;
  int c = c0 + cl;
  int row = idx / NK, col = idx % NK;
  int i = row / 24, j = row % 24, a = col / 24, b = col % 24;
  int u = 11 - i + a, v = 11 - j + b;
  float br = 0.f, bi = 0.f;
  if (u >= 0 && u < 24 && v >= 0 && v < 24) {
    float2 s0 = spec[(c * 2 + 0) * 576 + u * 24 + v];
    float2 s1 = spec[(c * 2 + 1) * 576 + u * 24 + v];
    float kx = (float)(a - 11), ky = (float)(b - 11);
    float xr = s0.x * kx + s1.x * ky;
    float xi = s0.y * kx + s1.y * ky;
    br = xi * scale;
    bi = -xr * scale;
  }
  size_t off = (size_t)cl * SETSTR + idx;
  __hip_bfloat16 h, l;
  bsplit(br, h, l); B[off] = h; B[off + PLN] = l;
  bsplit(bi, h, l); B[off + 2 * PLN] = h; B[off + 3 * PLN] = l;
  float d = (row == col) ? 1.f : 0.f;
  bsplit(br * (1.f / 5.f) + d, h, l); X0[off] = h; X0[off + PLN] = l;
  bsplit(bi * (1.f / 5.f), h, l);     X0[off + 2 * PLN] = h; X0[off + 3 * PLN] = l;
}

// ---------------- transpose the 4 split planes ----------------
__global__ __launch_bounds__(256) void transpose4(const __hip_bfloat16* __restrict__ src,
                                                  __hip_bfloat16* __restrict__ dst) {
  __shared__ __hip_bfloat16 tile[64][65];
  int cl = blockIdx.z;
  size_t off = (size_t)cl * SETSTR;
  int rB = blockIdx.y * 64, cB = blockIdx.x * 64;
  int tx = threadIdx.x & 63, ty = threadIdx.x >> 6;
  for (int p = 0; p < 4; ++p) {
    for (int li = 0; li < 16; ++li) {
      int r = ty * 16 + li;
      tile[r][tx] = src[off + (size_t)p * PLN + (size_t)(rB + r) * NK + cB + tx];
    }
    __syncthreads();
    for (int li = 0; li < 16; ++li) {
      int r = ty * 16 + li;
      dst[off + (size_t)p * PLN + (size_t)(cB + r) * NK + rB + tx] = tile[tx][r];
    }
    __syncthreads();
  }
}

// ---------------- Stage 3: batched split-complex MFMA GEMM, 128x128 tile ----------------
// D = alpha*(A*B) + delta*I.  A row-major [m][k] split planes; B given as BT [n][k].
// wf bit0: write D (row-major); bit1: write DT (transposed).
// SINGLE-buffered 64 KB LDS -> 2 blocks/CU (16 waves/CU); cross-block TLP hides the
// per-kstep stage drain. Flat 1D grid; when g==16, channel c -> XCD c&7 (L2 locality).
__global__ __launch_bounds__(512, 4) void cgemm_mfma(
    const __hip_bfloat16* __restrict__ A, const __hip_bfloat16* __restrict__ BT,
    __hip_bfloat16* __restrict__ D, __hip_bfloat16* __restrict__ DT,
    float alpha, float delta, int wf) {
  __shared__ char lds[65536];   // A planes @0 (4*8192), B planes @32768
  const int t = threadIdx.x;
  const int lane = t & 63;
  const int wid = t >> 6;
  const int wm = wid >> 2, wn = wid & 3;          // 2 x 4 waves, wave tile 64x32
  // block remap: XCD-local channels when full 16-channel group
  int p0 = blockIdx.x;
  int cl, tile;
  if (gridDim.x == 400) {
    cl = (p0 & 7) + ((p0 >> 3) / 25) * 8;
    tile = (p0 >> 3) % 25;
  } else {
    cl = p0 / 25;
    tile = p0 % 25;
  }
  const int rowBase = (tile / 5) * 128, colBase = (tile % 5) * 128;
  const size_t chOff = (size_t)cl * SETSTR;
  const __hip_bfloat16* Ab = A + chOff;
  const __hip_bfloat16* Bb = BT + chOff;

  // staging: 2048 16B-chunks per operand; cid = i*512+t -> plane p, row r, phys chunk cp
  size_t gA[4], gB[4];
  int ldsOff[4];
#pragma unroll
  for (int i = 0; i < 4; ++i) {
    int cid = i * 512 + t;
    int pp = cid >> 9, r = (cid >> 2) & 127, cp = cid & 3;
    int cg = cp ^ ((r >> 1) & 3);
    gA[i] = (size_t)pp * PLN + (size_t)(rowBase + r) * NK + cg * 8;
    gB[i] = (size_t)pp * PLN + (size_t)(colBase + r) * NK + cg * 8;
    ldsOff[i] = cid * 16;
  }
  // fragment read offsets
  int aoff[4], boff[2];
#pragma unroll
  for (int mi = 0; mi < 4; ++mi) {
    int ra = wm * 64 + mi * 16 + (lane & 15);
    int ch = (lane >> 4) ^ ((ra >> 1) & 3);
    aoff[mi] = (ra * 4 + ch) * 16;
  }
#pragma unroll
  for (int ni = 0; ni < 2; ++ni) {
    int cb = wn * 32 + ni * 16 + (lane & 15);
    int ch = (lane >> 4) ^ ((cb >> 1) & 3);
    boff[ni] = 32768 + (cb * 4 + ch) * 16;
  }

  f32x4 accP[4][2] = {}, accN[4][2] = {}, accI[4][2] = {};

  auto STAGE = [&](int k0) {
#pragma unroll
    for (int i = 0; i < 4; ++i) {
      gld16(Ab + gA[i] + k0, &lds[ldsOff[i]]);
      gld16(Bb + gB[i] + k0, &lds[32768 + ldsOff[i]]);
    }
  };

  STAGE(0);
  __syncthreads();   // drains vmcnt(0)

#pragma unroll 1
  for (int ks = 0; ks < 18; ++ks) {
    short8 arh[4], arl[4], aih[4], ail[4];
    short8 brh[2], brl[2], bih[2], bil[2];
#pragma unroll
    for (int mi = 0; mi < 4; ++mi) {
      const char* base = &lds[aoff[mi]];
      arh[mi] = *(const short8*)(base);
      arl[mi] = *(const short8*)(base + 8192);
      aih[mi] = *(const short8*)(base + 16384);
      ail[mi] = *(const short8*)(base + 24576);
    }
#pragma unroll
    for (int ni = 0; ni < 2; ++ni) {
      const char* base = &lds[boff[ni]];
      brh[ni] = *(const short8*)(base);
      brl[ni] = *(const short8*)(base + 8192);
      bih[ni] = *(const short8*)(base + 16384);
      bil[ni] = *(const short8*)(base + 24576);
    }
    __builtin_amdgcn_s_setprio(1);
#pragma unroll
    for (int mi = 0; mi < 4; ++mi)
#pragma unroll
      for (int ni = 0; ni < 2; ++ni) {
        accP[mi][ni] = MFMA16(arh[mi], brh[ni], accP[mi][ni]);
        accP[mi][ni] = MFMA16(arh[mi], brl[ni], accP[mi][ni]);
        accP[mi][ni] = MFMA16(arl[mi], brh[ni], accP[mi][ni]);
        accN[mi][ni] = MFMA16(aih[mi], bih[ni], accN[mi][ni]);
        accN[mi][ni] = MFMA16(aih[mi], bil[ni], accN[mi][ni]);
        accN[mi][ni] = MFMA16(ail[mi], bih[ni], accN[mi][ni]);
        accI[mi][ni] = MFMA16(arh[mi], bih[ni], accI[mi][ni]);
        accI[mi][ni] = MFMA16(arh[mi], bil[ni], accI[mi][ni]);
        accI[mi][ni] = MFMA16(arl[mi], bih[ni], accI[mi][ni]);
        accI[mi][ni] = MFMA16(aih[mi], brh[ni], accI[mi][ni]);
        accI[mi][ni] = MFMA16(aih[mi], brl[ni], accI[mi][ni]);
        accI[mi][ni] = MFMA16(ail[mi], brh[ni], accI[mi][ni]);
      }
    __builtin_amdgcn_s_setprio(0);
    if (ks < 17) {
      __syncthreads();              // all waves done reading current tile
      STAGE((ks + 1) * 32);
      __syncthreads();              // staging complete (compiler drains vmcnt)
    }
  }

  __hip_bfloat16* Dp = D + chOff;
  __hip_bfloat16* Tp = DT + chOff;
#pragma unroll
  for (int mi = 0; mi < 4; ++mi)
#pragma unroll
    for (int ni = 0; ni < 2; ++ni) {
      int rb = rowBase + wm * 64 + mi * 16 + (lane >> 4) * 4;
      int cc = colBase + wn * 32 + ni * 16 + (lane & 15);
      if (cc >= NK) continue;
#pragma unroll
      for (int j = 0; j < 4; ++j) {
        int r = rb + j;
        if (r >= NK) continue;
        float vR = alpha * (accP[mi][ni][j] - accN[mi][ni][j]) + ((r == cc) ? delta : 0.f);
        float vI = alpha * accI[mi][ni][j];
        __hip_bfloat16 hR, lR, hI, lI;
        bsplit(vR, hR, lR);
        bsplit(vI, hI, lI);
        if (wf & 1) {
          Dp[(size_t)r * NK + cc] = hR;
          Dp[PLN + (size_t)r * NK + cc] = lR;
          Dp[2 * PLN + (size_t)r * NK + cc] = hI;
          Dp[3 * PLN + (size_t)r * NK + cc] = lI;
        }
        if (wf & 2) {
          Tp[(size_t)cc * NK + r] = hR;
          Tp[PLN + (size_t)cc * NK + r] = lR;
          Tp[2 * PLN + (size_t)cc * NK + r] = hI;
          Tp[3 * PLN + (size_t)cc * NK + r] = lI;
        }
      }
    }
}

// ---------------- Stage 4: slice + roll + separable DFTs ----------------
__global__ void passA(const __hip_bfloat16* __restrict__ X, float2* __restrict__ P) {
  int cl = blockIdx.y;
  int idx = blockIdx.x * 256 + threadIdx.x;
  int v = idx % 20, u = (idx / 20) % 20, q = (idx / 400) % 16, p = idx / 6400;
  int pp = (p + 7) % 16;
  int qq = (q + 7) % 16;
  int row = (pp + 5) * 24 + (qq + 5);
  int uu = (u + 9) % 20;
  int aa = uu + 3;
  const __hip_bfloat16* tb = X + (size_t)cl * SETSTR;
  float2 acc = make_float2(0.f, 0.f);
  for (int vp = 0; vp < 20; ++vp) {
    int vv = (vp + 9) % 20;
    int col = aa * 24 + (vv + 3);
    size_t o = (size_t)row * NK + col;
    float xr = __bfloat162float(tb[o]) + __bfloat162float(tb[PLN + o]);
    float xi = __bfloat162float(tb[2 * PLN + o]) + __bfloat162float(tb[3 * PLN + o]);
    float ang = (TAU / 20.f) * (float)((v * vp) % 20);
    float s, co;
    sincosf(ang, &s, &co);
    acc.x += xr * co - xi * s;
    acc.y += xr * s + xi * co;
  }
  P[(size_t)cl * MAPSZ + idx] = acc;
}

__global__ void passB(const float2* __restrict__ Pin, float2* __restrict__ Pout) {
  int cl = blockIdx.y;
  int idx = blockIdx.x * 256 + threadIdx.x;
  int v = idx % 20, u = (idx / 20) % 20, q = (idx / 400) % 16, p = idx / 6400;
  const float2* in = Pin + (size_t)cl * MAPSZ;
  float2 acc = make_float2(0.f, 0.f);
  for (int up = 0; up < 20; ++up) {
    float2 val = in[(p * 16 + q) * 400 + up * 20 + v];
    float ang = (TAU / 20.f) * (float)((u * up) % 20);
    float s, co;
    sincosf(ang, &s, &co);
    acc.x += val.x * co - val.y * s;
    acc.y += val.x * s + val.y * co;
  }
  Pout[(size_t)cl * MAPSZ + idx] = acc;
}

__global__ void passC(const float2* __restrict__ Pin, float2* __restrict__ Pout) {
  int cl = blockIdx.y;
  int idx = blockIdx.x * 256 + threadIdx.x;
  int v = idx % 20, u = (idx / 20) % 20, q = (idx / 400) % 16, p = idx / 6400;
  const float2* in = Pin + (size_t)cl * MAPSZ;
  float2 acc = make_float2(0.f, 0.f);
  for (int qp = 0; qp < 16; ++qp) {
    float2 val = in[(p * 16 + qp) * 400 + u * 20 + v];
    float ang = -(TAU / 16.f) * (float)((q * qp) % 16);
    float s, co;
    sincosf(ang, &s, &co);
    acc.x += val.x * co - val.y * s;
    acc.y += val.x * s + val.y * co;
  }
  Pout[(size_t)cl * MAPSZ + idx] = acc;
}

// passD: final DFT, write split-bf16 m directly into padded [n][KOUT] planes
__global__ void passD(const float2* __restrict__ Pin, __hip_bfloat16* __restrict__ ms, int c0) {
  int cl = blockIdx.y;
  int c = c0 + cl;
  int idx = blockIdx.x * 256 + threadIdx.x;
  int v = idx % 20, u = (idx / 20) % 20, q = (idx / 400) % 16, p = idx / 6400;
  const float2* in = Pin + (size_t)cl * MAPSZ;
  float acc = 0.f;
  for (int pp = 0; pp < 16; ++pp) {
    float2 val = in[(pp * 16 + q) * 400 + u * 20 + v];
    float ang = -(TAU / 16.f) * (float)((p * pp) % 16);
    float s, co;
    sincosf(ang, &s, &co);
    acc += val.x * co - val.y * s;
  }
  acc *= (1.f / 400.f);
  int n = c * 256 + idx / 400;          // o = p*16+q
  int k = idx % 400;                    // k = u*20+v
  __hip_bfloat16 h, l;
  bsplit(acc, h, l);
  ms[(size_t)n * KOUT + k] = h;
  ms[MPL + (size_t)n * KOUT + k] = l;
}

// zero the k in [400,416) pad of the m planes
__global__ void pad_m(__hip_bfloat16* __restrict__ ms) {
  int idx = blockIdx.x * 256 + threadIdx.x;   // 4096*16*2
  int p = idx >> 16;
  int rem = idx & 65535;
  int n = rem >> 4;
  int k = 400 + (rem & 15);
  ms[(size_t)p * MPL + (size_t)n * KOUT + k] = __float2bfloat16(0.f);
}

// convert x (8192x400 f32) to split bf16 padded [2][8192][KOUT]
__global__ void prep_x(const float* __restrict__ x, __hip_bfloat16* __restrict__ xs) {
  int idx = blockIdx.x * 256 + threadIdx.x;   // 8192*52
  if (idx >= 8192 * 52) return;
  int b = idx / 52, c8 = idx % 52;
  int k = c8 * 8;
  short8 hh = {}, ll = {};
  if (k < 400) {
    const float4* xp = (const float4*)(x + (size_t)b * 400 + k);
    float4 v0 = xp[0], v1 = xp[1];
    float vals[8] = {v0.x, v0.y, v0.z, v0.w, v1.x, v1.y, v1.z, v1.w};
#pragma unroll
    for (int i = 0; i < 8; ++i) {
      __hip_bfloat16 h, l;
      bsplit(vals[i], h, l);
      hh[i] = braw(h);
      ll[i] = braw(l);
    }
  }
  *(short8*)(xs + (size_t)b * KOUT + k) = hh;
  *(short8*)(xs + XPL + (size_t)b * KOUT + k) = ll;
}

// ---------------- Stage 5: output GEMM, split-bf16 MFMA, 128x128 tile ----------------
__global__ __launch_bounds__(512, 2) void out_mfma(
    const __hip_bfloat16* __restrict__ xs, const __hip_bfloat16* __restrict__ ms,
    float* __restrict__ Y) {
  __shared__ char lds[2][32768];   // A planes @0 (2*8192), B planes @16384
  const int t = threadIdx.x;
  const int lane = t & 63;
  const int wid = t >> 6;
  const int wm = wid >> 2, wn = wid & 3;
  const int rowBase = blockIdx.y * 128, colBase = blockIdx.x * 128;

  size_t gA[2], gB[2];
  int ldsOff[2];
#pragma unroll
  for (int i = 0; i < 2; ++i) {
    int cid = i * 512 + t;
    int p = cid >> 9, r = (cid >> 2) & 127, cp = cid & 3;
    int cg = cp ^ ((r >> 1) & 3);
    gA[i] = (size_t)p * XPL + (size_t)(rowBase + r) * KOUT + cg * 8;
    gB[i] = (size_t)p * MPL + (size_t)(colBase + r) * KOUT + cg * 8;
    ldsOff[i] = cid * 16;
  }
  int aoff[4], boff[2];
#pragma unroll
  for (int mi = 0; mi < 4; ++mi) {
    int ra = wm * 64 + mi * 16 + (lane & 15);
    int ch = (lane >> 4) ^ ((ra >> 1) & 3);
    aoff[mi] = (ra * 4 + ch) * 16;
  }
#pragma unroll
  for (int ni = 0; ni < 2; ++ni) {
    int cb = wn * 32 + ni * 16 + (lane & 15);
    int ch = (lane >> 4) ^ ((cb >> 1) & 3);
    boff[ni] = 16384 + (cb * 4 + ch) * 16;
  }

  f32x4 acc[4][2] = {};

  auto STAGE = [&](int buf, int k0) {
#pragma unroll
    for (int i = 0; i < 2; ++i) {
      gld16(xs + gA[i] + k0, &lds[buf][ldsOff[i]]);
      gld16(ms + gB[i] + k0, &lds[buf][16384 + ldsOff[i]]);
    }
  };

  STAGE(0, 0);
  __syncthreads();

  int cur = 0;
#pragma unroll 1
  for (int ks = 0; ks < 13; ++ks) {
    if (ks < 12) STAGE(cur ^ 1, (ks + 1) * 32);
    short8 ah[4], al[4], bh[2], bl[2];
#pragma unroll
    for (int mi = 0; mi < 4; ++mi) {
      const char* base = &lds[cur][aoff[mi]];
      ah[mi] = *(const short8*)(base);
      al[mi] = *(const short8*)(base + 8192);
    }
#pragma unroll
    for (int ni = 0; ni < 2; ++ni) {
      const char* base = &lds[cur][boff[ni]];
      bh[ni] = *(const short8*)(base);
      bl[ni] = *(const short8*)(base + 8192);
    }
#pragma unroll
    for (int mi = 0; mi < 4; ++mi)
#pragma unroll
      for (int ni = 0; ni < 2; ++ni) {
        acc[mi][ni] = MFMA16(ah[mi], bh[ni], acc[mi][ni]);
        acc[mi][ni] = MFMA16(ah[mi], bl[ni], acc[mi][ni]);
        acc[mi][ni] = MFMA16(al[mi], bh[ni], acc[mi][ni]);
      }
    __syncthreads();
    cur ^= 1;
  }

#pragma unroll
  for (int mi = 0; mi < 4; ++mi)
#pragma unroll
    for (int ni = 0; ni < 2; ++ni) {
      int rb = rowBase + wm * 64 + mi * 16 + (lane >> 4) * 4;
      int cc = colBase + wn * 32 + ni * 16 + (lane & 15);
#pragma unroll
      for (int j = 0; j < 4; ++j)
        Y[(size_t)(rb + j) * 4096 + cc] = acc[mi][ni][j];
    }
}

// ---------------- Launcher ----------------
extern "C" void kernel_launch(void* const* d_in, const int* in_sizes, int n_in,
                              void* d_out, int out_size, void* d_ws, size_t ws_size,
                              hipStream_t stream) {
  const float* x = (const float*)d_in[0];     // (8192,1,20,20)
  const float* sig = (const float*)d_in[1];   // (16,2,24,24)
  float* out = (float*)d_out;                 // (8192,16,16,16)
  char* ws = (char*)d_ws;

  const size_t specBytes = 32ull * 576 * sizeof(float2);
  const size_t xsBytes = 2ull * XPL * 2;
  const size_t msBytes = 2ull * MPL * 2;
  const size_t fixed = specBytes + xsBytes + msBytes;
  const size_t setB = SETSTR * 2;                       // bytes per split set
  const size_t perCh = 5 * setB + 2ull * MAPSZ * 8;     // B, X0, X0T, X1, X1T + P0/P1

  int cg = 1;
  if (ws_size > fixed) {
    size_t av = (ws_size - fixed) / perCh;
    cg = (av < 1) ? 1 : (av > 16 ? 16 : (int)av);
  }

  float2* spec = (float2*)ws;
  __hip_bfloat16* xs = (__hip_bfloat16*)(ws + specBytes);
  __hip_bfloat16* ms = (__hip_bfloat16*)(ws + specBytes + xsBytes);
  __hip_bfloat16* Bst = (__hip_bfloat16*)(ws + fixed);
  __hip_bfloat16* X0 = Bst + (size_t)cg * SETSTR;
  __hip_bfloat16* X0T = X0 + (size_t)cg * SETSTR;
  __hip_bfloat16* X1 = X0T + (size_t)cg * SETSTR;
  __hip_bfloat16* X1T = X1 + (size_t)cg * SETSTR;
  float2* P0 = (float2*)(X1T + (size_t)cg * SETSTR);
  float2* P1 = P0 + (size_t)cg * MAPSZ;

  spectrum_kernel<<<dim3(32), dim3(576), 0, stream>>>(sig, spec);
  prep_x<<<dim3((8192 * 52 + 255) / 256), dim3(256), 0, stream>>>(x, xs);
  pad_m<<<dim3(512), dim3(256), 0, stream>>>(ms);

  const float scale = 1.f / 256.f;  // s = 8 squarings
  for (int c0 = 0; c0 < 16; c0 += cg) {
    int g = (16 - c0 < cg) ? (16 - c0) : cg;
    buildBX<<<dim3(1296, g), dim3(256), 0, stream>>>(spec, Bst, X0, c0, scale);
    transpose4<<<dim3(9, 9, g), dim3(256), 0, stream>>>(X0, X0T);
    __hip_bfloat16 *xr = X0, *xt = X0T, *yr = X1, *yt = X1T;
    // Horner (Taylor order 5): X <- I + (B*X)/k, k=4..1. Only DT consumed until k=1.
    for (int k = 4; k >= 1; --k) {
      int wf = (k == 1) ? 3 : 2;
      cgemm_mfma<<<dim3(25 * g), dim3(512), 0, stream>>>(Bst, xt, yr, yt,
                                                         1.f / (float)k, 1.f, wf);
      __hip_bfloat16* tmp;
      tmp = xr; xr = yr; yr = tmp;
      tmp = xt; xt = yt; yt = tmp;
    }
    // 8 squarings; last one only needs row-major output (feeds passA)
    for (int t8 = 0; t8 < 8; ++t8) {
      int wf = (t8 == 7) ? 1 : 3;
      cgemm_mfma<<<dim3(25 * g), dim3(512), 0, stream>>>(xr, xt, yr, yt, 1.f, 0.f, wf);
      __hip_bfloat16* tmp;
      tmp = xr; xr = yr; yr = tmp;
      tmp = xt; xt = yt; yt = tmp;
    }
    passA<<<dim3(400, g), dim3(256), 0, stream>>>(xr, P0);
    passB<<<dim3(400, g), dim3(256), 0, stream>>>(P0, P1);
    passC<<<dim3(400, g), dim3(256), 0, stream>>>(P1, P0);
    passD<<<dim3(400, g), dim3(256), 0, stream>>>(P0, ms, c0);
  }

  out_mfma<<<dim3(32, 64), dim3(512), 0, stream>>>(xs, ms, out);
}

// Round 6
// 1985.711 us; speedup vs baseline: 3.3355x; 3.3355x over previous
//
#include <hip/hip_runtime.h>
#include <hip/hip_bf16.h>
#include <math.h>

#define TAU 6.283185307179586f
#define NK 576                    // matrix dimension (K always exact: 18*32)
#define NPAD 640                  // padded row count for 128-row tiles
#define PLN ((size_t)NPAD * NK)   // elems per padded plane = 368640
#define SETSTR ((size_t)4 * PLN)  // elems per 4-plane split set
#define MAPSZ 102400              // 16*16*20*20
#define KOUT 416                  // padded K for output gemm (13*32)
#define XPL ((size_t)8192 * KOUT)
#define MPL ((size_t)4096 * KOUT)

typedef __attribute__((ext_vector_type(8))) short short8;
typedef __attribute__((ext_vector_type(4))) float f32x4;

__device__ inline void bsplit(float v, __hip_bfloat16& h, __hip_bfloat16& l) {
  h = __float2bfloat16(v);
  l = __float2bfloat16(v - __bfloat162float(h));
}
__device__ inline short braw(__hip_bfloat16 b) { return *reinterpret_cast<short*>(&b); }

__device__ inline void gld16(const void* g, const void* l) {
  __builtin_amdgcn_global_load_lds((const __attribute__((address_space(1))) unsigned*)g,
                                   (__attribute__((address_space(3))) unsigned*)l, 16, 0, 0);
}

#define MFMA16(a, b, c) __builtin_amdgcn_mfma_f32_16x16x32_bf16(a, b, c, 0, 0, 0)

// ---------------- Stage 1: signal -> spectrum ----------------
__device__ inline void dft24(const float2* in, float2* out, int t, float sgn, bool firstAxis) {
  int r = t / 24, c = t % 24;
  int kk = firstAxis ? r : c;
  float2 acc = make_float2(0.f, 0.f);
  for (int n = 0; n < 24; ++n) {
    float ang = sgn * (TAU / 24.f) * (float)((kk * n) % 24);
    float s, co;
    sincosf(ang, &s, &co);
    float2 v = firstAxis ? in[n * 24 + c] : in[r * 24 + n];
    acc.x += v.x * co - v.y * s;
    acc.y += v.x * s + v.y * co;
  }
  out[t] = acc;
}

__global__ void spectrum_kernel(const float* __restrict__ sig, float2* __restrict__ spec) {
  __shared__ float2 b0[576];
  __shared__ float2 b1[576];
  int f = blockIdx.x;
  int t = threadIdx.x;
  int r = t / 24, c = t % 24;
  b0[t] = make_float2(sig[f * 576 + t], 0.f);
  __syncthreads();
  dft24(b0, b1, t, -1.f, false); __syncthreads();
  dft24(b1, b0, t, -1.f, true);  __syncthreads();
  {
    int p2 = (r + 12) % 24 - 11;
    int q2 = (c + 12) % 24 - 11;
    float rr = (float)(1 + p2 * p2 + q2 * q2) * 5.f;
    float2 v = b0[t];
    b0[t] = make_float2(v.x / rr, v.y / rr);
  }
  __syncthreads();
  dft24(b0, b1, t, +1.f, false); __syncthreads();
  dft24(b1, b0, t, +1.f, true);  __syncthreads();
  {
    float winr = 0.5f * (1.f - cosf(TAU * (float)r / 24.f));
    float winc = 0.5f * (1.f - cosf(TAU * (float)c / 24.f));
    float w = winr * winc * (1.f / 576.f);
    float2 v = b0[t];
    b0[t] = make_float2(v.x * w, v.y * w);
  }
  __syncthreads();
  dft24(b0, b1, t, -1.f, false); __syncthreads();
  dft24(b1, b0, t, -1.f, true);  __syncthreads();
  int p = (r + 12) % 24, q = (c + 12) % 24;
  spec[f * 576 + p * 24 + q] = b0[t];
}

// ---------------- Stage 2: build split B and X0 = I + B/5 ----------------
__global__ void buildBX(const float2* __restrict__ spec, __hip_bfloat16* __restrict__ B,
                        __hip_bfloat16* __restrict__ X0, int c0, float scale) {
  int idx = blockIdx.x * 256 + threadIdx.x;   // 0..331775 (row*576+col, row<576)
  int cl = blockIdx.y;
  int c = c0 + cl;
  int row = idx / NK, col = idx % NK;
  int i = row / 24, j = row % 24, a = col / 24, b = col % 24;
  int u = 11 - i + a, v = 11 - j + b;
  float br = 0.f, bi = 0.f;
  if (u >= 0 && u < 24 && v >= 0 && v < 24) {
    float2 s0 = spec[(c * 2 + 0) * 576 + u * 24 + v];
    float2 s1 = spec[(c * 2 + 1) * 576 + u * 24 + v];
    float kx = (float)(a - 11), ky = (float)(b - 11);
    float xr = s0.x * kx + s1.x * ky;
    float xi = s0.y * kx + s1.y * ky;
    br = xi * scale;
    bi = -xr * scale;
  }
  size_t off = (size_t)cl * SETSTR + idx;
  __hip_bfloat16 h, l;
  bsplit(br, h, l); B[off] = h; B[off + PLN] = l;
  bsplit(bi, h, l); B[off + 2 * PLN] = h; B[off + 3 * PLN] = l;
  float d = (row == col) ? 1.f : 0.f;
  bsplit(br * (1.f / 5.f) + d, h, l); X0[off] = h; X0[off + PLN] = l;
  bsplit(bi * (1.f / 5.f), h, l);     X0[off + 2 * PLN] = h; X0[off + 3 * PLN] = l;
}

// ---------------- transpose the 4 split planes ----------------
__global__ __launch_bounds__(256) void transpose4(const __hip_bfloat16* __restrict__ src,
                                                  __hip_bfloat16* __restrict__ dst) {
  __shared__ __hip_bfloat16 tile[64][65];
  int cl = blockIdx.z;
  size_t off = (size_t)cl * SETSTR;
  int rB = blockIdx.y * 64, cB = blockIdx.x * 64;
  int tx = threadIdx.x & 63, ty = threadIdx.x >> 6;
  for (int p = 0; p < 4; ++p) {
    for (int li = 0; li < 16; ++li) {
      int r = ty * 16 + li;
      tile[r][tx] = src[off + (size_t)p * PLN + (size_t)(rB + r) * NK + cB + tx];
    }
    __syncthreads();
    for (int li = 0; li < 16; ++li) {
      int r = ty * 16 + li;
      dst[off + (size_t)p * PLN + (size_t)(cB + r) * NK + rB + tx] = tile[tx][r];
    }
    __syncthreads();
  }
}

// ---------------- Stage 3: batched split-complex MFMA GEMM, 128x128 tile ----------------
// D = alpha*(A*B) + delta*I.  A row-major [m][k] split planes; B given as BT [n][k].
// wf bit0: write D (row-major); bit1: write DT (transposed).
// Double-buffered LDS + counted-vmcnt pipeline (T3/T4): prefetched loads stay in
// flight across raw barriers; never drain vmcnt to 0 in the main loop.
__global__ __launch_bounds__(512, 2) void cgemm_mfma(
    const __hip_bfloat16* __restrict__ A, const __hip_bfloat16* __restrict__ BT,
    __hip_bfloat16* __restrict__ D, __hip_bfloat16* __restrict__ DT,
    float alpha, float delta, int wf) {
  __shared__ char lds[2][65536];   // per buf: A planes @0 (4*8192), B planes @32768
  const int t = threadIdx.x;
  const int lane = t & 63;
  const int wid = t >> 6;
  const int wm = wid >> 2, wn = wid & 3;          // 2 x 4 waves, wave tile 64x32
  // block remap: XCD-local channels when full 16-channel group
  int p0 = blockIdx.x;
  int cl, tile;
  if (gridDim.x == 400) {
    cl = (p0 & 7) + ((p0 >> 3) / 25) * 8;
    tile = (p0 >> 3) % 25;
  } else {
    cl = p0 / 25;
    tile = p0 % 25;
  }
  const int rowBase = (tile / 5) * 128, colBase = (tile % 5) * 128;
  const size_t chOff = (size_t)cl * SETSTR;
  const __hip_bfloat16* Ab = A + chOff;
  const __hip_bfloat16* Bb = BT + chOff;

  // staging: 2048 16B-chunks per operand; cid = i*512+t -> plane p, row r, phys chunk cp
  size_t gA[4], gB[4];
  int ldsOff[4];
#pragma unroll
  for (int i = 0; i < 4; ++i) {
    int cid = i * 512 + t;
    int pp = cid >> 9, r = (cid >> 2) & 127, cp = cid & 3;
    int cg = cp ^ ((r >> 1) & 3);
    gA[i] = (size_t)pp * PLN + (size_t)(rowBase + r) * NK + cg * 8;
    gB[i] = (size_t)pp * PLN + (size_t)(colBase + r) * NK + cg * 8;
    ldsOff[i] = cid * 16;
  }
  // fragment read offsets
  int aoff[4], boff[2];
#pragma unroll
  for (int mi = 0; mi < 4; ++mi) {
    int ra = wm * 64 + mi * 16 + (lane & 15);
    int ch = (lane >> 4) ^ ((ra >> 1) & 3);
    aoff[mi] = (ra * 4 + ch) * 16;
  }
#pragma unroll
  for (int ni = 0; ni < 2; ++ni) {
    int cb = wn * 32 + ni * 16 + (lane & 15);
    int ch = (lane >> 4) ^ ((cb >> 1) & 3);
    boff[ni] = 32768 + (cb * 4 + ch) * 16;
  }

  f32x4 accP[4][2] = {}, accN[4][2] = {}, accI[4][2] = {};

  auto STAGE = [&](int buf, int k0) {
#pragma unroll
    for (int i = 0; i < 4; ++i) {
      gld16(Ab + gA[i] + k0, &lds[buf][ldsOff[i]]);
      gld16(Bb + gB[i] + k0, &lds[buf][32768 + ldsOff[i]]);
    }
  };

  auto COMPUTE = [&](int cur) {
    short8 arh[4], arl[4], aih[4], ail[4];
    short8 brh[2], brl[2], bih[2], bil[2];
#pragma unroll
    for (int mi = 0; mi < 4; ++mi) {
      const char* base = &lds[cur][aoff[mi]];
      arh[mi] = *(const short8*)(base);
      arl[mi] = *(const short8*)(base + 8192);
      aih[mi] = *(const short8*)(base + 16384);
      ail[mi] = *(const short8*)(base + 24576);
    }
#pragma unroll
    for (int ni = 0; ni < 2; ++ni) {
      const char* base = &lds[cur][boff[ni]];
      brh[ni] = *(const short8*)(base);
      brl[ni] = *(const short8*)(base + 8192);
      bih[ni] = *(const short8*)(base + 16384);
      bil[ni] = *(const short8*)(base + 24576);
    }
    __builtin_amdgcn_s_setprio(1);
#pragma unroll
    for (int mi = 0; mi < 4; ++mi)
#pragma unroll
      for (int ni = 0; ni < 2; ++ni) {
        accP[mi][ni] = MFMA16(arh[mi], brh[ni], accP[mi][ni]);
        accP[mi][ni] = MFMA16(arh[mi], brl[ni], accP[mi][ni]);
        accP[mi][ni] = MFMA16(arl[mi], brh[ni], accP[mi][ni]);
        accN[mi][ni] = MFMA16(aih[mi], bih[ni], accN[mi][ni]);
        accN[mi][ni] = MFMA16(aih[mi], bil[ni], accN[mi][ni]);
        accN[mi][ni] = MFMA16(ail[mi], bih[ni], accN[mi][ni]);
        accI[mi][ni] = MFMA16(arh[mi], bih[ni], accI[mi][ni]);
        accI[mi][ni] = MFMA16(arh[mi], bil[ni], accI[mi][ni]);
        accI[mi][ni] = MFMA16(arl[mi], bih[ni], accI[mi][ni]);
        accI[mi][ni] = MFMA16(aih[mi], brh[ni], accI[mi][ni]);
        accI[mi][ni] = MFMA16(aih[mi], brl[ni], accI[mi][ni]);
        accI[mi][ni] = MFMA16(ail[mi], brh[ni], accI[mi][ni]);
      }
    __builtin_amdgcn_s_setprio(0);
  };

  STAGE(0, 0);
#pragma unroll 1
  for (int ks = 0; ks < 17; ++ks) {
    int cur = ks & 1;
    STAGE(cur ^ 1, (ks + 1) * 32);                       // 8 loads in flight
    asm volatile("s_waitcnt vmcnt(8)" ::: "memory");     // tile ks landed; ks+1 flies
    __builtin_amdgcn_s_barrier();
    __builtin_amdgcn_sched_barrier(0);
    COMPUTE(cur);
    __builtin_amdgcn_s_barrier();                        // all waves done reading cur
  }
  asm volatile("s_waitcnt vmcnt(0)" ::: "memory");       // last tile
  __builtin_amdgcn_s_barrier();
  __builtin_amdgcn_sched_barrier(0);
  COMPUTE(1);

  __hip_bfloat16* Dp = D + chOff;
  __hip_bfloat16* Tp = DT + chOff;
#pragma unroll
  for (int mi = 0; mi < 4; ++mi)
#pragma unroll
    for (int ni = 0; ni < 2; ++ni) {
      int rb = rowBase + wm * 64 + mi * 16 + (lane >> 4) * 4;
      int cc = colBase + wn * 32 + ni * 16 + (lane & 15);
      if (cc >= NK) continue;
#pragma unroll
      for (int j = 0; j < 4; ++j) {
        int r = rb + j;
        if (r >= NK) continue;
        float vR = alpha * (accP[mi][ni][j] - accN[mi][ni][j]) + ((r == cc) ? delta : 0.f);
        float vI = alpha * accI[mi][ni][j];
        __hip_bfloat16 hR, lR, hI, lI;
        bsplit(vR, hR, lR);
        bsplit(vI, hI, lI);
        if (wf & 1) {
          Dp[(size_t)r * NK + cc] = hR;
          Dp[PLN + (size_t)r * NK + cc] = lR;
          Dp[2 * PLN + (size_t)r * NK + cc] = hI;
          Dp[3 * PLN + (size_t)r * NK + cc] = lI;
        }
        if (wf & 2) {
          Tp[(size_t)cc * NK + r] = hR;
          Tp[PLN + (size_t)cc * NK + r] = lR;
          Tp[2 * PLN + (size_t)cc * NK + r] = hI;
          Tp[3 * PLN + (size_t)cc * NK + r] = lI;
        }
      }
    }
}

// ---------------- Stage 4: slice + roll + separable DFTs ----------------
__global__ void passA(const __hip_bfloat16* __restrict__ X, float2* __restrict__ P) {
  int cl = blockIdx.y;
  int idx = blockIdx.x * 256 + threadIdx.x;
  int v = idx % 20, u = (idx / 20) % 20, q = (idx / 400) % 16, p = idx / 6400;
  int pp = (p + 7) % 16;
  int qq = (q + 7) % 16;
  int row = (pp + 5) * 24 + (qq + 5);
  int uu = (u + 9) % 20;
  int aa = uu + 3;
  const __hip_bfloat16* tb = X + (size_t)cl * SETSTR;
  float2 acc = make_float2(0.f, 0.f);
  for (int vp = 0; vp < 20; ++vp) {
    int vv = (vp + 9) % 20;
    int col = aa * 24 + (vv + 3);
    size_t o = (size_t)row * NK + col;
    float xr = __bfloat162float(tb[o]) + __bfloat162float(tb[PLN + o]);
    float xi = __bfloat162float(tb[2 * PLN + o]) + __bfloat162float(tb[3 * PLN + o]);
    float ang = (TAU / 20.f) * (float)((v * vp) % 20);
    float s, co;
    sincosf(ang, &s, &co);
    acc.x += xr * co - xi * s;
    acc.y += xr * s + xi * co;
  }
  P[(size_t)cl * MAPSZ + idx] = acc;
}

__global__ void passB(const float2* __restrict__ Pin, float2* __restrict__ Pout) {
  int cl = blockIdx.y;
  int idx = blockIdx.x * 256 + threadIdx.x;
  int v = idx % 20, u = (idx / 20) % 20, q = (idx / 400) % 16, p = idx / 6400;
  const float2* in = Pin + (size_t)cl * MAPSZ;
  float2 acc = make_float2(0.f, 0.f);
  for (int up = 0; up < 20; ++up) {
    float2 val = in[(p * 16 + q) * 400 + up * 20 + v];
    float ang = (TAU / 20.f) * (float)((u * up) % 20);
    float s, co;
    sincosf(ang, &s, &co);
    acc.x += val.x * co - val.y * s;
    acc.y += val.x * s + val.y * co;
  }
  Pout[(size_t)cl * MAPSZ + idx] = acc;
}

__global__ void passC(const float2* __restrict__ Pin, float2* __restrict__ Pout) {
  int cl = blockIdx.y;
  int idx = blockIdx.x * 256 + threadIdx.x;
  int v = idx % 20, u = (idx / 20) % 20, q = (idx / 400) % 16, p = idx / 6400;
  const float2* in = Pin + (size_t)cl * MAPSZ;
  float2 acc = make_float2(0.f, 0.f);
  for (int qp = 0; qp < 16; ++qp) {
    float2 val = in[(p * 16 + qp) * 400 + u * 20 + v];
    float ang = -(TAU / 16.f) * (float)((q * qp) % 16);
    float s, co;
    sincosf(ang, &s, &co);
    acc.x += val.x * co - val.y * s;
    acc.y += val.x * s + val.y * co;
  }
  Pout[(size_t)cl * MAPSZ + idx] = acc;
}

// passD: final DFT, write split-bf16 m directly into padded [n][KOUT] planes
__global__ void passD(const float2* __restrict__ Pin, __hip_bfloat16* __restrict__ ms, int c0) {
  int cl = blockIdx.y;
  int c = c0 + cl;
  int idx = blockIdx.x * 256 + threadIdx.x;
  int v = idx % 20, u = (idx / 20) % 20, q = (idx / 400) % 16, p = idx / 6400;
  const float2* in = Pin + (size_t)cl * MAPSZ;
  float acc = 0.f;
  for (int pp = 0; pp < 16; ++pp) {
    float2 val = in[(pp * 16 + q) * 400 + u * 20 + v];
    float ang = -(TAU / 16.f) * (float)((p * pp) % 16);
    float s, co;
    sincosf(ang, &s, &co);
    acc += val.x * co - val.y * s;
  }
  acc *= (1.f / 400.f);
  int n = c * 256 + idx / 400;          // o = p*16+q
  int k = idx % 400;                    // k = u*20+v
  __hip_bfloat16 h, l;
  bsplit(acc, h, l);
  ms[(size_t)n * KOUT + k] = h;
  ms[MPL + (size_t)n * KOUT + k] = l;
}

// zero the k in [400,416) pad of the m planes
__global__ void pad_m(__hip_bfloat16* __restrict__ ms) {
  int idx = blockIdx.x * 256 + threadIdx.x;   // 4096*16*2
  int p = idx >> 16;
  int rem = idx & 65535;
  int n = rem >> 4;
  int k = 400 + (rem & 15);
  ms[(size_t)p * MPL + (size_t)n * KOUT + k] = __float2bfloat16(0.f);
}

// convert x (8192x400 f32) to split bf16 padded [2][8192][KOUT]
__global__ void prep_x(const float* __restrict__ x, __hip_bfloat16* __restrict__ xs) {
  int idx = blockIdx.x * 256 + threadIdx.x;   // 8192*52
  if (idx >= 8192 * 52) return;
  int b = idx / 52, c8 = idx % 52;
  int k = c8 * 8;
  short8 hh = {}, ll = {};
  if (k < 400) {
    const float4* xp = (const float4*)(x + (size_t)b * 400 + k);
    float4 v0 = xp[0], v1 = xp[1];
    float vals[8] = {v0.x, v0.y, v0.z, v0.w, v1.x, v1.y, v1.z, v1.w};
#pragma unroll
    for (int i = 0; i < 8; ++i) {
      __hip_bfloat16 h, l;
      bsplit(vals[i], h, l);
      hh[i] = braw(h);
      ll[i] = braw(l);
    }
  }
  *(short8*)(xs + (size_t)b * KOUT + k) = hh;
  *(short8*)(xs + XPL + (size_t)b * KOUT + k) = ll;
}

// ---------------- Stage 5: output GEMM, split-bf16 MFMA, 128x128 tile ----------------
__global__ __launch_bounds__(512, 2) void out_mfma(
    const __hip_bfloat16* __restrict__ xs, const __hip_bfloat16* __restrict__ ms,
    float* __restrict__ Y) {
  __shared__ char lds[2][32768];   // A planes @0 (2*8192), B planes @16384
  const int t = threadIdx.x;
  const int lane = t & 63;
  const int wid = t >> 6;
  const int wm = wid >> 2, wn = wid & 3;
  const int rowBase = blockIdx.y * 128, colBase = blockIdx.x * 128;

  size_t gA[2], gB[2];
  int ldsOff[2];
#pragma unroll
  for (int i = 0; i < 2; ++i) {
    int cid = i * 512 + t;
    int p = cid >> 9, r = (cid >> 2) & 127, cp = cid & 3;
    int cg = cp ^ ((r >> 1) & 3);
    gA[i] = (size_t)p * XPL + (size_t)(rowBase + r) * KOUT + cg * 8;
    gB[i] = (size_t)p * MPL + (size_t)(colBase + r) * KOUT + cg * 8;
    ldsOff[i] = cid * 16;
  }
  int aoff[4], boff[2];
#pragma unroll
  for (int mi = 0; mi < 4; ++mi) {
    int ra = wm * 64 + mi * 16 + (lane & 15);
    int ch = (lane >> 4) ^ ((ra >> 1) & 3);
    aoff[mi] = (ra * 4 + ch) * 16;
  }
#pragma unroll
  for (int ni = 0; ni < 2; ++ni) {
    int cb = wn * 32 + ni * 16 + (lane & 15);
    int ch = (lane >> 4) ^ ((cb >> 1) & 3);
    boff[ni] = 16384 + (cb * 4 + ch) * 16;
  }

  f32x4 acc[4][2] = {};

  auto STAGE = [&](int buf, int k0) {
#pragma unroll
    for (int i = 0; i < 2; ++i) {
      gld16(xs + gA[i] + k0, &lds[buf][ldsOff[i]]);
      gld16(ms + gB[i] + k0, &lds[buf][16384 + ldsOff[i]]);
    }
  };

  auto COMPUTE = [&](int cur) {
    short8 ah[4], al[4], bh[2], bl[2];
#pragma unroll
    for (int mi = 0; mi < 4; ++mi) {
      const char* base = &lds[cur][aoff[mi]];
      ah[mi] = *(const short8*)(base);
      al[mi] = *(const short8*)(base + 8192);
    }
#pragma unroll
    for (int ni = 0; ni < 2; ++ni) {
      const char* base = &lds[cur][boff[ni]];
      bh[ni] = *(const short8*)(base);
      bl[ni] = *(const short8*)(base + 8192);
    }
    __builtin_amdgcn_s_setprio(1);
#pragma unroll
    for (int mi = 0; mi < 4; ++mi)
#pragma unroll
      for (int ni = 0; ni < 2; ++ni) {
        acc[mi][ni] = MFMA16(ah[mi], bh[ni], acc[mi][ni]);
        acc[mi][ni] = MFMA16(ah[mi], bl[ni], acc[mi][ni]);
        acc[mi][ni] = MFMA16(al[mi], bh[ni], acc[mi][ni]);
      }
    __builtin_amdgcn_s_setprio(0);
  };

  STAGE(0, 0);
#pragma unroll 1
  for (int ks = 0; ks < 12; ++ks) {
    int cur = ks & 1;
    STAGE(cur ^ 1, (ks + 1) * 32);
    asm volatile("s_waitcnt vmcnt(4)" ::: "memory");
    __builtin_amdgcn_s_barrier();
    __builtin_amdgcn_sched_barrier(0);
    COMPUTE(cur);
    __builtin_amdgcn_s_barrier();
  }
  asm volatile("s_waitcnt vmcnt(0)" ::: "memory");
  __builtin_amdgcn_s_barrier();
  __builtin_amdgcn_sched_barrier(0);
  COMPUTE(0);

#pragma unroll
  for (int mi = 0; mi < 4; ++mi)
#pragma unroll
    for (int ni = 0; ni < 2; ++ni) {
      int rb = rowBase + wm * 64 + mi * 16 + (lane >> 4) * 4;
      int cc = colBase + wn * 32 + ni * 16 + (lane & 15);
#pragma unroll
      for (int j = 0; j < 4; ++j)
        Y[(size_t)(rb + j) * 4096 + cc] = acc[mi][ni][j];
    }
}

// ---------------- Launcher ----------------
extern "C" void kernel_launch(void* const* d_in, const int* in_sizes, int n_in,
                              void* d_out, int out_size, void* d_ws, size_t ws_size,
                              hipStream_t stream) {
  const float* x = (const float*)d_in[0];     // (8192,1,20,20)
  const float* sig = (const float*)d_in[1];   // (16,2,24,24)
  float* out = (float*)d_out;                 // (8192,16,16,16)
  char* ws = (char*)d_ws;

  const size_t specBytes = 32ull * 576 * sizeof(float2);
  const size_t xsBytes = 2ull * XPL * 2;
  const size_t msBytes = 2ull * MPL * 2;
  const size_t fixed = specBytes + xsBytes + msBytes;
  const size_t setB = SETSTR * 2;                       // bytes per split set
  const size_t perCh = 5 * setB + 2ull * MAPSZ * 8;     // B, X0, X0T, X1, X1T + P0/P1

  int cg = 1;
  if (ws_size > fixed) {
    size_t av = (ws_size - fixed) / perCh;
    cg = (av < 1) ? 1 : (av > 16 ? 16 : (int)av);
  }

  float2* spec = (float2*)ws;
  __hip_bfloat16* xs = (__hip_bfloat16*)(ws + specBytes);
  __hip_bfloat16* ms = (__hip_bfloat16*)(ws + specBytes + xsBytes);
  __hip_bfloat16* Bst = (__hip_bfloat16*)(ws + fixed);
  __hip_bfloat16* X0 = Bst + (size_t)cg * SETSTR;
  __hip_bfloat16* X0T = X0 + (size_t)cg * SETSTR;
  __hip_bfloat16* X1 = X0T + (size_t)cg * SETSTR;
  __hip_bfloat16* X1T = X1 + (size_t)cg * SETSTR;
  float2* P0 = (float2*)(X1T + (size_t)cg * SETSTR);
  float2* P1 = P0 + (size_t)cg * MAPSZ;

  spectrum_kernel<<<dim3(32), dim3(576), 0, stream>>>(sig, spec);
  prep_x<<<dim3((8192 * 52 + 255) / 256), dim3(256), 0, stream>>>(x, xs);
  pad_m<<<dim3(512), dim3(256), 0, stream>>>(ms);

  const float scale = 1.f / 256.f;  // s = 8 squarings
  for (int c0 = 0; c0 < 16; c0 += cg) {
    int g = (16 - c0 < cg) ? (16 - c0) : cg;
    buildBX<<<dim3(1296, g), dim3(256), 0, stream>>>(spec, Bst, X0, c0, scale);
    transpose4<<<dim3(9, 9, g), dim3(256), 0, stream>>>(X0, X0T);
    __hip_bfloat16 *xr = X0, *xt = X0T, *yr = X1, *yt = X1T;
    // Horner (Taylor order 5): X <- I + (B*X)/k, k=4..1. Only DT consumed until k=1.
    for (int k = 4; k >= 1; --k) {
      int wf = (k == 1) ? 3 : 2;
      cgemm_mfma<<<dim3(25 * g), dim3(512), 0, stream>>>(Bst, xt, yr, yt,
                                                         1.f / (float)k, 1.f, wf);
      __hip_bfloat16* tmp;
      tmp = xr; xr = yr; yr = tmp;
      tmp = xt; xt = yt; yt = tmp;
    }
    // 8 squarings; last one only needs row-major output (feeds passA)
    for (int t8 = 0; t8 < 8; ++t8) {
      int wf = (t8 == 7) ? 1 : 3;
      cgemm_mfma<<<dim3(25 * g), dim3(512), 0, stream>>>(xr, xt, yr, yt, 1.f, 0.f, wf);
      __hip_bfloat16* tmp;
      tmp = xr; xr = yr; yr = tmp;
      tmp = xt; xt = yt; yt = tmp;
    }
    passA<<<dim3(400, g), dim3(256), 0, stream>>>(xr, P0);
    passB<<<dim3(400, g), dim3(256), 0, stream>>>(P0, P1);
    passC<<<dim3(400, g), dim3(256), 0, stream>>>(P1, P0);
    passD<<<dim3(400, g), dim3(256), 0, stream>>>(P0, ms, c0);
  }

  out_mfma<<<dim3(32, 64), dim3(512), 0, stream>>>(xs, ms, out);
}

// Round 7
// 1285.516 us; speedup vs baseline: 5.1523x; 1.5447x over previous
//
#include <hip/hip_runtime.h>
#include <hip/hip_bf16.h>
#include <math.h>

#define TAU 6.283185307179586f
#define NK 576                    // matrix dimension (K always exact: 18*32)
#define NPAD 640                  // padded row count for 128-row tiles
#define PLN ((size_t)NPAD * NK)   // elems per padded plane = 368640
#define SETSTR ((size_t)4 * PLN)  // elems per 4-plane split set
#define MAPSZ 102400              // 16*16*20*20
#define KOUT 416                  // padded K for output gemm (13*32)
#define XPL ((size_t)8192 * KOUT)
#define MPL ((size_t)4096 * KOUT)

typedef __attribute__((ext_vector_type(8))) short short8;
typedef __attribute__((ext_vector_type(4))) short short4v;
typedef __attribute__((ext_vector_type(4))) float f32x4;

__device__ inline void bsplit(float v, __hip_bfloat16& h, __hip_bfloat16& l) {
  h = __float2bfloat16(v);
  l = __float2bfloat16(v - __bfloat162float(h));
}
__device__ inline short braw(__hip_bfloat16 b) { return *reinterpret_cast<short*>(&b); }

__device__ inline void gld16(const void* g, const void* l) {
  __builtin_amdgcn_global_load_lds((const __attribute__((address_space(1))) unsigned*)g,
                                   (__attribute__((address_space(3))) unsigned*)l, 16, 0, 0);
}

#define MFMA16(a, b, c) __builtin_amdgcn_mfma_f32_16x16x32_bf16(a, b, c, 0, 0, 0)

// ---------------- Stage 1: signal -> spectrum ----------------
__device__ inline void dft24(const float2* in, float2* out, int t, float sgn, bool firstAxis) {
  int r = t / 24, c = t % 24;
  int kk = firstAxis ? r : c;
  float2 acc = make_float2(0.f, 0.f);
  for (int n = 0; n < 24; ++n) {
    float ang = sgn * (TAU / 24.f) * (float)((kk * n) % 24);
    float s, co;
    sincosf(ang, &s, &co);
    float2 v = firstAxis ? in[n * 24 + c] : in[r * 24 + n];
    acc.x += v.x * co - v.y * s;
    acc.y += v.x * s + v.y * co;
  }
  out[t] = acc;
}

__global__ void spectrum_kernel(const float* __restrict__ sig, float2* __restrict__ spec) {
  __shared__ float2 b0[576];
  __shared__ float2 b1[576];
  int f = blockIdx.x;
  int t = threadIdx.x;
  int r = t / 24, c = t % 24;
  b0[t] = make_float2(sig[f * 576 + t], 0.f);
  __syncthreads();
  dft24(b0, b1, t, -1.f, false); __syncthreads();
  dft24(b1, b0, t, -1.f, true);  __syncthreads();
  {
    int p2 = (r + 12) % 24 - 11;
    int q2 = (c + 12) % 24 - 11;
    float rr = (float)(1 + p2 * p2 + q2 * q2) * 5.f;
    float2 v = b0[t];
    b0[t] = make_float2(v.x / rr, v.y / rr);
  }
  __syncthreads();
  dft24(b0, b1, t, +1.f, false); __syncthreads();
  dft24(b1, b0, t, +1.f, true);  __syncthreads();
  {
    float winr = 0.5f * (1.f - cosf(TAU * (float)r / 24.f));
    float winc = 0.5f * (1.f - cosf(TAU * (float)c / 24.f));
    float w = winr * winc * (1.f / 576.f);
    float2 v = b0[t];
    b0[t] = make_float2(v.x * w, v.y * w);
  }
  __syncthreads();
  dft24(b0, b1, t, -1.f, false); __syncthreads();
  dft24(b1, b0, t, -1.f, true);  __syncthreads();
  int p = (r + 12) % 24, q = (c + 12) % 24;
  spec[f * 576 + p * 24 + q] = b0[t];
}

// ---------------- Stage 2: build split B and X0 = I + B/5 ----------------
__global__ void buildBX(const float2* __restrict__ spec, __hip_bfloat16* __restrict__ B,
                        __hip_bfloat16* __restrict__ X0, int c0, float scale) {
  int idx = blockIdx.x * 256 + threadIdx.x;   // 0..331775 (row*576+col, row<576)
  int cl = blockIdx.y;
  int c = c0 + cl;
  int row = idx / NK, col = idx % NK;
  int i = row / 24, j = row % 24, a = col / 24, b = col % 24;
  int u = 11 - i + a, v = 11 - j + b;
  float br = 0.f, bi = 0.f;
  if (u >= 0 && u < 24 && v >= 0 && v < 24) {
    float2 s0 = spec[(c * 2 + 0) * 576 + u * 24 + v];
    float2 s1 = spec[(c * 2 + 1) * 576 + u * 24 + v];
    float kx = (float)(a - 11), ky = (float)(b - 11);
    float xr = s0.x * kx + s1.x * ky;
    float xi = s0.y * kx + s1.y * ky;
    br = xi * scale;
    bi = -xr * scale;
  }
  size_t off = (size_t)cl * SETSTR + idx;
  __hip_bfloat16 h, l;
  bsplit(br, h, l); B[off] = h; B[off + PLN] = l;
  bsplit(bi, h, l); B[off + 2 * PLN] = h; B[off + 3 * PLN] = l;
  float d = (row == col) ? 1.f : 0.f;
  bsplit(br * (1.f / 5.f) + d, h, l); X0[off] = h; X0[off + PLN] = l;
  bsplit(bi * (1.f / 5.f), h, l);     X0[off + 2 * PLN] = h; X0[off + 3 * PLN] = l;
}

// ---------------- transpose the 4 split planes ----------------
__global__ __launch_bounds__(256) void transpose4(const __hip_bfloat16* __restrict__ src,
                                                  __hip_bfloat16* __restrict__ dst) {
  __shared__ __hip_bfloat16 tile[64][65];
  int cl = blockIdx.z;
  size_t off = (size_t)cl * SETSTR;
  int rB = blockIdx.y * 64, cB = blockIdx.x * 64;
  int tx = threadIdx.x & 63, ty = threadIdx.x >> 6;
  for (int p = 0; p < 4; ++p) {
    for (int li = 0; li < 16; ++li) {
      int r = ty * 16 + li;
      tile[r][tx] = src[off + (size_t)p * PLN + (size_t)(rB + r) * NK + cB + tx];
    }
    __syncthreads();
    for (int li = 0; li < 16; ++li) {
      int r = ty * 16 + li;
      dst[off + (size_t)p * PLN + (size_t)(cB + r) * NK + rB + tx] = tile[tx][r];
    }
    __syncthreads();
  }
}

// ---------------- Stage 3: batched split-complex MFMA GEMM, 128x128 tile ----------------
// D = alpha*(A*B) + delta*I.  A row-major [m][k] split planes; B given as BT [n][k].
// wf bit0: write D (row-major); bit1: write DT (transposed).
// 4-phase K-step (m201 schedule): per phase {ds_read A-subtile || issue staging ->
// s_barrier -> lgkmcnt(0)+sched_barrier -> setprio(1) MFMA cluster setprio(0) -> s_barrier}.
// Staged loads for tile ks+1 stay in flight across the phases of tile ks.
__global__ __launch_bounds__(512, 2) void cgemm_mfma(
    const __hip_bfloat16* __restrict__ A, const __hip_bfloat16* __restrict__ BT,
    __hip_bfloat16* __restrict__ D, __hip_bfloat16* __restrict__ DT,
    float alpha, float delta, int wf) {
  __shared__ char lds[2][65536];   // per buf: A planes @0 (4*8192), B planes @32768
  const int t = threadIdx.x;
  const int lane = t & 63;
  const int wid = t >> 6;
  const int wm = wid >> 2, wn = wid & 3;          // 2 x 4 waves, wave tile 64x32
  // block remap: XCD-local channels when full 16-channel group
  int p0 = blockIdx.x;
  int cl, tile;
  if (gridDim.x == 400) {
    cl = (p0 & 7) + ((p0 >> 3) / 25) * 8;
    tile = (p0 >> 3) % 25;
  } else {
    cl = p0 / 25;
    tile = p0 % 25;
  }
  const int rowBase = (tile / 5) * 128, colBase = (tile % 5) * 128;
  const size_t chOff = (size_t)cl * SETSTR;
  const __hip_bfloat16* Ab = A + chOff;
  const __hip_bfloat16* Bb = BT + chOff;

  // staging: 2048 16B-chunks per operand; cid = i*512+t -> plane p, row r, phys chunk cp
  size_t gA[4], gB[4];
  int ldsOff[4];
#pragma unroll
  for (int i = 0; i < 4; ++i) {
    int cid = i * 512 + t;
    int pp = cid >> 9, r = (cid >> 2) & 127, cp = cid & 3;
    int cg = cp ^ ((r >> 1) & 3);
    gA[i] = (size_t)pp * PLN + (size_t)(rowBase + r) * NK + cg * 8;
    gB[i] = (size_t)pp * PLN + (size_t)(colBase + r) * NK + cg * 8;
    ldsOff[i] = cid * 16;
  }
  // fragment read offsets
  int aoff[4], boff[2];
#pragma unroll
  for (int mi = 0; mi < 4; ++mi) {
    int ra = wm * 64 + mi * 16 + (lane & 15);
    int ch = (lane >> 4) ^ ((ra >> 1) & 3);
    aoff[mi] = (ra * 4 + ch) * 16;
  }
#pragma unroll
  for (int ni = 0; ni < 2; ++ni) {
    int cb = wn * 32 + ni * 16 + (lane & 15);
    int ch = (lane >> 4) ^ ((cb >> 1) & 3);
    boff[ni] = 32768 + (cb * 4 + ch) * 16;
  }

  f32x4 accP[4][2] = {}, accN[4][2] = {}, accI[4][2] = {};
  short8 brh[2], brl[2], bih[2], bil[2];   // B fragments live across the 4 phases

  auto STAGE2 = [&](int buf, int k0, int i) {
    gld16(Ab + gA[i] + k0, &lds[buf][ldsOff[i]]);
    gld16(Bb + gB[i] + k0, &lds[buf][32768 + ldsOff[i]]);
  };

  // prologue: tile 0 into buf 0
#pragma unroll
  for (int i = 0; i < 4; ++i) STAGE2(0, 0, i);

#pragma unroll 1
  for (int ks = 0; ks < 18; ++ks) {
    const int cur = ks & 1;
    asm volatile("s_waitcnt vmcnt(0)" ::: "memory");   // tile ks landed (issued >=2 phases ago)
    __builtin_amdgcn_s_barrier();
#pragma unroll
    for (int p = 0; p < 4; ++p) {
      short8 arh, arl, aih, ail;
      {
        const char* base = &lds[cur][aoff[p]];
        arh = *(const short8*)(base);
        arl = *(const short8*)(base + 8192);
        aih = *(const short8*)(base + 16384);
        ail = *(const short8*)(base + 24576);
      }
      if (p == 0) {
#pragma unroll
        for (int ni = 0; ni < 2; ++ni) {
          const char* base = &lds[cur][boff[ni]];
          brh[ni] = *(const short8*)(base);
          brl[ni] = *(const short8*)(base + 8192);
          bih[ni] = *(const short8*)(base + 16384);
          bil[ni] = *(const short8*)(base + 24576);
        }
      }
      if (ks < 17 && p < 2) {          // issue next-tile staging in phases 0,1
        STAGE2(cur ^ 1, (ks + 1) * 32, 2 * p);
        STAGE2(cur ^ 1, (ks + 1) * 32, 2 * p + 1);
      }
      __builtin_amdgcn_s_barrier();
      asm volatile("s_waitcnt lgkmcnt(0)" ::: "memory");
      __builtin_amdgcn_sched_barrier(0);
      __builtin_amdgcn_s_setprio(1);
#pragma unroll
      for (int ni = 0; ni < 2; ++ni) {
        accP[p][ni] = MFMA16(arh, brh[ni], accP[p][ni]);
        accP[p][ni] = MFMA16(arh, brl[ni], accP[p][ni]);
        accP[p][ni] = MFMA16(arl, brh[ni], accP[p][ni]);
        accN[p][ni] = MFMA16(aih, bih[ni], accN[p][ni]);
        accN[p][ni] = MFMA16(aih, bil[ni], accN[p][ni]);
        accN[p][ni] = MFMA16(ail, bih[ni], accN[p][ni]);
        accI[p][ni] = MFMA16(arh, bih[ni], accI[p][ni]);
        accI[p][ni] = MFMA16(arh, bil[ni], accI[p][ni]);
        accI[p][ni] = MFMA16(arl, bih[ni], accI[p][ni]);
        accI[p][ni] = MFMA16(aih, brh[ni], accI[p][ni]);
        accI[p][ni] = MFMA16(aih, brl[ni], accI[p][ni]);
        accI[p][ni] = MFMA16(ail, brh[ni], accI[p][ni]);
      }
      __builtin_amdgcn_s_setprio(0);
      __builtin_amdgcn_s_barrier();
    }
  }

  __hip_bfloat16* Dp = D + chOff;
  __hip_bfloat16* Tp = DT + chOff;
#pragma unroll
  for (int mi = 0; mi < 4; ++mi)
#pragma unroll
    for (int ni = 0; ni < 2; ++ni) {
      int rb = rowBase + wm * 64 + mi * 16 + (lane >> 4) * 4;
      int cc = colBase + wn * 32 + ni * 16 + (lane & 15);
      if (cc >= NK || rb >= NK) continue;   // rb % 4 == 0, NK % 4 == 0 -> whole quad valid
      short hR[4], lR[4], hI[4], lI[4];
#pragma unroll
      for (int j = 0; j < 4; ++j) {
        float vR = alpha * (accP[mi][ni][j] - accN[mi][ni][j]) + ((rb + j == cc) ? delta : 0.f);
        float vI = alpha * accI[mi][ni][j];
        __hip_bfloat16 h, l;
        bsplit(vR, h, l); hR[j] = braw(h); lR[j] = braw(l);
        bsplit(vI, h, l); hI[j] = braw(h); lI[j] = braw(l);
      }
      if (wf & 1) {
#pragma unroll
        for (int j = 0; j < 4; ++j) {
          size_t o = (size_t)(rb + j) * NK + cc;
          *(short*)&Dp[o] = hR[j];
          *(short*)&Dp[PLN + o] = lR[j];
          *(short*)&Dp[2 * PLN + o] = hI[j];
          *(short*)&Dp[3 * PLN + o] = lI[j];
        }
      }
      if (wf & 2) {
        size_t o = (size_t)cc * NK + rb;
        short4v vR4 = {hR[0], hR[1], hR[2], hR[3]};
        short4v vL4 = {lR[0], lR[1], lR[2], lR[3]};
        short4v vI4 = {hI[0], hI[1], hI[2], hI[3]};
        short4v vJ4 = {lI[0], lI[1], lI[2], lI[3]};
        *(short4v*)&Tp[o] = vR4;
        *(short4v*)&Tp[PLN + o] = vL4;
        *(short4v*)&Tp[2 * PLN + o] = vI4;
        *(short4v*)&Tp[3 * PLN + o] = vJ4;
      }
    }
}

// ---------------- Stage 4: slice + roll + separable DFTs ----------------
__global__ void passA(const __hip_bfloat16* __restrict__ X, float2* __restrict__ P) {
  int cl = blockIdx.y;
  int idx = blockIdx.x * 256 + threadIdx.x;
  int v = idx % 20, u = (idx / 20) % 20, q = (idx / 400) % 16, p = idx / 6400;
  int pp = (p + 7) % 16;
  int qq = (q + 7) % 16;
  int row = (pp + 5) * 24 + (qq + 5);
  int uu = (u + 9) % 20;
  int aa = uu + 3;
  const __hip_bfloat16* tb = X + (size_t)cl * SETSTR;
  float2 acc = make_float2(0.f, 0.f);
  for (int vp = 0; vp < 20; ++vp) {
    int vv = (vp + 9) % 20;
    int col = aa * 24 + (vv + 3);
    size_t o = (size_t)row * NK + col;
    float xr = __bfloat162float(tb[o]) + __bfloat162float(tb[PLN + o]);
    float xi = __bfloat162float(tb[2 * PLN + o]) + __bfloat162float(tb[3 * PLN + o]);
    float ang = (TAU / 20.f) * (float)((v * vp) % 20);
    float s, co;
    sincosf(ang, &s, &co);
    acc.x += xr * co - xi * s;
    acc.y += xr * s + xi * co;
  }
  P[(size_t)cl * MAPSZ + idx] = acc;
}

__global__ void passB(const float2* __restrict__ Pin, float2* __restrict__ Pout) {
  int cl = blockIdx.y;
  int idx = blockIdx.x * 256 + threadIdx.x;
  int v = idx % 20, u = (idx / 20) % 20, q = (idx / 400) % 16, p = idx / 6400;
  const float2* in = Pin + (size_t)cl * MAPSZ;
  float2 acc = make_float2(0.f, 0.f);
  for (int up = 0; up < 20; ++up) {
    float2 val = in[(p * 16 + q) * 400 + up * 20 + v];
    float ang = (TAU / 20.f) * (float)((u * up) % 20);
    float s, co;
    sincosf(ang, &s, &co);
    acc.x += val.x * co - val.y * s;
    acc.y += val.x * s + val.y * co;
  }
  Pout[(size_t)cl * MAPSZ + idx] = acc;
}

__global__ void passC(const float2* __restrict__ Pin, float2* __restrict__ Pout) {
  int cl = blockIdx.y;
  int idx = blockIdx.x * 256 + threadIdx.x;
  int v = idx % 20, u = (idx / 20) % 20, q = (idx / 400) % 16, p = idx / 6400;
  const float2* in = Pin + (size_t)cl * MAPSZ;
  float2 acc = make_float2(0.f, 0.f);
  for (int qp = 0; qp < 16; ++qp) {
    float2 val = in[(p * 16 + qp) * 400 + u * 20 + v];
    float ang = -(TAU / 16.f) * (float)((q * qp) % 16);
    float s, co;
    sincosf(ang, &s, &co);
    acc.x += val.x * co - val.y * s;
    acc.y += val.x * s + val.y * co;
  }
  Pout[(size_t)cl * MAPSZ + idx] = acc;
}

// passD: final DFT, write split-bf16 m directly into padded [n][KOUT] planes
__global__ void passD(const float2* __restrict__ Pin, __hip_bfloat16* __restrict__ ms, int c0) {
  int cl = blockIdx.y;
  int c = c0 + cl;
  int idx = blockIdx.x * 256 + threadIdx.x;
  int v = idx % 20, u = (idx / 20) % 20, q = (idx / 400) % 16, p = idx / 6400;
  const float2* in = Pin + (size_t)cl * MAPSZ;
  float acc = 0.f;
  for (int pp = 0; pp < 16; ++pp) {
    float2 val = in[(pp * 16 + q) * 400 + u * 20 + v];
    float ang = -(TAU / 16.f) * (float)((p * pp) % 16);
    float s, co;
    sincosf(ang, &s, &co);
    acc += val.x * co - val.y * s;
  }
  acc *= (1.f / 400.f);
  int n = c * 256 + idx / 400;          // o = p*16+q
  int k = idx % 400;                    // k = u*20+v
  __hip_bfloat16 h, l;
  bsplit(acc, h, l);
  ms[(size_t)n * KOUT + k] = h;
  ms[MPL + (size_t)n * KOUT + k] = l;
}

// zero the k in [400,416) pad of the m planes
__global__ void pad_m(__hip_bfloat16* __restrict__ ms) {
  int idx = blockIdx.x * 256 + threadIdx.x;   // 4096*16*2
  int p = idx >> 16;
  int rem = idx & 65535;
  int n = rem >> 4;
  int k = 400 + (rem & 15);
  ms[(size_t)p * MPL + (size_t)n * KOUT + k] = __float2bfloat16(0.f);
}

// convert x (8192x400 f32) to split bf16 padded [2][8192][KOUT]
__global__ void prep_x(const float* __restrict__ x, __hip_bfloat16* __restrict__ xs) {
  int idx = blockIdx.x * 256 + threadIdx.x;   // 8192*52
  if (idx >= 8192 * 52) return;
  int b = idx / 52, c8 = idx % 52;
  int k = c8 * 8;
  short8 hh = {}, ll = {};
  if (k < 400) {
    const float4* xp = (const float4*)(x + (size_t)b * 400 + k);
    float4 v0 = xp[0], v1 = xp[1];
    float vals[8] = {v0.x, v0.y, v0.z, v0.w, v1.x, v1.y, v1.z, v1.w};
#pragma unroll
    for (int i = 0; i < 8; ++i) {
      __hip_bfloat16 h, l;
      bsplit(vals[i], h, l);
      hh[i] = braw(h);
      ll[i] = braw(l);
    }
  }
  *(short8*)(xs + (size_t)b * KOUT + k) = hh;
  *(short8*)(xs + XPL + (size_t)b * KOUT + k) = ll;
}

// ---------------- Stage 5: output GEMM, split-bf16 MFMA, 128x128 tile ----------------
__global__ __launch_bounds__(512, 2) void out_mfma(
    const __hip_bfloat16* __restrict__ xs, const __hip_bfloat16* __restrict__ ms,
    float* __restrict__ Y) {
  __shared__ char lds[2][32768];   // A planes @0 (2*8192), B planes @16384
  const int t = threadIdx.x;
  const int lane = t & 63;
  const int wid = t >> 6;
  const int wm = wid >> 2, wn = wid & 3;
  const int rowBase = blockIdx.y * 128, colBase = blockIdx.x * 128;

  size_t gA[2], gB[2];
  int ldsOff[2];
#pragma unroll
  for (int i = 0; i < 2; ++i) {
    int cid = i * 512 + t;
    int p = cid >> 9, r = (cid >> 2) & 127, cp = cid & 3;
    int cg = cp ^ ((r >> 1) & 3);
    gA[i] = (size_t)p * XPL + (size_t)(rowBase + r) * KOUT + cg * 8;
    gB[i] = (size_t)p * MPL + (size_t)(colBase + r) * KOUT + cg * 8;
    ldsOff[i] = cid * 16;
  }
  int aoff[4], boff[2];
#pragma unroll
  for (int mi = 0; mi < 4; ++mi) {
    int ra = wm * 64 + mi * 16 + (lane & 15);
    int ch = (lane >> 4) ^ ((ra >> 1) & 3);
    aoff[mi] = (ra * 4 + ch) * 16;
  }
#pragma unroll
  for (int ni = 0; ni < 2; ++ni) {
    int cb = wn * 32 + ni * 16 + (lane & 15);
    int ch = (lane >> 4) ^ ((cb >> 1) & 3);
    boff[ni] = 16384 + (cb * 4 + ch) * 16;
  }

  f32x4 acc[4][2] = {};

  auto STAGE = [&](int buf, int k0) {
#pragma unroll
    for (int i = 0; i < 2; ++i) {
      gld16(xs + gA[i] + k0, &lds[buf][ldsOff[i]]);
      gld16(ms + gB[i] + k0, &lds[buf][16384 + ldsOff[i]]);
    }
  };

  auto COMPUTE = [&](int cur) {
    short8 ah[4], al[4], bh[2], bl[2];
#pragma unroll
    for (int mi = 0; mi < 4; ++mi) {
      const char* base = &lds[cur][aoff[mi]];
      ah[mi] = *(const short8*)(base);
      al[mi] = *(const short8*)(base + 8192);
    }
#pragma unroll
    for (int ni = 0; ni < 2; ++ni) {
      const char* base = &lds[cur][boff[ni]];
      bh[ni] = *(const short8*)(base);
      bl[ni] = *(const short8*)(base + 8192);
    }
    __builtin_amdgcn_s_setprio(1);
#pragma unroll
    for (int mi = 0; mi < 4; ++mi)
#pragma unroll
      for (int ni = 0; ni < 2; ++ni) {
        acc[mi][ni] = MFMA16(ah[mi], bh[ni], acc[mi][ni]);
        acc[mi][ni] = MFMA16(ah[mi], bl[ni], acc[mi][ni]);
        acc[mi][ni] = MFMA16(al[mi], bh[ni], acc[mi][ni]);
      }
    __builtin_amdgcn_s_setprio(0);
  };

  STAGE(0, 0);
#pragma unroll 1
  for (int ks = 0; ks < 12; ++ks) {
    int cur = ks & 1;
    STAGE(cur ^ 1, (ks + 1) * 32);
    asm volatile("s_waitcnt vmcnt(4)" ::: "memory");
    __builtin_amdgcn_s_barrier();
    __builtin_amdgcn_sched_barrier(0);
    COMPUTE(cur);
    __builtin_amdgcn_s_barrier();
  }
  asm volatile("s_waitcnt vmcnt(0)" ::: "memory");
  __builtin_amdgcn_s_barrier();
  __builtin_amdgcn_sched_barrier(0);
  COMPUTE(0);

#pragma unroll
  for (int mi = 0; mi < 4; ++mi)
#pragma unroll
    for (int ni = 0; ni < 2; ++ni) {
      int rb = rowBase + wm * 64 + mi * 16 + (lane >> 4) * 4;
      int cc = colBase + wn * 32 + ni * 16 + (lane & 15);
#pragma unroll
      for (int j = 0; j < 4; ++j)
        Y[(size_t)(rb + j) * 4096 + cc] = acc[mi][ni][j];
    }
}

// ---------------- Launcher ----------------
extern "C" void kernel_launch(void* const* d_in, const int* in_sizes, int n_in,
                              void* d_out, int out_size, void* d_ws, size_t ws_size,
                              hipStream_t stream) {
  const float* x = (const float*)d_in[0];     // (8192,1,20,20)
  const float* sig = (const float*)d_in[1];   // (16,2,24,24)
  float* out = (float*)d_out;                 // (8192,16,16,16)
  char* ws = (char*)d_ws;

  const size_t specBytes = 32ull * 576 * sizeof(float2);
  const size_t xsBytes = 2ull * XPL * 2;
  const size_t msBytes = 2ull * MPL * 2;
  const size_t fixed = specBytes + xsBytes + msBytes;
  const size_t setB = SETSTR * 2;                       // bytes per split set
  const size_t perCh = 5 * setB + 2ull * MAPSZ * 8;     // B, X0, X0T, X1, X1T + P0/P1

  int cg = 1;
  if (ws_size > fixed) {
    size_t av = (ws_size - fixed) / perCh;
    cg = (av < 1) ? 1 : (av > 16 ? 16 : (int)av);
  }

  float2* spec = (float2*)ws;
  __hip_bfloat16* xs = (__hip_bfloat16*)(ws + specBytes);
  __hip_bfloat16* ms = (__hip_bfloat16*)(ws + specBytes + xsBytes);
  __hip_bfloat16* Bst = (__hip_bfloat16*)(ws + fixed);
  __hip_bfloat16* X0 = Bst + (size_t)cg * SETSTR;
  __hip_bfloat16* X0T = X0 + (size_t)cg * SETSTR;
  __hip_bfloat16* X1 = X0T + (size_t)cg * SETSTR;
  __hip_bfloat16* X1T = X1 + (size_t)cg * SETSTR;
  float2* P0 = (float2*)(X1T + (size_t)cg * SETSTR);
  float2* P1 = P0 + (size_t)cg * MAPSZ;

  spectrum_kernel<<<dim3(32), dim3(576), 0, stream>>>(sig, spec);
  prep_x<<<dim3((8192 * 52 + 255) / 256), dim3(256), 0, stream>>>(x, xs);
  pad_m<<<dim3(512), dim3(256), 0, stream>>>(ms);

  const float scale = 1.f / 64.f;  // s = 6 squarings
  for (int c0 = 0; c0 < 16; c0 += cg) {
    int g = (16 - c0 < cg) ? (16 - c0) : cg;
    buildBX<<<dim3(1296, g), dim3(256), 0, stream>>>(spec, Bst, X0, c0, scale);
    transpose4<<<dim3(9, 9, g), dim3(256), 0, stream>>>(X0, X0T);
    __hip_bfloat16 *xr = X0, *xt = X0T, *yr = X1, *yt = X1T;
    // Horner (Taylor order 5): X <- I + (B*X)/k, k=4..1. Only DT consumed until k=1.
    for (int k = 4; k >= 1; --k) {
      int wf = (k == 1) ? 3 : 2;
      cgemm_mfma<<<dim3(25 * g), dim3(512), 0, stream>>>(Bst, xt, yr, yt,
                                                         1.f / (float)k, 1.f, wf);
      __hip_bfloat16* tmp;
      tmp = xr; xr = yr; yr = tmp;
      tmp = xt; xt = yt; yt = tmp;
    }
    // 6 squarings; last one only needs row-major output (feeds passA)
    for (int t8 = 0; t8 < 6; ++t8) {
      int wf = (t8 == 5) ? 1 : 3;
      cgemm_mfma<<<dim3(25 * g), dim3(512), 0, stream>>>(xr, xt, yr, yt, 1.f, 0.f, wf);
      __hip_bfloat16* tmp;
      tmp = xr; xr = yr; yr = tmp;
      tmp = xt; xt = yt; yt = tmp;
    }
    passA<<<dim3(400, g), dim3(256), 0, stream>>>(xr, P0);
    passB<<<dim3(400, g), dim3(256), 0, stream>>>(P0, P1);
    passC<<<dim3(400, g), dim3(256), 0, stream>>>(P1, P0);
    passD<<<dim3(400, g), dim3(256), 0, stream>>>(P0, ms, c0);
  }

  out_mfma<<<dim3(32, 64), dim3(512), 0, stream>>>(xs, ms, out);
}

// Round 8
// 1240.805 us; speedup vs baseline: 5.3380x; 1.0360x over previous
//
#include <hip/hip_runtime.h>
#include <hip/hip_bf16.h>
#include <math.h>

#define TAU 6.283185307179586f
#define NK 576                    // matrix dimension (K always exact: 18*32)
#define NPAD 640                  // padded row count for 128-row tiles
#define PLN ((size_t)NPAD * NK)   // elems per padded plane = 368640
#define SETSTR ((size_t)4 * PLN)  // elems per 4-plane split set
#define MAPSZ 102400              // 16*16*20*20
#define KOUT 416                  // padded K for output gemm (13*32)
#define XPL ((size_t)8192 * KOUT)
#define MPL ((size_t)4096 * KOUT)

typedef __attribute__((ext_vector_type(8))) short short8;
typedef __attribute__((ext_vector_type(4))) short short4v;
typedef __attribute__((ext_vector_type(4))) float f32x4;

__device__ inline void bsplit(float v, __hip_bfloat16& h, __hip_bfloat16& l) {
  h = __float2bfloat16(v);
  l = __float2bfloat16(v - __bfloat162float(h));
}
__device__ inline short braw(__hip_bfloat16 b) { return *reinterpret_cast<short*>(&b); }

__device__ inline void gld16(const void* g, const void* l) {
  __builtin_amdgcn_global_load_lds((const __attribute__((address_space(1))) unsigned*)g,
                                   (__attribute__((address_space(3))) unsigned*)l, 16, 0, 0);
}

#define MFMA16(a, b, c) __builtin_amdgcn_mfma_f32_16x16x32_bf16(a, b, c, 0, 0, 0)

// ---------------- Stage 1: signal -> spectrum ----------------
__device__ inline void dft24(const float2* in, float2* out, int t, float sgn, bool firstAxis) {
  int r = t / 24, c = t % 24;
  int kk = firstAxis ? r : c;
  float2 acc = make_float2(0.f, 0.f);
  for (int n = 0; n < 24; ++n) {
    float ang = sgn * (TAU / 24.f) * (float)((kk * n) % 24);
    float s, co;
    sincosf(ang, &s, &co);
    float2 v = firstAxis ? in[n * 24 + c] : in[r * 24 + n];
    acc.x += v.x * co - v.y * s;
    acc.y += v.x * s + v.y * co;
  }
  out[t] = acc;
}

__global__ void spectrum_kernel(const float* __restrict__ sig, float2* __restrict__ spec) {
  __shared__ float2 b0[576];
  __shared__ float2 b1[576];
  int f = blockIdx.x;
  int t = threadIdx.x;
  int r = t / 24, c = t % 24;
  b0[t] = make_float2(sig[f * 576 + t], 0.f);
  __syncthreads();
  dft24(b0, b1, t, -1.f, false); __syncthreads();
  dft24(b1, b0, t, -1.f, true);  __syncthreads();
  {
    int p2 = (r + 12) % 24 - 11;
    int q2 = (c + 12) % 24 - 11;
    float rr = (float)(1 + p2 * p2 + q2 * q2) * 5.f;
    float2 v = b0[t];
    b0[t] = make_float2(v.x / rr, v.y / rr);
  }
  __syncthreads();
  dft24(b0, b1, t, +1.f, false); __syncthreads();
  dft24(b1, b0, t, +1.f, true);  __syncthreads();
  {
    float winr = 0.5f * (1.f - cosf(TAU * (float)r / 24.f));
    float winc = 0.5f * (1.f - cosf(TAU * (float)c / 24.f));
    float w = winr * winc * (1.f / 576.f);
    float2 v = b0[t];
    b0[t] = make_float2(v.x * w, v.y * w);
  }
  __syncthreads();
  dft24(b0, b1, t, -1.f, false); __syncthreads();
  dft24(b1, b0, t, -1.f, true);  __syncthreads();
  int p = (r + 12) % 24, q = (c + 12) % 24;
  spec[f * 576 + p * 24 + q] = b0[t];
}

// ---------------- Stage 2: build split B and X0 = I + B/5 ----------------
__global__ void buildBX(const float2* __restrict__ spec, __hip_bfloat16* __restrict__ B,
                        __hip_bfloat16* __restrict__ X0, int c0, float scale) {
  int idx = blockIdx.x * 256 + threadIdx.x;   // 0..331775 (row*576+col, row<576)
  int cl = blockIdx.y;
  int c = c0 + cl;
  int row = idx / NK, col = idx % NK;
  int i = row / 24, j = row % 24, a = col / 24, b = col % 24;
  int u = 11 - i + a, v = 11 - j + b;
  float br = 0.f, bi = 0.f;
  if (u >= 0 && u < 24 && v >= 0 && v < 24) {
    float2 s0 = spec[(c * 2 + 0) * 576 + u * 24 + v];
    float2 s1 = spec[(c * 2 + 1) * 576 + u * 24 + v];
    float kx = (float)(a - 11), ky = (float)(b - 11);
    float xr = s0.x * kx + s1.x * ky;
    float xi = s0.y * kx + s1.y * ky;
    br = xi * scale;
    bi = -xr * scale;
  }
  size_t off = (size_t)cl * SETSTR + idx;
  __hip_bfloat16 h, l;
  bsplit(br, h, l); B[off] = h; B[off + PLN] = l;
  bsplit(bi, h, l); B[off + 2 * PLN] = h; B[off + 3 * PLN] = l;
  float d = (row == col) ? 1.f : 0.f;
  bsplit(br * (1.f / 5.f) + d, h, l); X0[off] = h; X0[off + PLN] = l;
  bsplit(bi * (1.f / 5.f), h, l);     X0[off + 2 * PLN] = h; X0[off + 3 * PLN] = l;
}

// ---------------- transpose the 4 split planes ----------------
__global__ __launch_bounds__(256) void transpose4(const __hip_bfloat16* __restrict__ src,
                                                  __hip_bfloat16* __restrict__ dst) {
  __shared__ __hip_bfloat16 tile[64][65];
  int cl = blockIdx.z;
  size_t off = (size_t)cl * SETSTR;
  int rB = blockIdx.y * 64, cB = blockIdx.x * 64;
  int tx = threadIdx.x & 63, ty = threadIdx.x >> 6;
  for (int p = 0; p < 4; ++p) {
    for (int li = 0; li < 16; ++li) {
      int r = ty * 16 + li;
      tile[r][tx] = src[off + (size_t)p * PLN + (size_t)(rB + r) * NK + cB + tx];
    }
    __syncthreads();
    for (int li = 0; li < 16; ++li) {
      int r = ty * 16 + li;
      dst[off + (size_t)p * PLN + (size_t)(cB + r) * NK + rB + tx] = tile[tx][r];
    }
    __syncthreads();
  }
}

// ---------------- Stage 3: batched split-complex MFMA GEMM, 128x128 tile ----------------
// D = alpha*(A*B) + delta*I.  A row-major [m][k] split planes; B given as BT [n][k].
// wf bit0: write D (row-major); bit1: write DT (transposed).
// ONE barrier per K-step: within a kstep all reads hit the stable buffer, so waves
// free-run (compiler emits counted lgkmcnt between ds_read and MFMA). vmcnt(0) at the
// top waits only tile-ks loads issued a full kstep earlier. sched_barrier(0) on both
// sides of the raw s_barrier pins LDS ops to their side.
__global__ __launch_bounds__(512, 2) void cgemm_mfma(
    const __hip_bfloat16* __restrict__ A, const __hip_bfloat16* __restrict__ BT,
    __hip_bfloat16* __restrict__ D, __hip_bfloat16* __restrict__ DT,
    float alpha, float delta, int wf) {
  __shared__ char lds[2][65536];   // per buf: A planes @0 (4*8192), B planes @32768
  const int t = threadIdx.x;
  const int lane = t & 63;
  const int wid = t >> 6;
  const int wm = wid >> 2, wn = wid & 3;          // 2 x 4 waves, wave tile 64x32
  // block remap: XCD-local channels when full 16-channel group
  int p0 = blockIdx.x;
  int cl, tile;
  if (gridDim.x == 400) {
    cl = (p0 & 7) + ((p0 >> 3) / 25) * 8;
    tile = (p0 >> 3) % 25;
  } else {
    cl = p0 / 25;
    tile = p0 % 25;
  }
  const int rowBase = (tile / 5) * 128, colBase = (tile % 5) * 128;
  const size_t chOff = (size_t)cl * SETSTR;
  const __hip_bfloat16* Ab = A + chOff;
  const __hip_bfloat16* Bb = BT + chOff;

  // staging: 2048 16B-chunks per operand; cid = i*512+t -> plane p, row r, phys chunk cp
  size_t gA[4], gB[4];
  int ldsOff[4];
#pragma unroll
  for (int i = 0; i < 4; ++i) {
    int cid = i * 512 + t;
    int pp = cid >> 9, r = (cid >> 2) & 127, cp = cid & 3;
    int cg = cp ^ ((r >> 1) & 3);
    gA[i] = (size_t)pp * PLN + (size_t)(rowBase + r) * NK + cg * 8;
    gB[i] = (size_t)pp * PLN + (size_t)(colBase + r) * NK + cg * 8;
    ldsOff[i] = cid * 16;
  }
  // fragment read offsets
  int aoff[4], boff[2];
#pragma unroll
  for (int mi = 0; mi < 4; ++mi) {
    int ra = wm * 64 + mi * 16 + (lane & 15);
    int ch = (lane >> 4) ^ ((ra >> 1) & 3);
    aoff[mi] = (ra * 4 + ch) * 16;
  }
#pragma unroll
  for (int ni = 0; ni < 2; ++ni) {
    int cb = wn * 32 + ni * 16 + (lane & 15);
    int ch = (lane >> 4) ^ ((cb >> 1) & 3);
    boff[ni] = 32768 + (cb * 4 + ch) * 16;
  }

  f32x4 accP[4][2] = {}, accN[4][2] = {}, accI[4][2] = {};

  auto STAGE2 = [&](int buf, int k0, int i) {
    gld16(Ab + gA[i] + k0, &lds[buf][ldsOff[i]]);
    gld16(Bb + gB[i] + k0, &lds[buf][32768 + ldsOff[i]]);
  };

  // prologue: tile 0 into buf 0
#pragma unroll
  for (int i = 0; i < 4; ++i) STAGE2(0, 0, i);

#pragma unroll 1
  for (int ks = 0; ks < 18; ++ks) {
    const int cur = ks & 1;
    asm volatile("s_waitcnt vmcnt(0)" ::: "memory");   // tile ks landed (issued last kstep)
    __builtin_amdgcn_sched_barrier(0);
    __builtin_amdgcn_s_barrier();                      // prev kstep reads done; buf cur valid
    __builtin_amdgcn_sched_barrier(0);

    short8 brh[2], brl[2], bih[2], bil[2];
#pragma unroll
    for (int ni = 0; ni < 2; ++ni) {
      const char* base = &lds[cur][boff[ni]];
      brh[ni] = *(const short8*)(base);
      brl[ni] = *(const short8*)(base + 8192);
      bih[ni] = *(const short8*)(base + 16384);
      bil[ni] = *(const short8*)(base + 24576);
    }
#pragma unroll
    for (int p = 0; p < 4; ++p) {
      short8 arh, arl, aih, ail;
      {
        const char* base = &lds[cur][aoff[p]];
        arh = *(const short8*)(base);
        arl = *(const short8*)(base + 8192);
        aih = *(const short8*)(base + 16384);
        ail = *(const short8*)(base + 24576);
      }
      if (ks < 17 && p < 2) {          // issue next-tile staging early
        STAGE2(cur ^ 1, (ks + 1) * 32, 2 * p);
        STAGE2(cur ^ 1, (ks + 1) * 32, 2 * p + 1);
      }
      __builtin_amdgcn_s_setprio(1);
#pragma unroll
      for (int ni = 0; ni < 2; ++ni) {
        accP[p][ni] = MFMA16(arh, brh[ni], accP[p][ni]);
        accP[p][ni] = MFMA16(arh, brl[ni], accP[p][ni]);
        accP[p][ni] = MFMA16(arl, brh[ni], accP[p][ni]);
        accN[p][ni] = MFMA16(aih, bih[ni], accN[p][ni]);
        accN[p][ni] = MFMA16(aih, bil[ni], accN[p][ni]);
        accN[p][ni] = MFMA16(ail, bih[ni], accN[p][ni]);
        accI[p][ni] = MFMA16(arh, bih[ni], accI[p][ni]);
        accI[p][ni] = MFMA16(arh, bil[ni], accI[p][ni]);
        accI[p][ni] = MFMA16(arl, bih[ni], accI[p][ni]);
        accI[p][ni] = MFMA16(aih, brh[ni], accI[p][ni]);
        accI[p][ni] = MFMA16(aih, brl[ni], accI[p][ni]);
        accI[p][ni] = MFMA16(ail, brh[ni], accI[p][ni]);
      }
      __builtin_amdgcn_s_setprio(0);
    }
    __builtin_amdgcn_sched_barrier(0);   // keep this kstep's LDS reads above next barrier
  }

  __hip_bfloat16* Dp = D + chOff;
  __hip_bfloat16* Tp = DT + chOff;
#pragma unroll
  for (int mi = 0; mi < 4; ++mi)
#pragma unroll
    for (int ni = 0; ni < 2; ++ni) {
      int rb = rowBase + wm * 64 + mi * 16 + (lane >> 4) * 4;
      int cc = colBase + wn * 32 + ni * 16 + (lane & 15);
      if (cc >= NK || rb >= NK) continue;   // rb % 4 == 0, NK % 4 == 0 -> whole quad valid
      short hR[4], lR[4], hI[4], lI[4];
#pragma unroll
      for (int j = 0; j < 4; ++j) {
        float vR = alpha * (accP[mi][ni][j] - accN[mi][ni][j]) + ((rb + j == cc) ? delta : 0.f);
        float vI = alpha * accI[mi][ni][j];
        __hip_bfloat16 h, l;
        bsplit(vR, h, l); hR[j] = braw(h); lR[j] = braw(l);
        bsplit(vI, h, l); hI[j] = braw(h); lI[j] = braw(l);
      }
      if (wf & 1) {
#pragma unroll
        for (int j = 0; j < 4; ++j) {
          size_t o = (size_t)(rb + j) * NK + cc;
          *(short*)&Dp[o] = hR[j];
          *(short*)&Dp[PLN + o] = lR[j];
          *(short*)&Dp[2 * PLN + o] = hI[j];
          *(short*)&Dp[3 * PLN + o] = lI[j];
        }
      }
      if (wf & 2) {
        size_t o = (size_t)cc * NK + rb;
        short4v vR4 = {hR[0], hR[1], hR[2], hR[3]};
        short4v vL4 = {lR[0], lR[1], lR[2], lR[3]};
        short4v vI4 = {hI[0], hI[1], hI[2], hI[3]};
        short4v vJ4 = {lI[0], lI[1], lI[2], lI[3]};
        *(short4v*)&Tp[o] = vR4;
        *(short4v*)&Tp[PLN + o] = vL4;
        *(short4v*)&Tp[2 * PLN + o] = vI4;
        *(short4v*)&Tp[3 * PLN + o] = vJ4;
      }
    }
}

// ---------------- Stage 4: slice + roll + separable DFTs ----------------
__global__ void passA(const __hip_bfloat16* __restrict__ X, float2* __restrict__ P) {
  int cl = blockIdx.y;
  int idx = blockIdx.x * 256 + threadIdx.x;
  int v = idx % 20, u = (idx / 20) % 20, q = (idx / 400) % 16, p = idx / 6400;
  int pp = (p + 7) % 16;
  int qq = (q + 7) % 16;
  int row = (pp + 5) * 24 + (qq + 5);
  int uu = (u + 9) % 20;
  int aa = uu + 3;
  const __hip_bfloat16* tb = X + (size_t)cl * SETSTR;
  float2 acc = make_float2(0.f, 0.f);
  for (int vp = 0; vp < 20; ++vp) {
    int vv = (vp + 9) % 20;
    int col = aa * 24 + (vv + 3);
    size_t o = (size_t)row * NK + col;
    float xr = __bfloat162float(tb[o]) + __bfloat162float(tb[PLN + o]);
    float xi = __bfloat162float(tb[2 * PLN + o]) + __bfloat162float(tb[3 * PLN + o]);
    float ang = (TAU / 20.f) * (float)((v * vp) % 20);
    float s, co;
    sincosf(ang, &s, &co);
    acc.x += xr * co - xi * s;
    acc.y += xr * s + xi * co;
  }
  P[(size_t)cl * MAPSZ + idx] = acc;
}

__global__ void passB(const float2* __restrict__ Pin, float2* __restrict__ Pout) {
  int cl = blockIdx.y;
  int idx = blockIdx.x * 256 + threadIdx.x;
  int v = idx % 20, u = (idx / 20) % 20, q = (idx / 400) % 16, p = idx / 6400;
  const float2* in = Pin + (size_t)cl * MAPSZ;
  float2 acc = make_float2(0.f, 0.f);
  for (int up = 0; up < 20; ++up) {
    float2 val = in[(p * 16 + q) * 400 + up * 20 + v];
    float ang = (TAU / 20.f) * (float)((u * up) % 20);
    float s, co;
    sincosf(ang, &s, &co);
    acc.x += val.x * co - val.y * s;
    acc.y += val.x * s + val.y * co;
  }
  Pout[(size_t)cl * MAPSZ + idx] = acc;
}

__global__ void passC(const float2* __restrict__ Pin, float2* __restrict__ Pout) {
  int cl = blockIdx.y;
  int idx = blockIdx.x * 256 + threadIdx.x;
  int v = idx % 20, u = (idx / 20) % 20, q = (idx / 400) % 16, p = idx / 6400;
  const float2* in = Pin + (size_t)cl * MAPSZ;
  float2 acc = make_float2(0.f, 0.f);
  for (int qp = 0; qp < 16; ++qp) {
    float2 val = in[(p * 16 + qp) * 400 + u * 20 + v];
    float ang = -(TAU / 16.f) * (float)((q * qp) % 16);
    float s, co;
    sincosf(ang, &s, &co);
    acc.x += val.x * co - val.y * s;
    acc.y += val.x * s + val.y * co;
  }
  Pout[(size_t)cl * MAPSZ + idx] = acc;
}

// passD: final DFT, write split-bf16 m directly into padded [n][KOUT] planes
__global__ void passD(const float2* __restrict__ Pin, __hip_bfloat16* __restrict__ ms, int c0) {
  int cl = blockIdx.y;
  int c = c0 + cl;
  int idx = blockIdx.x * 256 + threadIdx.x;
  int v = idx % 20, u = (idx / 20) % 20, q = (idx / 400) % 16, p = idx / 6400;
  const float2* in = Pin + (size_t)cl * MAPSZ;
  float acc = 0.f;
  for (int pp = 0; pp < 16; ++pp) {
    float2 val = in[(pp * 16 + q) * 400 + u * 20 + v];
    float ang = -(TAU / 16.f) * (float)((p * pp) % 16);
    float s, co;
    sincosf(ang, &s, &co);
    acc += val.x * co - val.y * s;
  }
  acc *= (1.f / 400.f);
  int n = c * 256 + idx / 400;          // o = p*16+q
  int k = idx % 400;                    // k = u*20+v
  __hip_bfloat16 h, l;
  bsplit(acc, h, l);
  ms[(size_t)n * KOUT + k] = h;
  ms[MPL + (size_t)n * KOUT + k] = l;
}

// zero the k in [400,416) pad of the m planes
__global__ void pad_m(__hip_bfloat16* __restrict__ ms) {
  int idx = blockIdx.x * 256 + threadIdx.x;   // 4096*16*2
  int p = idx >> 16;
  int rem = idx & 65535;
  int n = rem >> 4;
  int k = 400 + (rem & 15);
  ms[(size_t)p * MPL + (size_t)n * KOUT + k] = __float2bfloat16(0.f);
}

// convert x (8192x400 f32) to split bf16 padded [2][8192][KOUT]
__global__ void prep_x(const float* __restrict__ x, __hip_bfloat16* __restrict__ xs) {
  int idx = blockIdx.x * 256 + threadIdx.x;   // 8192*52
  if (idx >= 8192 * 52) return;
  int b = idx / 52, c8 = idx % 52;
  int k = c8 * 8;
  short8 hh = {}, ll = {};
  if (k < 400) {
    const float4* xp = (const float4*)(x + (size_t)b * 400 + k);
    float4 v0 = xp[0], v1 = xp[1];
    float vals[8] = {v0.x, v0.y, v0.z, v0.w, v1.x, v1.y, v1.z, v1.w};
#pragma unroll
    for (int i = 0; i < 8; ++i) {
      __hip_bfloat16 h, l;
      bsplit(vals[i], h, l);
      hh[i] = braw(h);
      ll[i] = braw(l);
    }
  }
  *(short8*)(xs + (size_t)b * KOUT + k) = hh;
  *(short8*)(xs + XPL + (size_t)b * KOUT + k) = ll;
}

// ---------------- Stage 5: output GEMM, split-bf16 MFMA, 128x128 tile ----------------
__global__ __launch_bounds__(512, 2) void out_mfma(
    const __hip_bfloat16* __restrict__ xs, const __hip_bfloat16* __restrict__ ms,
    float* __restrict__ Y) {
  __shared__ char lds[2][32768];   // A planes @0 (2*8192), B planes @16384
  const int t = threadIdx.x;
  const int lane = t & 63;
  const int wid = t >> 6;
  const int wm = wid >> 2, wn = wid & 3;
  const int rowBase = blockIdx.y * 128, colBase = blockIdx.x * 128;

  size_t gA[2], gB[2];
  int ldsOff[2];
#pragma unroll
  for (int i = 0; i < 2; ++i) {
    int cid = i * 512 + t;
    int p = cid >> 9, r = (cid >> 2) & 127, cp = cid & 3;
    int cg = cp ^ ((r >> 1) & 3);
    gA[i] = (size_t)p * XPL + (size_t)(rowBase + r) * KOUT + cg * 8;
    gB[i] = (size_t)p * MPL + (size_t)(colBase + r) * KOUT + cg * 8;
    ldsOff[i] = cid * 16;
  }
  int aoff[4], boff[2];
#pragma unroll
  for (int mi = 0; mi < 4; ++mi) {
    int ra = wm * 64 + mi * 16 + (lane & 15);
    int ch = (lane >> 4) ^ ((ra >> 1) & 3);
    aoff[mi] = (ra * 4 + ch) * 16;
  }
#pragma unroll
  for (int ni = 0; ni < 2; ++ni) {
    int cb = wn * 32 + ni * 16 + (lane & 15);
    int ch = (lane >> 4) ^ ((cb >> 1) & 3);
    boff[ni] = 16384 + (cb * 4 + ch) * 16;
  }

  f32x4 acc[4][2] = {};

  auto STAGE = [&](int buf, int k0) {
#pragma unroll
    for (int i = 0; i < 2; ++i) {
      gld16(xs + gA[i] + k0, &lds[buf][ldsOff[i]]);
      gld16(ms + gB[i] + k0, &lds[buf][16384 + ldsOff[i]]);
    }
  };

  STAGE(0, 0);
#pragma unroll 1
  for (int ks = 0; ks < 13; ++ks) {
    int cur = ks & 1;
    asm volatile("s_waitcnt vmcnt(0)" ::: "memory");
    __builtin_amdgcn_sched_barrier(0);
    __builtin_amdgcn_s_barrier();
    __builtin_amdgcn_sched_barrier(0);
    short8 bh[2], bl[2];
#pragma unroll
    for (int ni = 0; ni < 2; ++ni) {
      const char* base = &lds[cur][boff[ni]];
      bh[ni] = *(const short8*)(base);
      bl[ni] = *(const short8*)(base + 8192);
    }
#pragma unroll
    for (int mi = 0; mi < 4; ++mi) {
      short8 ah, al;
      {
        const char* base = &lds[cur][aoff[mi]];
        ah = *(const short8*)(base);
        al = *(const short8*)(base + 8192);
      }
      if (ks < 12 && mi < 2) STAGE(cur ^ 1, (ks + 1) * 32);  // 2 stages split over mi 0,1
      __builtin_amdgcn_s_setprio(1);
#pragma unroll
      for (int ni = 0; ni < 2; ++ni) {
        acc[mi][ni] = MFMA16(ah, bh[ni], acc[mi][ni]);
        acc[mi][ni] = MFMA16(ah, bl[ni], acc[mi][ni]);
        acc[mi][ni] = MFMA16(al, bh[ni], acc[mi][ni]);
      }
      __builtin_amdgcn_s_setprio(0);
    }
    __builtin_amdgcn_sched_barrier(0);
  }

#pragma unroll
  for (int mi = 0; mi < 4; ++mi)
#pragma unroll
    for (int ni = 0; ni < 2; ++ni) {
      int rb = rowBase + wm * 64 + mi * 16 + (lane >> 4) * 4;
      int cc = colBase + wn * 32 + ni * 16 + (lane & 15);
#pragma unroll
      for (int j = 0; j < 4; ++j)
        Y[(size_t)(rb + j) * 4096 + cc] = acc[mi][ni][j];
    }
}

// ---------------- Launcher ----------------
extern "C" void kernel_launch(void* const* d_in, const int* in_sizes, int n_in,
                              void* d_out, int out_size, void* d_ws, size_t ws_size,
                              hipStream_t stream) {
  const float* x = (const float*)d_in[0];     // (8192,1,20,20)
  const float* sig = (const float*)d_in[1];   // (16,2,24,24)
  float* out = (float*)d_out;                 // (8192,16,16,16)
  char* ws = (char*)d_ws;

  const size_t specBytes = 32ull * 576 * sizeof(float2);
  const size_t xsBytes = 2ull * XPL * 2;
  const size_t msBytes = 2ull * MPL * 2;
  const size_t fixed = specBytes + xsBytes + msBytes;
  const size_t setB = SETSTR * 2;                       // bytes per split set
  const size_t perCh = 5 * setB + 2ull * MAPSZ * 8;     // B, X0, X0T, X1, X1T + P0/P1

  int cg = 1;
  if (ws_size > fixed) {
    size_t av = (ws_size - fixed) / perCh;
    cg = (av < 1) ? 1 : (av > 16 ? 16 : (int)av);
  }

  float2* spec = (float2*)ws;
  __hip_bfloat16* xs = (__hip_bfloat16*)(ws + specBytes);
  __hip_bfloat16* ms = (__hip_bfloat16*)(ws + specBytes + xsBytes);
  __hip_bfloat16* Bst = (__hip_bfloat16*)(ws + fixed);
  __hip_bfloat16* X0 = Bst + (size_t)cg * SETSTR;
  __hip_bfloat16* X0T = X0 + (size_t)cg * SETSTR;
  __hip_bfloat16* X1 = X0T + (size_t)cg * SETSTR;
  __hip_bfloat16* X1T = X1 + (size_t)cg * SETSTR;
  float2* P0 = (float2*)(X1T + (size_t)cg * SETSTR);
  float2* P1 = P0 + (size_t)cg * MAPSZ;

  spectrum_kernel<<<dim3(32), dim3(576), 0, stream>>>(sig, spec);
  prep_x<<<dim3((8192 * 52 + 255) / 256), dim3(256), 0, stream>>>(x, xs);
  pad_m<<<dim3(512), dim3(256), 0, stream>>>(ms);

  const float scale = 1.f / 64.f;  // s = 6 squarings
  for (int c0 = 0; c0 < 16; c0 += cg) {
    int g = (16 - c0 < cg) ? (16 - c0) : cg;
    buildBX<<<dim3(1296, g), dim3(256), 0, stream>>>(spec, Bst, X0, c0, scale);
    transpose4<<<dim3(9, 9, g), dim3(256), 0, stream>>>(X0, X0T);
    __hip_bfloat16 *xr = X0, *xt = X0T, *yr = X1, *yt = X1T;
    // Horner (Taylor order 5): X <- I + (B*X)/k, k=4..1. Only DT consumed until k=1.
    for (int k = 4; k >= 1; --k) {
      int wf = (k == 1) ? 3 : 2;
      cgemm_mfma<<<dim3(25 * g), dim3(512), 0, stream>>>(Bst, xt, yr, yt,
                                                         1.f / (float)k, 1.f, wf);
      __hip_bfloat16* tmp;
      tmp = xr; xr = yr; yr = tmp;
      tmp = xt; xt = yt; yt = tmp;
    }
    // 6 squarings; last one only needs row-major output (feeds passA)
    for (int t8 = 0; t8 < 6; ++t8) {
      int wf = (t8 == 5) ? 1 : 3;
      cgemm_mfma<<<dim3(25 * g), dim3(512), 0, stream>>>(xr, xt, yr, yt, 1.f, 0.f, wf);
      __hip_bfloat16* tmp;
      tmp = xr; xr = yr; yr = tmp;
      tmp = xt; xt = yt; yt = tmp;
    }
    passA<<<dim3(400, g), dim3(256), 0, stream>>>(xr, P0);
    passB<<<dim3(400, g), dim3(256), 0, stream>>>(P0, P1);
    passC<<<dim3(400, g), dim3(256), 0, stream>>>(P1, P0);
    passD<<<dim3(400, g), dim3(256), 0, stream>>>(P0, ms, c0);
  }

  out_mfma<<<dim3(32, 64), dim3(512), 0, stream>>>(xs, ms, out);
}

// Round 9
// 1086.622 us; speedup vs baseline: 6.0954x; 1.1419x over previous
//
#include <hip/hip_runtime.h>
#include <hip/hip_bf16.h>
#include <math.h>

#define TAU 6.283185307179586f
#define NK 576                    // matrix dimension (K always exact: 18*32)
#define NPAD 640                  // padded row count for 128-row tiles
#define PLN ((size_t)NPAD * NK)   // elems per padded plane = 368640
#define SETSTR ((size_t)4 * PLN)  // elems per 4-plane split set
#define MAPSZ 102400              // 16*16*20*20
#define KOUT 416                  // padded K for output gemm (13*32)
#define XPL ((size_t)8192 * KOUT)
#define MPL ((size_t)4096 * KOUT)

typedef __attribute__((ext_vector_type(8))) short short8;
typedef __attribute__((ext_vector_type(4))) short short4v;
typedef __attribute__((ext_vector_type(4))) float f32x4;

__device__ inline void bsplit(float v, __hip_bfloat16& h, __hip_bfloat16& l) {
  h = __float2bfloat16(v);
  l = __float2bfloat16(v - __bfloat162float(h));
}
__device__ inline short braw(__hip_bfloat16 b) { return *reinterpret_cast<short*>(&b); }

__device__ inline void gld16(const void* g, const void* l) {
  __builtin_amdgcn_global_load_lds((const __attribute__((address_space(1))) unsigned*)g,
                                   (__attribute__((address_space(3))) unsigned*)l, 16, 0, 0);
}

#define MFMA16(a, b, c) __builtin_amdgcn_mfma_f32_16x16x32_bf16(a, b, c, 0, 0, 0)

// ---------------- Stage 1: signal -> spectrum ----------------
__device__ inline void dft24(const float2* in, float2* out, int t, float sgn, bool firstAxis) {
  int r = t / 24, c = t % 24;
  int kk = firstAxis ? r : c;
  float2 acc = make_float2(0.f, 0.f);
  for (int n = 0; n < 24; ++n) {
    float ang = sgn * (TAU / 24.f) * (float)((kk * n) % 24);
    float s, co;
    sincosf(ang, &s, &co);
    float2 v = firstAxis ? in[n * 24 + c] : in[r * 24 + n];
    acc.x += v.x * co - v.y * s;
    acc.y += v.x * s + v.y * co;
  }
  out[t] = acc;
}

__global__ void spectrum_kernel(const float* __restrict__ sig, float2* __restrict__ spec) {
  __shared__ float2 b0[576];
  __shared__ float2 b1[576];
  int f = blockIdx.x;
  int t = threadIdx.x;
  int r = t / 24, c = t % 24;
  b0[t] = make_float2(sig[f * 576 + t], 0.f);
  __syncthreads();
  dft24(b0, b1, t, -1.f, false); __syncthreads();
  dft24(b1, b0, t, -1.f, true);  __syncthreads();
  {
    int p2 = (r + 12) % 24 - 11;
    int q2 = (c + 12) % 24 - 11;
    float rr = (float)(1 + p2 * p2 + q2 * q2) * 5.f;
    float2 v = b0[t];
    b0[t] = make_float2(v.x / rr, v.y / rr);
  }
  __syncthreads();
  dft24(b0, b1, t, +1.f, false); __syncthreads();
  dft24(b1, b0, t, +1.f, true);  __syncthreads();
  {
    float winr = 0.5f * (1.f - cosf(TAU * (float)r / 24.f));
    float winc = 0.5f * (1.f - cosf(TAU * (float)c / 24.f));
    float w = winr * winc * (1.f / 576.f);
    float2 v = b0[t];
    b0[t] = make_float2(v.x * w, v.y * w);
  }
  __syncthreads();
  dft24(b0, b1, t, -1.f, false); __syncthreads();
  dft24(b1, b0, t, -1.f, true);  __syncthreads();
  int p = (r + 12) % 24, q = (c + 12) % 24;
  spec[f * 576 + p * 24 + q] = b0[t];
}

// ---------------- Stage 2: build split B and X0 = I + B/5 ----------------
__global__ void buildBX(const float2* __restrict__ spec, __hip_bfloat16* __restrict__ B,
                        __hip_bfloat16* __restrict__ X0, int c0, float scale) {
  int idx = blockIdx.x * 256 + threadIdx.x;   // 0..331775 (row*576+col, row<576)
  int cl = blockIdx.y;
  int c = c0 + cl;
  int row = idx / NK, col = idx % NK;
  int i = row / 24, j = row % 24, a = col / 24, b = col % 24;
  int u = 11 - i + a, v = 11 - j + b;
  float br = 0.f, bi = 0.f;
  if (u >= 0 && u < 24 && v >= 0 && v < 24) {
    float2 s0 = spec[(c * 2 + 0) * 576 + u * 24 + v];
    float2 s1 = spec[(c * 2 + 1) * 576 + u * 24 + v];
    float kx = (float)(a - 11), ky = (float)(b - 11);
    float xr = s0.x * kx + s1.x * ky;
    float xi = s0.y * kx + s1.y * ky;
    br = xi * scale;
    bi = -xr * scale;
  }
  size_t off = (size_t)cl * SETSTR + idx;
  __hip_bfloat16 h, l;
  bsplit(br, h, l); B[off] = h; B[off + PLN] = l;
  bsplit(bi, h, l); B[off + 2 * PLN] = h; B[off + 3 * PLN] = l;
  float d = (row == col) ? 1.f : 0.f;
  bsplit(br * (1.f / 5.f) + d, h, l); X0[off] = h; X0[off + PLN] = l;
  bsplit(bi * (1.f / 5.f), h, l);     X0[off + 2 * PLN] = h; X0[off + 3 * PLN] = l;
}

// ---------------- transpose the 4 split planes ----------------
__global__ __launch_bounds__(256) void transpose4(const __hip_bfloat16* __restrict__ src,
                                                  __hip_bfloat16* __restrict__ dst) {
  __shared__ __hip_bfloat16 tile[64][65];
  int cl = blockIdx.z;
  size_t off = (size_t)cl * SETSTR;
  int rB = blockIdx.y * 64, cB = blockIdx.x * 64;
  int tx = threadIdx.x & 63, ty = threadIdx.x >> 6;
  for (int p = 0; p < 4; ++p) {
    for (int li = 0; li < 16; ++li) {
      int r = ty * 16 + li;
      tile[r][tx] = src[off + (size_t)p * PLN + (size_t)(rB + r) * NK + cB + tx];
    }
    __syncthreads();
    for (int li = 0; li < 16; ++li) {
      int r = ty * 16 + li;
      dst[off + (size_t)p * PLN + (size_t)(cB + r) * NK + rB + tx] = tile[tx][r];
    }
    __syncthreads();
  }
}

// ---------------- Stage 3: batched split-complex MFMA GEMM, 128x192 tile ----------------
// D = alpha*(A*B) + delta*I.  A row-major [m][k] split planes; B given as BT [n][k].
// wf bit0: write D (row-major); bit1: write DT (transposed).
// 15 tiles/channel (5 row x 3 col) -> 240 blocks = ONE dispatch round on 256 CUs.
// Wave tile 64x48 (mi=4, ni=3): 144 MFMA per 28 ds_read_b128 per kstep.
// LDS: 2 x (A 32KB + B 48KB) = 160 KiB (full CU capacity, 1 block/CU).
__global__ __launch_bounds__(512, 2) void cgemm_mfma(
    const __hip_bfloat16* __restrict__ A, const __hip_bfloat16* __restrict__ BT,
    __hip_bfloat16* __restrict__ D, __hip_bfloat16* __restrict__ DT,
    float alpha, float delta, int wf) {
  __shared__ char lds[2][81920];   // per buf: A planes @0 (4*8192), B planes @32768 (4*12288)
  const int t = threadIdx.x;
  const int lane = t & 63;
  const int wid = t >> 6;
  const int wm = wid >> 2, wn = wid & 3;          // 2 x 4 waves, wave tile 64x48
  // block remap: XCD-local channels when full 16-channel group (240 % 8 == 0, bijective)
  int p0 = blockIdx.x;
  int cl, tile;
  if (gridDim.x == 240) {
    int idx = p0 >> 3;
    cl = (p0 & 7) + 8 * (idx / 15);
    tile = idx % 15;
  } else {
    cl = p0 / 15;
    tile = p0 % 15;
  }
  const int rowBase = (tile / 3) * 128, colBase = (tile % 3) * 192;
  const size_t chOff = (size_t)cl * SETSTR;
  const __hip_bfloat16* Ab = A + chOff;
  const __hip_bfloat16* Bb = BT + chOff;

  // staging: A 2048 + B 3072 16B-chunks per buffer; 10 chunks/thread
  size_t gA[4], gB[6];
  int ldsA[4], ldsB[6];
#pragma unroll
  for (int i = 0; i < 4; ++i) {
    int cid = i * 512 + t;                 // 0..2047
    int pp = cid >> 9, r = (cid >> 2) & 127, cp = cid & 3;
    int cg = cp ^ ((r >> 1) & 3);
    gA[i] = (size_t)pp * PLN + (size_t)(rowBase + r) * NK + cg * 8;
    ldsA[i] = cid * 16;
  }
#pragma unroll
  for (int i = 0; i < 6; ++i) {
    int cid = i * 512 + t;                 // 0..3071
    int pp = cid / 768, rem = cid % 768;
    int r = rem >> 2, cp = rem & 3;
    int cg = cp ^ ((r >> 1) & 3);
    gB[i] = (size_t)pp * PLN + (size_t)(colBase + r) * NK + cg * 8;
    ldsB[i] = 32768 + cid * 16;
  }
  // fragment read offsets
  int aoff[4], boff[3];
#pragma unroll
  for (int mi = 0; mi < 4; ++mi) {
    int ra = wm * 64 + mi * 16 + (lane & 15);
    int ch = (lane >> 4) ^ ((ra >> 1) & 3);
    aoff[mi] = (ra * 4 + ch) * 16;
  }
#pragma unroll
  for (int ni = 0; ni < 3; ++ni) {
    int cb = wn * 48 + ni * 16 + (lane & 15);
    int ch = (lane >> 4) ^ ((cb >> 1) & 3);
    boff[ni] = 32768 + (cb * 4 + ch) * 16;
  }

  f32x4 accP[4][3] = {}, accN[4][3] = {}, accI[4][3] = {};

  // prologue: tile 0 into buf 0
#pragma unroll
  for (int i = 0; i < 4; ++i) gld16(Ab + gA[i], &lds[0][ldsA[i]]);
#pragma unroll
  for (int i = 0; i < 6; ++i) gld16(Bb + gB[i], &lds[0][ldsB[i]]);

#pragma unroll 1
  for (int ks = 0; ks < 18; ++ks) {
    const int cur = ks & 1;
    const int k1 = (ks + 1) * 32;
    asm volatile("s_waitcnt vmcnt(0)" ::: "memory");   // tile ks landed (issued last kstep)
    __builtin_amdgcn_sched_barrier(0);
    __builtin_amdgcn_s_barrier();                      // prev kstep reads done; buf cur valid
    __builtin_amdgcn_sched_barrier(0);

    short8 brh[3], brl[3], bih[3], bil[3];
#pragma unroll
    for (int ni = 0; ni < 3; ++ni) {
      const char* base = &lds[cur][boff[ni]];
      brh[ni] = *(const short8*)(base);
      brl[ni] = *(const short8*)(base + 12288);
      bih[ni] = *(const short8*)(base + 24576);
      bil[ni] = *(const short8*)(base + 36864);
    }
#pragma unroll
    for (int p = 0; p < 4; ++p) {
      short8 arh, arl, aih, ail;
      {
        const char* base = &lds[cur][aoff[p]];
        arh = *(const short8*)(base);
        arl = *(const short8*)(base + 8192);
        aih = *(const short8*)(base + 16384);
        ail = *(const short8*)(base + 24576);
      }
      if (ks < 17) {                       // issue next-tile staging across phases 0..2
        if (p == 0) {
          gld16(Ab + gA[0] + k1, &lds[cur ^ 1][ldsA[0]]);
          gld16(Ab + gA[1] + k1, &lds[cur ^ 1][ldsA[1]]);
          gld16(Ab + gA[2] + k1, &lds[cur ^ 1][ldsA[2]]);
          gld16(Ab + gA[3] + k1, &lds[cur ^ 1][ldsA[3]]);
        } else if (p == 1) {
          gld16(Bb + gB[0] + k1, &lds[cur ^ 1][ldsB[0]]);
          gld16(Bb + gB[1] + k1, &lds[cur ^ 1][ldsB[1]]);
          gld16(Bb + gB[2] + k1, &lds[cur ^ 1][ldsB[2]]);
        } else if (p == 2) {
          gld16(Bb + gB[3] + k1, &lds[cur ^ 1][ldsB[3]]);
          gld16(Bb + gB[4] + k1, &lds[cur ^ 1][ldsB[4]]);
          gld16(Bb + gB[5] + k1, &lds[cur ^ 1][ldsB[5]]);
        }
      }
      __builtin_amdgcn_s_setprio(1);
#pragma unroll
      for (int ni = 0; ni < 3; ++ni) {
        accP[p][ni] = MFMA16(arh, brh[ni], accP[p][ni]);
        accP[p][ni] = MFMA16(arh, brl[ni], accP[p][ni]);
        accP[p][ni] = MFMA16(arl, brh[ni], accP[p][ni]);
        accN[p][ni] = MFMA16(aih, bih[ni], accN[p][ni]);
        accN[p][ni] = MFMA16(aih, bil[ni], accN[p][ni]);
        accN[p][ni] = MFMA16(ail, bih[ni], accN[p][ni]);
        accI[p][ni] = MFMA16(arh, bih[ni], accI[p][ni]);
        accI[p][ni] = MFMA16(arh, bil[ni], accI[p][ni]);
        accI[p][ni] = MFMA16(arl, bih[ni], accI[p][ni]);
        accI[p][ni] = MFMA16(aih, brh[ni], accI[p][ni]);
        accI[p][ni] = MFMA16(aih, brl[ni], accI[p][ni]);
        accI[p][ni] = MFMA16(ail, brh[ni], accI[p][ni]);
      }
      __builtin_amdgcn_s_setprio(0);
    }
    __builtin_amdgcn_sched_barrier(0);   // keep this kstep's LDS reads above next barrier
  }

  __hip_bfloat16* Dp = D + chOff;
  __hip_bfloat16* Tp = DT + chOff;
#pragma unroll
  for (int mi = 0; mi < 4; ++mi)
#pragma unroll
    for (int ni = 0; ni < 3; ++ni) {
      int rb = rowBase + wm * 64 + mi * 16 + (lane >> 4) * 4;
      int cc = colBase + wn * 48 + ni * 16 + (lane & 15);
      if (rb >= NK) continue;   // cols always < 576; rb quad fully valid when rb < 576
      short hR[4], lR[4], hI[4], lI[4];
#pragma unroll
      for (int j = 0; j < 4; ++j) {
        float vR = alpha * (accP[mi][ni][j] - accN[mi][ni][j]) + ((rb + j == cc) ? delta : 0.f);
        float vI = alpha * accI[mi][ni][j];
        __hip_bfloat16 h, l;
        bsplit(vR, h, l); hR[j] = braw(h); lR[j] = braw(l);
        bsplit(vI, h, l); hI[j] = braw(h); lI[j] = braw(l);
      }
      if (wf & 1) {
#pragma unroll
        for (int j = 0; j < 4; ++j) {
          size_t o = (size_t)(rb + j) * NK + cc;
          *(short*)&Dp[o] = hR[j];
          *(short*)&Dp[PLN + o] = lR[j];
          *(short*)&Dp[2 * PLN + o] = hI[j];
          *(short*)&Dp[3 * PLN + o] = lI[j];
        }
      }
      if (wf & 2) {
        size_t o = (size_t)cc * NK + rb;
        short4v vR4 = {hR[0], hR[1], hR[2], hR[3]};
        short4v vL4 = {lR[0], lR[1], lR[2], lR[3]};
        short4v vI4 = {hI[0], hI[1], hI[2], hI[3]};
        short4v vJ4 = {lI[0], lI[1], lI[2], lI[3]};
        *(short4v*)&Tp[o] = vR4;
        *(short4v*)&Tp[PLN + o] = vL4;
        *(short4v*)&Tp[2 * PLN + o] = vI4;
        *(short4v*)&Tp[3 * PLN + o] = vJ4;
      }
    }
}

// ---------------- Stage 4: slice + roll + separable DFTs ----------------
__global__ void passA(const __hip_bfloat16* __restrict__ X, float2* __restrict__ P) {
  int cl = blockIdx.y;
  int idx = blockIdx.x * 256 + threadIdx.x;
  int v = idx % 20, u = (idx / 20) % 20, q = (idx / 400) % 16, p = idx / 6400;
  int pp = (p + 7) % 16;
  int qq = (q + 7) % 16;
  int row = (pp + 5) * 24 + (qq + 5);
  int uu = (u + 9) % 20;
  int aa = uu + 3;
  const __hip_bfloat16* tb = X + (size_t)cl * SETSTR;
  float2 acc = make_float2(0.f, 0.f);
  for (int vp = 0; vp < 20; ++vp) {
    int vv = (vp + 9) % 20;
    int col = aa * 24 + (vv + 3);
    size_t o = (size_t)row * NK + col;
    float xr = __bfloat162float(tb[o]) + __bfloat162float(tb[PLN + o]);
    float xi = __bfloat162float(tb[2 * PLN + o]) + __bfloat162float(tb[3 * PLN + o]);
    float ang = (TAU / 20.f) * (float)((v * vp) % 20);
    float s, co;
    sincosf(ang, &s, &co);
    acc.x += xr * co - xi * s;
    acc.y += xr * s + xi * co;
  }
  P[(size_t)cl * MAPSZ + idx] = acc;
}

__global__ void passB(const float2* __restrict__ Pin, float2* __restrict__ Pout) {
  int cl = blockIdx.y;
  int idx = blockIdx.x * 256 + threadIdx.x;
  int v = idx % 20, u = (idx / 20) % 20, q = (idx / 400) % 16, p = idx / 6400;
  const float2* in = Pin + (size_t)cl * MAPSZ;
  float2 acc = make_float2(0.f, 0.f);
  for (int up = 0; up < 20; ++up) {
    float2 val = in[(p * 16 + q) * 400 + up * 20 + v];
    float ang = (TAU / 20.f) * (float)((u * up) % 20);
    float s, co;
    sincosf(ang, &s, &co);
    acc.x += val.x * co - val.y * s;
    acc.y += val.x * s + val.y * co;
  }
  Pout[(size_t)cl * MAPSZ + idx] = acc;
}

__global__ void passC(const float2* __restrict__ Pin, float2* __restrict__ Pout) {
  int cl = blockIdx.y;
  int idx = blockIdx.x * 256 + threadIdx.x;
  int v = idx % 20, u = (idx / 20) % 20, q = (idx / 400) % 16, p = idx / 6400;
  const float2* in = Pin + (size_t)cl * MAPSZ;
  float2 acc = make_float2(0.f, 0.f);
  for (int qp = 0; qp < 16; ++qp) {
    float2 val = in[(p * 16 + qp) * 400 + u * 20 + v];
    float ang = -(TAU / 16.f) * (float)((q * qp) % 16);
    float s, co;
    sincosf(ang, &s, &co);
    acc.x += val.x * co - val.y * s;
    acc.y += val.x * s + val.y * co;
  }
  Pout[(size_t)cl * MAPSZ + idx] = acc;
}

// passD: final DFT, write split-bf16 m directly into padded [n][KOUT] planes
__global__ void passD(const float2* __restrict__ Pin, __hip_bfloat16* __restrict__ ms, int c0) {
  int cl = blockIdx.y;
  int c = c0 + cl;
  int idx = blockIdx.x * 256 + threadIdx.x;
  int v = idx % 20, u = (idx / 20) % 20, q = (idx / 400) % 16, p = idx / 6400;
  const float2* in = Pin + (size_t)cl * MAPSZ;
  float acc = 0.f;
  for (int pp = 0; pp < 16; ++pp) {
    float2 val = in[(pp * 16 + q) * 400 + u * 20 + v];
    float ang = -(TAU / 16.f) * (float)((p * pp) % 16);
    float s, co;
    sincosf(ang, &s, &co);
    acc += val.x * co - val.y * s;
  }
  acc *= (1.f / 400.f);
  int n = c * 256 + idx / 400;          // o = p*16+q
  int k = idx % 400;                    // k = u*20+v
  __hip_bfloat16 h, l;
  bsplit(acc, h, l);
  ms[(size_t)n * KOUT + k] = h;
  ms[MPL + (size_t)n * KOUT + k] = l;
}

// zero the k in [400,416) pad of the m planes
__global__ void pad_m(__hip_bfloat16* __restrict__ ms) {
  int idx = blockIdx.x * 256 + threadIdx.x;   // 4096*16*2
  int p = idx >> 16;
  int rem = idx & 65535;
  int n = rem >> 4;
  int k = 400 + (rem & 15);
  ms[(size_t)p * MPL + (size_t)n * KOUT + k] = __float2bfloat16(0.f);
}

// convert x (8192x400 f32) to split bf16 padded [2][8192][KOUT]
__global__ void prep_x(const float* __restrict__ x, __hip_bfloat16* __restrict__ xs) {
  int idx = blockIdx.x * 256 + threadIdx.x;   // 8192*52
  if (idx >= 8192 * 52) return;
  int b = idx / 52, c8 = idx % 52;
  int k = c8 * 8;
  short8 hh = {}, ll = {};
  if (k < 400) {
    const float4* xp = (const float4*)(x + (size_t)b * 400 + k);
    float4 v0 = xp[0], v1 = xp[1];
    float vals[8] = {v0.x, v0.y, v0.z, v0.w, v1.x, v1.y, v1.z, v1.w};
#pragma unroll
    for (int i = 0; i < 8; ++i) {
      __hip_bfloat16 h, l;
      bsplit(vals[i], h, l);
      hh[i] = braw(h);
      ll[i] = braw(l);
    }
  }
  *(short8*)(xs + (size_t)b * KOUT + k) = hh;
  *(short8*)(xs + XPL + (size_t)b * KOUT + k) = ll;
}

// ---------------- Stage 5: output GEMM, split-bf16 MFMA, 128x128 tile ----------------
__global__ __launch_bounds__(512, 2) void out_mfma(
    const __hip_bfloat16* __restrict__ xs, const __hip_bfloat16* __restrict__ ms,
    float* __restrict__ Y) {
  __shared__ char lds[2][32768];   // A planes @0 (2*8192), B planes @16384
  const int t = threadIdx.x;
  const int lane = t & 63;
  const int wid = t >> 6;
  const int wm = wid >> 2, wn = wid & 3;
  const int rowBase = blockIdx.y * 128, colBase = blockIdx.x * 128;

  size_t gA[2], gB[2];
  int ldsOff[2];
#pragma unroll
  for (int i = 0; i < 2; ++i) {
    int cid = i * 512 + t;
    int p = cid >> 9, r = (cid >> 2) & 127, cp = cid & 3;
    int cg = cp ^ ((r >> 1) & 3);
    gA[i] = (size_t)p * XPL + (size_t)(rowBase + r) * KOUT + cg * 8;
    gB[i] = (size_t)p * MPL + (size_t)(colBase + r) * KOUT + cg * 8;
    ldsOff[i] = cid * 16;
  }
  int aoff[4], boff[2];
#pragma unroll
  for (int mi = 0; mi < 4; ++mi) {
    int ra = wm * 64 + mi * 16 + (lane & 15);
    int ch = (lane >> 4) ^ ((ra >> 1) & 3);
    aoff[mi] = (ra * 4 + ch) * 16;
  }
#pragma unroll
  for (int ni = 0; ni < 2; ++ni) {
    int cb = wn * 32 + ni * 16 + (lane & 15);
    int ch = (lane >> 4) ^ ((cb >> 1) & 3);
    boff[ni] = 16384 + (cb * 4 + ch) * 16;
  }

  f32x4 acc[4][2] = {};

  auto STAGE = [&](int buf, int k0) {
#pragma unroll
    for (int i = 0; i < 2; ++i) {
      gld16(xs + gA[i] + k0, &lds[buf][ldsOff[i]]);
      gld16(ms + gB[i] + k0, &lds[buf][16384 + ldsOff[i]]);
    }
  };

  STAGE(0, 0);
#pragma unroll 1
  for (int ks = 0; ks < 13; ++ks) {
    int cur = ks & 1;
    asm volatile("s_waitcnt vmcnt(0)" ::: "memory");
    __builtin_amdgcn_sched_barrier(0);
    __builtin_amdgcn_s_barrier();
    __builtin_amdgcn_sched_barrier(0);
    short8 bh[2], bl[2];
#pragma unroll
    for (int ni = 0; ni < 2; ++ni) {
      const char* base = &lds[cur][boff[ni]];
      bh[ni] = *(const short8*)(base);
      bl[ni] = *(const short8*)(base + 8192);
    }
#pragma unroll
    for (int mi = 0; mi < 4; ++mi) {
      short8 ah, al;
      {
        const char* base = &lds[cur][aoff[mi]];
        ah = *(const short8*)(base);
        al = *(const short8*)(base + 8192);
      }
      if (ks < 12 && mi < 2) STAGE(cur ^ 1, (ks + 1) * 32);  // 2 stages split over mi 0,1
      __builtin_amdgcn_s_setprio(1);
#pragma unroll
      for (int ni = 0; ni < 2; ++ni) {
        acc[mi][ni] = MFMA16(ah, bh[ni], acc[mi][ni]);
        acc[mi][ni] = MFMA16(ah, bl[ni], acc[mi][ni]);
        acc[mi][ni] = MFMA16(al, bh[ni], acc[mi][ni]);
      }
      __builtin_amdgcn_s_setprio(0);
    }
    __builtin_amdgcn_sched_barrier(0);
  }

#pragma unroll
  for (int mi = 0; mi < 4; ++mi)
#pragma unroll
    for (int ni = 0; ni < 2; ++ni) {
      int rb = rowBase + wm * 64 + mi * 16 + (lane >> 4) * 4;
      int cc = colBase + wn * 32 + ni * 16 + (lane & 15);
#pragma unroll
      for (int j = 0; j < 4; ++j)
        Y[(size_t)(rb + j) * 4096 + cc] = acc[mi][ni][j];
    }
}

// ---------------- Launcher ----------------
extern "C" void kernel_launch(void* const* d_in, const int* in_sizes, int n_in,
                              void* d_out, int out_size, void* d_ws, size_t ws_size,
                              hipStream_t stream) {
  const float* x = (const float*)d_in[0];     // (8192,1,20,20)
  const float* sig = (const float*)d_in[1];   // (16,2,24,24)
  float* out = (float*)d_out;                 // (8192,16,16,16)
  char* ws = (char*)d_ws;

  const size_t specBytes = 32ull * 576 * sizeof(float2);
  const size_t xsBytes = 2ull * XPL * 2;
  const size_t msBytes = 2ull * MPL * 2;
  const size_t fixed = specBytes + xsBytes + msBytes;
  const size_t setB = SETSTR * 2;                       // bytes per split set
  const size_t perCh = 5 * setB + 2ull * MAPSZ * 8;     // B, X0, X0T, X1, X1T + P0/P1

  int cg = 1;
  if (ws_size > fixed) {
    size_t av = (ws_size - fixed) / perCh;
    cg = (av < 1) ? 1 : (av > 16 ? 16 : (int)av);
  }

  float2* spec = (float2*)ws;
  __hip_bfloat16* xs = (__hip_bfloat16*)(ws + specBytes);
  __hip_bfloat16* ms = (__hip_bfloat16*)(ws + specBytes + xsBytes);
  __hip_bfloat16* Bst = (__hip_bfloat16*)(ws + fixed);
  __hip_bfloat16* X0 = Bst + (size_t)cg * SETSTR;
  __hip_bfloat16* X0T = X0 + (size_t)cg * SETSTR;
  __hip_bfloat16* X1 = X0T + (size_t)cg * SETSTR;
  __hip_bfloat16* X1T = X1 + (size_t)cg * SETSTR;
  float2* P0 = (float2*)(X1T + (size_t)cg * SETSTR);
  float2* P1 = P0 + (size_t)cg * MAPSZ;

  spectrum_kernel<<<dim3(32), dim3(576), 0, stream>>>(sig, spec);
  prep_x<<<dim3((8192 * 52 + 255) / 256), dim3(256), 0, stream>>>(x, xs);
  pad_m<<<dim3(512), dim3(256), 0, stream>>>(ms);

  const float scale = 1.f / 64.f;  // s = 6 squarings
  for (int c0 = 0; c0 < 16; c0 += cg) {
    int g = (16 - c0 < cg) ? (16 - c0) : cg;
    buildBX<<<dim3(1296, g), dim3(256), 0, stream>>>(spec, Bst, X0, c0, scale);
    transpose4<<<dim3(9, 9, g), dim3(256), 0, stream>>>(X0, X0T);
    __hip_bfloat16 *xr = X0, *xt = X0T, *yr = X1, *yt = X1T;
    // Horner (Taylor order 5): X <- I + (B*X)/k, k=4..1. Only DT consumed until k=1.
    for (int k = 4; k >= 1; --k) {
      int wf = (k == 1) ? 3 : 2;
      cgemm_mfma<<<dim3(15 * g), dim3(512), 0, stream>>>(Bst, xt, yr, yt,
                                                         1.f / (float)k, 1.f, wf);
      __hip_bfloat16* tmp;
      tmp = xr; xr = yr; yr = tmp;
      tmp = xt; xt = yt; yt = tmp;
    }
    // 6 squarings; last one only needs row-major output (feeds passA)
    for (int t8 = 0; t8 < 6; ++t8) {
      int wf = (t8 == 5) ? 1 : 3;
      cgemm_mfma<<<dim3(15 * g), dim3(512), 0, stream>>>(xr, xt, yr, yt, 1.f, 0.f, wf);
      __hip_bfloat16* tmp;
      tmp = xr; xr = yr; yr = tmp;
      tmp = xt; xt = yt; yt = tmp;
    }
    passA<<<dim3(400, g), dim3(256), 0, stream>>>(xr, P0);
    passB<<<dim3(400, g), dim3(256), 0, stream>>>(P0, P1);
    passC<<<dim3(400, g), dim3(256), 0, stream>>>(P1, P0);
    passD<<<dim3(400, g), dim3(256), 0, stream>>>(P0, ms, c0);
  }

  out_mfma<<<dim3(32, 64), dim3(512), 0, stream>>>(xs, ms, out);
}

// Round 10
// 908.243 us; speedup vs baseline: 7.2926x; 1.1964x over previous
//
#include <hip/hip_runtime.h>
#include <hip/hip_bf16.h>
#include <math.h>

#define TAU 6.283185307179586f
#define NK 576                    // matrix dimension (K always exact: 18*32)
#define NPAD 640                  // padded row count for 128-row tiles
#define PLN ((size_t)NPAD * NK)   // elems per padded plane = 368640
#define SETSTR ((size_t)4 * PLN)  // elems per 4-plane split set
#define MAPSZ 102400              // 16*16*20*20
#define KOUT 416                  // padded K for output gemm (13*32)
#define XPL ((size_t)8192 * KOUT)
#define MPL ((size_t)4096 * KOUT)

typedef __attribute__((ext_vector_type(8))) short short8;
typedef __attribute__((ext_vector_type(4))) short short4v;
typedef __attribute__((ext_vector_type(4))) float f32x4;

__device__ inline void bsplit(float v, __hip_bfloat16& h, __hip_bfloat16& l) {
  h = __float2bfloat16(v);
  l = __float2bfloat16(v - __bfloat162float(h));
}
__device__ inline short braw(__hip_bfloat16 b) { return *reinterpret_cast<short*>(&b); }

__device__ inline void gld16(const void* g, const void* l) {
  __builtin_amdgcn_global_load_lds((const __attribute__((address_space(1))) unsigned*)g,
                                   (__attribute__((address_space(3))) unsigned*)l, 16, 0, 0);
}

#define MFMA16(a, b, c) __builtin_amdgcn_mfma_f32_16x16x32_bf16(a, b, c, 0, 0, 0)

// ---------------- Stage 1: signal -> spectrum ----------------
__device__ inline void dft24(const float2* in, float2* out, int t, float sgn, bool firstAxis) {
  int r = t / 24, c = t % 24;
  int kk = firstAxis ? r : c;
  float2 acc = make_float2(0.f, 0.f);
  for (int n = 0; n < 24; ++n) {
    float ang = sgn * (TAU / 24.f) * (float)((kk * n) % 24);
    float s, co;
    sincosf(ang, &s, &co);
    float2 v = firstAxis ? in[n * 24 + c] : in[r * 24 + n];
    acc.x += v.x * co - v.y * s;
    acc.y += v.x * s + v.y * co;
  }
  out[t] = acc;
}

__global__ void spectrum_kernel(const float* __restrict__ sig, float2* __restrict__ spec) {
  __shared__ float2 b0[576];
  __shared__ float2 b1[576];
  int f = blockIdx.x;
  int t = threadIdx.x;
  int r = t / 24, c = t % 24;
  b0[t] = make_float2(sig[f * 576 + t], 0.f);
  __syncthreads();
  dft24(b0, b1, t, -1.f, false); __syncthreads();
  dft24(b1, b0, t, -1.f, true);  __syncthreads();
  {
    int p2 = (r + 12) % 24 - 11;
    int q2 = (c + 12) % 24 - 11;
    float rr = (float)(1 + p2 * p2 + q2 * q2) * 5.f;
    float2 v = b0[t];
    b0[t] = make_float2(v.x / rr, v.y / rr);
  }
  __syncthreads();
  dft24(b0, b1, t, +1.f, false); __syncthreads();
  dft24(b1, b0, t, +1.f, true);  __syncthreads();
  {
    float winr = 0.5f * (1.f - cosf(TAU * (float)r / 24.f));
    float winc = 0.5f * (1.f - cosf(TAU * (float)c / 24.f));
    float w = winr * winc * (1.f / 576.f);
    float2 v = b0[t];
    b0[t] = make_float2(v.x * w, v.y * w);
  }
  __syncthreads();
  dft24(b0, b1, t, -1.f, false); __syncthreads();
  dft24(b1, b0, t, -1.f, true);  __syncthreads();
  int p = (r + 12) % 24, q = (c + 12) % 24;
  spec[f * 576 + p * 24 + q] = b0[t];
}

// ---------------- Stage 2: build split B and X0 = I + B/4 ----------------
__global__ void buildBX(const float2* __restrict__ spec, __hip_bfloat16* __restrict__ B,
                        __hip_bfloat16* __restrict__ X0, int c0, float scale) {
  int idx = blockIdx.x * 256 + threadIdx.x;   // 0..331775 (row*576+col, row<576)
  int cl = blockIdx.y;
  int c = c0 + cl;
  int row = idx / NK, col = idx % NK;
  int i = row / 24, j = row % 24, a = col / 24, b = col % 24;
  int u = 11 - i + a, v = 11 - j + b;
  float br = 0.f, bi = 0.f;
  if (u >= 0 && u < 24 && v >= 0 && v < 24) {
    float2 s0 = spec[(c * 2 + 0) * 576 + u * 24 + v];
    float2 s1 = spec[(c * 2 + 1) * 576 + u * 24 + v];
    float kx = (float)(a - 11), ky = (float)(b - 11);
    float xr = s0.x * kx + s1.x * ky;
    float xi = s0.y * kx + s1.y * ky;
    br = xi * scale;
    bi = -xr * scale;
  }
  size_t off = (size_t)cl * SETSTR + idx;
  __hip_bfloat16 h, l;
  bsplit(br, h, l); B[off] = h; B[off + PLN] = l;
  bsplit(bi, h, l); B[off + 2 * PLN] = h; B[off + 3 * PLN] = l;
  float d = (row == col) ? 1.f : 0.f;
  bsplit(br * 0.25f + d, h, l); X0[off] = h; X0[off + PLN] = l;
  bsplit(bi * 0.25f, h, l);     X0[off + 2 * PLN] = h; X0[off + 3 * PLN] = l;
}

// ---------------- transpose the 4 split planes ----------------
__global__ __launch_bounds__(256) void transpose4(const __hip_bfloat16* __restrict__ src,
                                                  __hip_bfloat16* __restrict__ dst) {
  __shared__ __hip_bfloat16 tile[64][65];
  int cl = blockIdx.z;
  size_t off = (size_t)cl * SETSTR;
  int rB = blockIdx.y * 64, cB = blockIdx.x * 64;
  int tx = threadIdx.x & 63, ty = threadIdx.x >> 6;
  for (int p = 0; p < 4; ++p) {
    for (int li = 0; li < 16; ++li) {
      int r = ty * 16 + li;
      tile[r][tx] = src[off + (size_t)p * PLN + (size_t)(rB + r) * NK + cB + tx];
    }
    __syncthreads();
    for (int li = 0; li < 16; ++li) {
      int r = ty * 16 + li;
      dst[off + (size_t)p * PLN + (size_t)(cB + r) * NK + rB + tx] = tile[tx][r];
    }
    __syncthreads();
  }
}

// ---------------- Stage 3: batched split-complex MFMA GEMM, 128x192 tile ----------------
// D = alpha*(A*B) + delta*I.  A row-major [m][k] split planes; B given as BT [n][k].
// wf bit0: write D (row-major); bit1: write DT (transposed).
// 15 tiles/channel (5 row x 3 col) -> 240 blocks = ONE dispatch round on 256 CUs.
__global__ __launch_bounds__(512, 2) void cgemm_mfma(
    const __hip_bfloat16* __restrict__ A, const __hip_bfloat16* __restrict__ BT,
    __hip_bfloat16* __restrict__ D, __hip_bfloat16* __restrict__ DT,
    float alpha, float delta, int wf) {
  __shared__ char lds[2][81920];   // per buf: A planes @0 (4*8192), B planes @32768 (4*12288)
  const int t = threadIdx.x;
  const int lane = t & 63;
  const int wid = t >> 6;
  const int wm = wid >> 2, wn = wid & 3;          // 2 x 4 waves, wave tile 64x48
  // block remap: XCD-local channels when full 16-channel group (240 % 8 == 0, bijective)
  int p0 = blockIdx.x;
  int cl, tile;
  if (gridDim.x == 240) {
    int idx = p0 >> 3;
    cl = (p0 & 7) + 8 * (idx / 15);
    tile = idx % 15;
  } else {
    cl = p0 / 15;
    tile = p0 % 15;
  }
  const int rowBase = (tile / 3) * 128, colBase = (tile % 3) * 192;
  const size_t chOff = (size_t)cl * SETSTR;
  const __hip_bfloat16* Ab = A + chOff;
  const __hip_bfloat16* Bb = BT + chOff;

  // staging: A 2048 + B 3072 16B-chunks per buffer; 10 chunks/thread
  size_t gA[4], gB[6];
  int ldsA[4], ldsB[6];
#pragma unroll
  for (int i = 0; i < 4; ++i) {
    int cid = i * 512 + t;                 // 0..2047
    int pp = cid >> 9, r = (cid >> 2) & 127, cp = cid & 3;
    int cg = cp ^ ((r >> 1) & 3);
    gA[i] = (size_t)pp * PLN + (size_t)(rowBase + r) * NK + cg * 8;
    ldsA[i] = cid * 16;
  }
#pragma unroll
  for (int i = 0; i < 6; ++i) {
    int cid = i * 512 + t;                 // 0..3071
    int pp = cid / 768, rem = cid % 768;
    int r = rem >> 2, cp = rem & 3;
    int cg = cp ^ ((r >> 1) & 3);
    gB[i] = (size_t)pp * PLN + (size_t)(colBase + r) * NK + cg * 8;
    ldsB[i] = 32768 + cid * 16;
  }
  // fragment read offsets
  int aoff[4], boff[3];
#pragma unroll
  for (int mi = 0; mi < 4; ++mi) {
    int ra = wm * 64 + mi * 16 + (lane & 15);
    int ch = (lane >> 4) ^ ((ra >> 1) & 3);
    aoff[mi] = (ra * 4 + ch) * 16;
  }
#pragma unroll
  for (int ni = 0; ni < 3; ++ni) {
    int cb = wn * 48 + ni * 16 + (lane & 15);
    int ch = (lane >> 4) ^ ((cb >> 1) & 3);
    boff[ni] = 32768 + (cb * 4 + ch) * 16;
  }

  f32x4 accP[4][3] = {}, accN[4][3] = {}, accI[4][3] = {};

  // prologue: tile 0 into buf 0
#pragma unroll
  for (int i = 0; i < 4; ++i) gld16(Ab + gA[i], &lds[0][ldsA[i]]);
#pragma unroll
  for (int i = 0; i < 6; ++i) gld16(Bb + gB[i], &lds[0][ldsB[i]]);

#pragma unroll 1
  for (int ks = 0; ks < 18; ++ks) {
    const int cur = ks & 1;
    const int k1 = (ks + 1) * 32;
    asm volatile("s_waitcnt vmcnt(0)" ::: "memory");   // tile ks landed (issued last kstep)
    __builtin_amdgcn_sched_barrier(0);
    __builtin_amdgcn_s_barrier();                      // prev kstep reads done; buf cur valid
    __builtin_amdgcn_sched_barrier(0);

    short8 brh[3], brl[3], bih[3], bil[3];
#pragma unroll
    for (int ni = 0; ni < 3; ++ni) {
      const char* base = &lds[cur][boff[ni]];
      brh[ni] = *(const short8*)(base);
      brl[ni] = *(const short8*)(base + 12288);
      bih[ni] = *(const short8*)(base + 24576);
      bil[ni] = *(const short8*)(base + 36864);
    }
#pragma unroll
    for (int p = 0; p < 4; ++p) {
      short8 arh, arl, aih, ail;
      {
        const char* base = &lds[cur][aoff[p]];
        arh = *(const short8*)(base);
        arl = *(const short8*)(base + 8192);
        aih = *(const short8*)(base + 16384);
        ail = *(const short8*)(base + 24576);
      }
      if (ks < 17) {                       // issue next-tile staging across phases 0..2
        if (p == 0) {
          gld16(Ab + gA[0] + k1, &lds[cur ^ 1][ldsA[0]]);
          gld16(Ab + gA[1] + k1, &lds[cur ^ 1][ldsA[1]]);
          gld16(Ab + gA[2] + k1, &lds[cur ^ 1][ldsA[2]]);
          gld16(Ab + gA[3] + k1, &lds[cur ^ 1][ldsA[3]]);
        } else if (p == 1) {
          gld16(Bb + gB[0] + k1, &lds[cur ^ 1][ldsB[0]]);
          gld16(Bb + gB[1] + k1, &lds[cur ^ 1][ldsB[1]]);
          gld16(Bb + gB[2] + k1, &lds[cur ^ 1][ldsB[2]]);
        } else if (p == 2) {
          gld16(Bb + gB[3] + k1, &lds[cur ^ 1][ldsB[3]]);
          gld16(Bb + gB[4] + k1, &lds[cur ^ 1][ldsB[4]]);
          gld16(Bb + gB[5] + k1, &lds[cur ^ 1][ldsB[5]]);
        }
      }
      __builtin_amdgcn_s_setprio(1);
#pragma unroll
      for (int ni = 0; ni < 3; ++ni) {
        accP[p][ni] = MFMA16(arh, brh[ni], accP[p][ni]);
        accP[p][ni] = MFMA16(arh, brl[ni], accP[p][ni]);
        accP[p][ni] = MFMA16(arl, brh[ni], accP[p][ni]);
        accN[p][ni] = MFMA16(aih, bih[ni], accN[p][ni]);
        accN[p][ni] = MFMA16(aih, bil[ni], accN[p][ni]);
        accN[p][ni] = MFMA16(ail, bih[ni], accN[p][ni]);
        accI[p][ni] = MFMA16(arh, bih[ni], accI[p][ni]);
        accI[p][ni] = MFMA16(arh, bil[ni], accI[p][ni]);
        accI[p][ni] = MFMA16(arl, bih[ni], accI[p][ni]);
        accI[p][ni] = MFMA16(aih, brh[ni], accI[p][ni]);
        accI[p][ni] = MFMA16(aih, brl[ni], accI[p][ni]);
        accI[p][ni] = MFMA16(ail, brh[ni], accI[p][ni]);
      }
      __builtin_amdgcn_s_setprio(0);
    }
    __builtin_amdgcn_sched_barrier(0);   // keep this kstep's LDS reads above next barrier
  }

  __hip_bfloat16* Dp = D + chOff;
  __hip_bfloat16* Tp = DT + chOff;
#pragma unroll
  for (int mi = 0; mi < 4; ++mi)
#pragma unroll
    for (int ni = 0; ni < 3; ++ni) {
      int rb = rowBase + wm * 64 + mi * 16 + (lane >> 4) * 4;
      int cc = colBase + wn * 48 + ni * 16 + (lane & 15);
      if (rb >= NK) continue;   // cols always < 576; rb quad fully valid when rb < 576
      short hR[4], lR[4], hI[4], lI[4];
#pragma unroll
      for (int j = 0; j < 4; ++j) {
        float vR = alpha * (accP[mi][ni][j] - accN[mi][ni][j]) + ((rb + j == cc) ? delta : 0.f);
        float vI = alpha * accI[mi][ni][j];
        __hip_bfloat16 h, l;
        bsplit(vR, h, l); hR[j] = braw(h); lR[j] = braw(l);
        bsplit(vI, h, l); hI[j] = braw(h); lI[j] = braw(l);
      }
      if (wf & 1) {
#pragma unroll
        for (int j = 0; j < 4; ++j) {
          size_t o = (size_t)(rb + j) * NK + cc;
          *(short*)&Dp[o] = hR[j];
          *(short*)&Dp[PLN + o] = lR[j];
          *(short*)&Dp[2 * PLN + o] = hI[j];
          *(short*)&Dp[3 * PLN + o] = lI[j];
        }
      }
      if (wf & 2) {
        size_t o = (size_t)cc * NK + rb;
        short4v vR4 = {hR[0], hR[1], hR[2], hR[3]};
        short4v vL4 = {lR[0], lR[1], lR[2], lR[3]};
        short4v vI4 = {hI[0], hI[1], hI[2], hI[3]};
        short4v vJ4 = {lI[0], lI[1], lI[2], lI[3]};
        *(short4v*)&Tp[o] = vR4;
        *(short4v*)&Tp[PLN + o] = vL4;
        *(short4v*)&Tp[2 * PLN + o] = vI4;
        *(short4v*)&Tp[3 * PLN + o] = vJ4;
      }
    }
}

// ---------------- Stage 4: slice + roll + separable DFTs (LDS twiddle tables) ----------------
__global__ void passA(const __hip_bfloat16* __restrict__ X, float2* __restrict__ P) {
  __shared__ float2 tw[20];
  if (threadIdx.x < 20) {
    float s, c;
    sincosf((TAU / 20.f) * (float)threadIdx.x, &s, &c);
    tw[threadIdx.x] = make_float2(c, s);
  }
  __syncthreads();
  int cl = blockIdx.y;
  int idx = blockIdx.x * 256 + threadIdx.x;
  int v = idx % 20, u = (idx / 20) % 20, q = (idx / 400) % 16, p = idx / 6400;
  int pp = (p + 7) % 16;
  int qq = (q + 7) % 16;
  int row = (pp + 5) * 24 + (qq + 5);
  int uu = (u + 9) % 20;
  int aa = uu + 3;
  const __hip_bfloat16* tb = X + (size_t)cl * SETSTR;
  float2 acc = make_float2(0.f, 0.f);
  for (int vp = 0; vp < 20; ++vp) {
    int vv = (vp + 9) % 20;
    int col = aa * 24 + (vv + 3);
    size_t o = (size_t)row * NK + col;
    float xr = __bfloat162float(tb[o]) + __bfloat162float(tb[PLN + o]);
    float xi = __bfloat162float(tb[2 * PLN + o]) + __bfloat162float(tb[3 * PLN + o]);
    float2 w = tw[(v * vp) % 20];
    acc.x += xr * w.x - xi * w.y;
    acc.y += xr * w.y + xi * w.x;
  }
  P[(size_t)cl * MAPSZ + idx] = acc;
}

__global__ void passB(const float2* __restrict__ Pin, float2* __restrict__ Pout) {
  __shared__ float2 tw[20];
  if (threadIdx.x < 20) {
    float s, c;
    sincosf((TAU / 20.f) * (float)threadIdx.x, &s, &c);
    tw[threadIdx.x] = make_float2(c, s);
  }
  __syncthreads();
  int cl = blockIdx.y;
  int idx = blockIdx.x * 256 + threadIdx.x;
  int v = idx % 20, u = (idx / 20) % 20, q = (idx / 400) % 16, p = idx / 6400;
  const float2* in = Pin + (size_t)cl * MAPSZ;
  float2 acc = make_float2(0.f, 0.f);
  for (int up = 0; up < 20; ++up) {
    float2 val = in[(p * 16 + q) * 400 + up * 20 + v];
    float2 w = tw[(u * up) % 20];
    acc.x += val.x * w.x - val.y * w.y;
    acc.y += val.x * w.y + val.y * w.x;
  }
  Pout[(size_t)cl * MAPSZ + idx] = acc;
}

__global__ void passC(const float2* __restrict__ Pin, float2* __restrict__ Pout) {
  __shared__ float2 tw[16];
  if (threadIdx.x < 16) {
    float s, c;
    sincosf(-(TAU / 16.f) * (float)threadIdx.x, &s, &c);
    tw[threadIdx.x] = make_float2(c, s);
  }
  __syncthreads();
  int cl = blockIdx.y;
  int idx = blockIdx.x * 256 + threadIdx.x;
  int v = idx % 20, u = (idx / 20) % 20, q = (idx / 400) % 16, p = idx / 6400;
  const float2* in = Pin + (size_t)cl * MAPSZ;
  float2 acc = make_float2(0.f, 0.f);
  for (int qp = 0; qp < 16; ++qp) {
    float2 val = in[(p * 16 + qp) * 400 + u * 20 + v];
    float2 w = tw[(q * qp) % 16];
    acc.x += val.x * w.x - val.y * w.y;
    acc.y += val.x * w.y + val.y * w.x;
  }
  Pout[(size_t)cl * MAPSZ + idx] = acc;
}

// passD: final DFT, write split-bf16 m directly into padded [n][KOUT] planes
__global__ void passD(const float2* __restrict__ Pin, __hip_bfloat16* __restrict__ ms, int c0) {
  __shared__ float2 tw[16];
  if (threadIdx.x < 16) {
    float s, c;
    sincosf(-(TAU / 16.f) * (float)threadIdx.x, &s, &c);
    tw[threadIdx.x] = make_float2(c, s);
  }
  __syncthreads();
  int cl = blockIdx.y;
  int c = c0 + cl;
  int idx = blockIdx.x * 256 + threadIdx.x;
  int v = idx % 20, u = (idx / 20) % 20, q = (idx / 400) % 16, p = idx / 6400;
  const float2* in = Pin + (size_t)cl * MAPSZ;
  float acc = 0.f;
  for (int pp = 0; pp < 16; ++pp) {
    float2 val = in[(pp * 16 + q) * 400 + u * 20 + v];
    float2 w = tw[(p * pp) % 16];
    acc += val.x * w.x - val.y * w.y;
  }
  acc *= (1.f / 400.f);
  int n = c * 256 + idx / 400;          // o = p*16+q
  int k = idx % 400;                    // k = u*20+v
  __hip_bfloat16 h, l;
  bsplit(acc, h, l);
  ms[(size_t)n * KOUT + k] = h;
  ms[MPL + (size_t)n * KOUT + k] = l;
}

// zero the k in [400,416) pad of the m planes
__global__ void pad_m(__hip_bfloat16* __restrict__ ms) {
  int idx = blockIdx.x * 256 + threadIdx.x;   // 4096*16*2
  int p = idx >> 16;
  int rem = idx & 65535;
  int n = rem >> 4;
  int k = 400 + (rem & 15);
  ms[(size_t)p * MPL + (size_t)n * KOUT + k] = __float2bfloat16(0.f);
}

// convert x (8192x400 f32) to bf16 padded [8192][KOUT] (hi only)
__global__ void prep_x(const float* __restrict__ x, __hip_bfloat16* __restrict__ xs) {
  int idx = blockIdx.x * 256 + threadIdx.x;   // 8192*52
  if (idx >= 8192 * 52) return;
  int b = idx / 52, c8 = idx % 52;
  int k = c8 * 8;
  short8 hh = {};
  if (k < 400) {
    const float4* xp = (const float4*)(x + (size_t)b * 400 + k);
    float4 v0 = xp[0], v1 = xp[1];
    float vals[8] = {v0.x, v0.y, v0.z, v0.w, v1.x, v1.y, v1.z, v1.w};
#pragma unroll
    for (int i = 0; i < 8; ++i) hh[i] = braw(__float2bfloat16(vals[i]));
  }
  *(short8*)(xs + (size_t)b * KOUT + k) = hh;
}

// ---------------- Stage 5: output GEMM, x bf16 x m split-bf16, 128x128 tile ----------------
// LDS per buf: A 8KB (1 plane) + B 16KB (2 planes) = 24KB; 48KB total -> 3 blocks/CU.
__global__ __launch_bounds__(512, 2) void out_mfma(
    const __hip_bfloat16* __restrict__ xs, const __hip_bfloat16* __restrict__ ms,
    float* __restrict__ Y) {
  __shared__ char lds[2][24576];   // A @0 (8192), B planes @8192 (2*8192)
  const int t = threadIdx.x;
  const int lane = t & 63;
  const int wid = t >> 6;
  const int wm = wid >> 2, wn = wid & 3;
  const int rowBase = blockIdx.y * 128, colBase = blockIdx.x * 128;

  size_t gA1, gB[2];
  int ldsA1, ldsB[2];
  {
    int cid = t;                          // 0..511 A chunks
    int r = (cid >> 2) & 127, cp = cid & 3;
    int cg = cp ^ ((r >> 1) & 3);
    gA1 = (size_t)(rowBase + r) * KOUT + cg * 8;
    ldsA1 = cid * 16;
  }
#pragma unroll
  for (int i = 0; i < 2; ++i) {
    int cid = i * 512 + t;                // 0..1023 B chunks
    int pp = cid >> 9, r = (cid >> 2) & 127, cp = cid & 3;
    int cg = cp ^ ((r >> 1) & 3);
    gB[i] = (size_t)pp * MPL + (size_t)(colBase + r) * KOUT + cg * 8;
    ldsB[i] = 8192 + cid * 16;
  }
  int aoff[4], boff[2];
#pragma unroll
  for (int mi = 0; mi < 4; ++mi) {
    int ra = wm * 64 + mi * 16 + (lane & 15);
    int ch = (lane >> 4) ^ ((ra >> 1) & 3);
    aoff[mi] = (ra * 4 + ch) * 16;
  }
#pragma unroll
  for (int ni = 0; ni < 2; ++ni) {
    int cb = wn * 32 + ni * 16 + (lane & 15);
    int ch = (lane >> 4) ^ ((cb >> 1) & 3);
    boff[ni] = 8192 + (cb * 4 + ch) * 16;
  }

  f32x4 acc[4][2] = {};

  // prologue
  gld16(xs + gA1, &lds[0][ldsA1]);
  gld16(ms + gB[0], &lds[0][ldsB[0]]);
  gld16(ms + gB[1], &lds[0][ldsB[1]]);

#pragma unroll 1
  for (int ks = 0; ks < 13; ++ks) {
    int cur = ks & 1;
    int k1 = (ks + 1) * 32;
    asm volatile("s_waitcnt vmcnt(0)" ::: "memory");
    __builtin_amdgcn_sched_barrier(0);
    __builtin_amdgcn_s_barrier();
    __builtin_amdgcn_sched_barrier(0);
    short8 bh[2], bl[2];
#pragma unroll
    for (int ni = 0; ni < 2; ++ni) {
      const char* base = &lds[cur][boff[ni]];
      bh[ni] = *(const short8*)(base);
      bl[ni] = *(const short8*)(base + 8192);
    }
#pragma unroll
    for (int mi = 0; mi < 4; ++mi) {
      short8 ah;
      {
        const char* base = &lds[cur][aoff[mi]];
        ah = *(const short8*)(base);
      }
      if (ks < 12) {
        if (mi == 0) gld16(xs + gA1 + k1, &lds[cur ^ 1][ldsA1]);
        else if (mi == 1) gld16(ms + gB[0] + k1, &lds[cur ^ 1][ldsB[0]]);
        else if (mi == 2) gld16(ms + gB[1] + k1, &lds[cur ^ 1][ldsB[1]]);
      }
      __builtin_amdgcn_s_setprio(1);
#pragma unroll
      for (int ni = 0; ni < 2; ++ni) {
        acc[mi][ni] = MFMA16(ah, bh[ni], acc[mi][ni]);
        acc[mi][ni] = MFMA16(ah, bl[ni], acc[mi][ni]);
      }
      __builtin_amdgcn_s_setprio(0);
    }
    __builtin_amdgcn_sched_barrier(0);
  }

#pragma unroll
  for (int mi = 0; mi < 4; ++mi)
#pragma unroll
    for (int ni = 0; ni < 2; ++ni) {
      int rb = rowBase + wm * 64 + mi * 16 + (lane >> 4) * 4;
      int cc = colBase + wn * 32 + ni * 16 + (lane & 15);
#pragma unroll
      for (int j = 0; j < 4; ++j)
        Y[(size_t)(rb + j) * 4096 + cc] = acc[mi][ni][j];
    }
}

// ---------------- Launcher ----------------
extern "C" void kernel_launch(void* const* d_in, const int* in_sizes, int n_in,
                              void* d_out, int out_size, void* d_ws, size_t ws_size,
                              hipStream_t stream) {
  const float* x = (const float*)d_in[0];     // (8192,1,20,20)
  const float* sig = (const float*)d_in[1];   // (16,2,24,24)
  float* out = (float*)d_out;                 // (8192,16,16,16)
  char* ws = (char*)d_ws;

  const size_t specBytes = 32ull * 576 * sizeof(float2);
  const size_t xsBytes = XPL * 2;                       // one bf16 plane
  const size_t msBytes = 2ull * MPL * 2;
  const size_t fixed = specBytes + xsBytes + msBytes;
  const size_t setB = SETSTR * 2;                       // bytes per split set
  const size_t perCh = 5 * setB + 2ull * MAPSZ * 8;     // B, X0, X0T, X1, X1T + P0/P1

  int cg = 1;
  if (ws_size > fixed) {
    size_t av = (ws_size - fixed) / perCh;
    cg = (av < 1) ? 1 : (av > 16 ? 16 : (int)av);
  }

  float2* spec = (float2*)ws;
  __hip_bfloat16* xs = (__hip_bfloat16*)(ws + specBytes);
  __hip_bfloat16* ms = (__hip_bfloat16*)(ws + specBytes + xsBytes);
  __hip_bfloat16* Bst = (__hip_bfloat16*)(ws + fixed);
  __hip_bfloat16* X0 = Bst + (size_t)cg * SETSTR;
  __hip_bfloat16* X0T = X0 + (size_t)cg * SETSTR;
  __hip_bfloat16* X1 = X0T + (size_t)cg * SETSTR;
  __hip_bfloat16* X1T = X1 + (size_t)cg * SETSTR;
  float2* P0 = (float2*)(X1T + (size_t)cg * SETSTR);
  float2* P1 = P0 + (size_t)cg * MAPSZ;

  spectrum_kernel<<<dim3(32), dim3(576), 0, stream>>>(sig, spec);
  prep_x<<<dim3((8192 * 52 + 255) / 256), dim3(256), 0, stream>>>(x, xs);
  pad_m<<<dim3(512), dim3(256), 0, stream>>>(ms);

  const float scale = 1.f / 64.f;  // s = 6 squarings
  for (int c0 = 0; c0 < 16; c0 += cg) {
    int g = (16 - c0 < cg) ? (16 - c0) : cg;
    buildBX<<<dim3(1296, g), dim3(256), 0, stream>>>(spec, Bst, X0, c0, scale);
    transpose4<<<dim3(9, 9, g), dim3(256), 0, stream>>>(X0, X0T);
    __hip_bfloat16 *xr = X0, *xt = X0T, *yr = X1, *yt = X1T;
    // Horner (Taylor order 4): X <- I + (B*X)/k, k=3..1. Only DT consumed until k=1.
    for (int k = 3; k >= 1; --k) {
      int wf = (k == 1) ? 3 : 2;
      cgemm_mfma<<<dim3(15 * g), dim3(512), 0, stream>>>(Bst, xt, yr, yt,
                                                         1.f / (float)k, 1.f, wf);
      __hip_bfloat16* tmp;
      tmp = xr; xr = yr; yr = tmp;
      tmp = xt; xt = yt; yt = tmp;
    }
    // 6 squarings; last one only needs row-major output (feeds passA)
    for (int t8 = 0; t8 < 6; ++t8) {
      int wf = (t8 == 5) ? 1 : 3;
      cgemm_mfma<<<dim3(15 * g), dim3(512), 0, stream>>>(xr, xt, yr, yt, 1.f, 0.f, wf);
      __hip_bfloat16* tmp;
      tmp = xr; xr = yr; yr = tmp;
      tmp = xt; xt = yt; yt = tmp;
    }
    passA<<<dim3(400, g), dim3(256), 0, stream>>>(xr, P0);
    passB<<<dim3(400, g), dim3(256), 0, stream>>>(P0, P1);
    passC<<<dim3(400, g), dim3(256), 0, stream>>>(P1, P0);
    passD<<<dim3(400, g), dim3(256), 0, stream>>>(P0, ms, c0);
  }

  out_mfma<<<dim3(32, 64), dim3(512), 0, stream>>>(xs, ms, out);
}

// Round 11
// 845.533 us; speedup vs baseline: 7.8334x; 1.0742x over previous
//
#include <hip/hip_runtime.h>
#include <hip/hip_bf16.h>
#include <math.h>

#define TAU 6.283185307179586f
#define NK 576                    // matrix dimension (K always exact: 18*32)
#define NPAD 640                  // padded row count for 128-row tiles
#define PLN ((size_t)NPAD * NK)   // elems per padded plane = 368640
#define SETSTR ((size_t)4 * PLN)  // elems per 4-plane split set
#define MAPSZ 102400              // 16*16*20*20
#define KOUT 416                  // padded K for output gemm (13*32)
#define XPL ((size_t)8192 * KOUT)
#define MPL ((size_t)4096 * KOUT)

typedef __attribute__((ext_vector_type(8))) short short8;
typedef __attribute__((ext_vector_type(4))) short short4v;
typedef __attribute__((ext_vector_type(4))) float f32x4;

__device__ inline void bsplit(float v, __hip_bfloat16& h, __hip_bfloat16& l) {
  h = __float2bfloat16(v);
  l = __float2bfloat16(v - __bfloat162float(h));
}
__device__ inline short braw(__hip_bfloat16 b) { return *reinterpret_cast<short*>(&b); }

__device__ inline void gld16(const void* g, const void* l) {
  __builtin_amdgcn_global_load_lds((const __attribute__((address_space(1))) unsigned*)g,
                                   (__attribute__((address_space(3))) unsigned*)l, 16, 0, 0);
}

#define MFMA16(a, b, c) __builtin_amdgcn_mfma_f32_16x16x32_bf16(a, b, c, 0, 0, 0)

// ---------------- Stage 1: signal -> spectrum ----------------
__device__ inline void dft24(const float2* in, float2* out, int t, float sgn, bool firstAxis) {
  int r = t / 24, c = t % 24;
  int kk = firstAxis ? r : c;
  float2 acc = make_float2(0.f, 0.f);
  for (int n = 0; n < 24; ++n) {
    float ang = sgn * (TAU / 24.f) * (float)((kk * n) % 24);
    float s, co;
    sincosf(ang, &s, &co);
    float2 v = firstAxis ? in[n * 24 + c] : in[r * 24 + n];
    acc.x += v.x * co - v.y * s;
    acc.y += v.x * s + v.y * co;
  }
  out[t] = acc;
}

__global__ void spectrum_kernel(const float* __restrict__ sig, float2* __restrict__ spec) {
  __shared__ float2 b0[576];
  __shared__ float2 b1[576];
  int f = blockIdx.x;
  int t = threadIdx.x;
  int r = t / 24, c = t % 24;
  b0[t] = make_float2(sig[f * 576 + t], 0.f);
  __syncthreads();
  dft24(b0, b1, t, -1.f, false); __syncthreads();
  dft24(b1, b0, t, -1.f, true);  __syncthreads();
  {
    int p2 = (r + 12) % 24 - 11;
    int q2 = (c + 12) % 24 - 11;
    float rr = (float)(1 + p2 * p2 + q2 * q2) * 5.f;
    float2 v = b0[t];
    b0[t] = make_float2(v.x / rr, v.y / rr);
  }
  __syncthreads();
  dft24(b0, b1, t, +1.f, false); __syncthreads();
  dft24(b1, b0, t, +1.f, true);  __syncthreads();
  {
    float winr = 0.5f * (1.f - cosf(TAU * (float)r / 24.f));
    float winc = 0.5f * (1.f - cosf(TAU * (float)c / 24.f));
    float w = winr * winc * (1.f / 576.f);
    float2 v = b0[t];
    b0[t] = make_float2(v.x * w, v.y * w);
  }
  __syncthreads();
  dft24(b0, b1, t, -1.f, false); __syncthreads();
  dft24(b1, b0, t, -1.f, true);  __syncthreads();
  int p = (r + 12) % 24, q = (c + 12) % 24;
  spec[f * 576 + p * 24 + q] = b0[t];
}

// ---------------- Stage 2: build split B and X0 = I + B/3 ----------------
__global__ void buildBX(const float2* __restrict__ spec, __hip_bfloat16* __restrict__ B,
                        __hip_bfloat16* __restrict__ X0, int c0, float scale) {
  int idx = blockIdx.x * 256 + threadIdx.x;   // 0..331775 (row*576+col, row<576)
  int cl = blockIdx.y;
  int c = c0 + cl;
  int row = idx / NK, col = idx % NK;
  int i = row / 24, j = row % 24, a = col / 24, b = col % 24;
  int u = 11 - i + a, v = 11 - j + b;
  float br = 0.f, bi = 0.f;
  if (u >= 0 && u < 24 && v >= 0 && v < 24) {
    float2 s0 = spec[(c * 2 + 0) * 576 + u * 24 + v];
    float2 s1 = spec[(c * 2 + 1) * 576 + u * 24 + v];
    float kx = (float)(a - 11), ky = (float)(b - 11);
    float xr = s0.x * kx + s1.x * ky;
    float xi = s0.y * kx + s1.y * ky;
    br = xi * scale;
    bi = -xr * scale;
  }
  size_t off = (size_t)cl * SETSTR + idx;
  __hip_bfloat16 h, l;
  bsplit(br, h, l); B[off] = h; B[off + PLN] = l;
  bsplit(bi, h, l); B[off + 2 * PLN] = h; B[off + 3 * PLN] = l;
  float d = (row == col) ? 1.f : 0.f;
  bsplit(br * (1.f / 3.f) + d, h, l); X0[off] = h; X0[off + PLN] = l;
  bsplit(bi * (1.f / 3.f), h, l);     X0[off + 2 * PLN] = h; X0[off + 3 * PLN] = l;
}

// ---------------- transpose the 4 split planes ----------------
__global__ __launch_bounds__(256) void transpose4(const __hip_bfloat16* __restrict__ src,
                                                  __hip_bfloat16* __restrict__ dst) {
  __shared__ __hip_bfloat16 tile[64][65];
  int cl = blockIdx.z;
  size_t off = (size_t)cl * SETSTR;
  int rB = blockIdx.y * 64, cB = blockIdx.x * 64;
  int tx = threadIdx.x & 63, ty = threadIdx.x >> 6;
  for (int p = 0; p < 4; ++p) {
    for (int li = 0; li < 16; ++li) {
      int r = ty * 16 + li;
      tile[r][tx] = src[off + (size_t)p * PLN + (size_t)(rB + r) * NK + cB + tx];
    }
    __syncthreads();
    for (int li = 0; li < 16; ++li) {
      int r = ty * 16 + li;
      dst[off + (size_t)p * PLN + (size_t)(cB + r) * NK + rB + tx] = tile[tx][r];
    }
    __syncthreads();
  }
}

// ---------------- Stage 3: batched split-complex MFMA GEMM, 128x192 tile ----------------
// D = alpha*(A*B) + delta*I.  A row-major [m][k] split planes; B given as BT [n][k].
// wf bit0: write D (row-major); bit1: write DT (transposed).
// 15 tiles/channel (5 row x 3 col) -> 240 blocks = ONE dispatch round on 256 CUs.
// Wave-phase STAGGER: wm=1 waves process A-phases in order 2,3,0,1 so the two waves
// sharing a SIMD are 2 phases apart -> one wave's ds_reads overlap the other's MFMAs.
__global__ __launch_bounds__(512, 2) void cgemm_mfma(
    const __hip_bfloat16* __restrict__ A, const __hip_bfloat16* __restrict__ BT,
    __hip_bfloat16* __restrict__ D, __hip_bfloat16* __restrict__ DT,
    float alpha, float delta, int wf) {
  __shared__ char lds[2][81920];   // per buf: A planes @0 (4*8192), B planes @32768 (4*12288)
  const int t = threadIdx.x;
  const int lane = t & 63;
  const int wid = t >> 6;
  const int wm = wid >> 2, wn = wid & 3;          // 2 x 4 waves, wave tile 64x48
  // block remap: XCD-local channels when full 16-channel group (240 % 8 == 0, bijective)
  int p0 = blockIdx.x;
  int cl, tile;
  if (gridDim.x == 240) {
    int idx = p0 >> 3;
    cl = (p0 & 7) + 8 * (idx / 15);
    tile = idx % 15;
  } else {
    cl = p0 / 15;
    tile = p0 % 15;
  }
  const int rowBase = (tile / 3) * 128, colBase = (tile % 3) * 192;
  const size_t chOff = (size_t)cl * SETSTR;
  const __hip_bfloat16* Ab = A + chOff;
  const __hip_bfloat16* Bb = BT + chOff;

  // staging: A 2048 + B 3072 16B-chunks per buffer; 10 chunks/thread
  size_t gA[4], gB[6];
  int ldsA[4], ldsB[6];
#pragma unroll
  for (int i = 0; i < 4; ++i) {
    int cid = i * 512 + t;                 // 0..2047
    int pp = cid >> 9, r = (cid >> 2) & 127, cp = cid & 3;
    int cg = cp ^ ((r >> 1) & 3);
    gA[i] = (size_t)pp * PLN + (size_t)(rowBase + r) * NK + cg * 8;
    ldsA[i] = cid * 16;
  }
#pragma unroll
  for (int i = 0; i < 6; ++i) {
    int cid = i * 512 + t;                 // 0..3071
    int pp = cid / 768, rem = cid % 768;
    int r = rem >> 2, cp = rem & 3;
    int cg = cp ^ ((r >> 1) & 3);
    gB[i] = (size_t)pp * PLN + (size_t)(colBase + r) * NK + cg * 8;
    ldsB[i] = 32768 + cid * 16;
  }
  // fragment read offsets
  int aoff[4], boff[3];
#pragma unroll
  for (int mi = 0; mi < 4; ++mi) {
    int ra = wm * 64 + mi * 16 + (lane & 15);
    int ch = (lane >> 4) ^ ((ra >> 1) & 3);
    aoff[mi] = (ra * 4 + ch) * 16;
  }
#pragma unroll
  for (int ni = 0; ni < 3; ++ni) {
    int cb = wn * 48 + ni * 16 + (lane & 15);
    int ch = (lane >> 4) ^ ((cb >> 1) & 3);
    boff[ni] = 32768 + (cb * 4 + ch) * 16;
  }

  f32x4 accP[4][3] = {}, accN[4][3] = {}, accI[4][3] = {};

  // prologue: tile 0 into buf 0
#pragma unroll
  for (int i = 0; i < 4; ++i) gld16(Ab + gA[i], &lds[0][ldsA[i]]);
#pragma unroll
  for (int i = 0; i < 6; ++i) gld16(Bb + gB[i], &lds[0][ldsB[i]]);

#define STG(I)                                                      \
  if (ks < 17) {                                                    \
    if ((I) == 0) {                                                 \
      gld16(Ab + gA[0] + k1, &lds[cur ^ 1][ldsA[0]]);               \
      gld16(Ab + gA[1] + k1, &lds[cur ^ 1][ldsA[1]]);               \
      gld16(Ab + gA[2] + k1, &lds[cur ^ 1][ldsA[2]]);               \
      gld16(Ab + gA[3] + k1, &lds[cur ^ 1][ldsA[3]]);               \
    } else if ((I) == 1) {                                          \
      gld16(Bb + gB[0] + k1, &lds[cur ^ 1][ldsB[0]]);               \
      gld16(Bb + gB[1] + k1, &lds[cur ^ 1][ldsB[1]]);               \
      gld16(Bb + gB[2] + k1, &lds[cur ^ 1][ldsB[2]]);               \
    } else if ((I) == 2) {                                          \
      gld16(Bb + gB[3] + k1, &lds[cur ^ 1][ldsB[3]]);               \
      gld16(Bb + gB[4] + k1, &lds[cur ^ 1][ldsB[4]]);               \
      gld16(Bb + gB[5] + k1, &lds[cur ^ 1][ldsB[5]]);               \
    }                                                               \
  }

#define MFS(P, NI)                                                  \
  accP[P][NI] = MFMA16(arh, brh[NI], accP[P][NI]);                  \
  accP[P][NI] = MFMA16(arh, brl[NI], accP[P][NI]);                  \
  accP[P][NI] = MFMA16(arl, brh[NI], accP[P][NI]);                  \
  accN[P][NI] = MFMA16(aih, bih[NI], accN[P][NI]);                  \
  accN[P][NI] = MFMA16(aih, bil[NI], accN[P][NI]);                  \
  accN[P][NI] = MFMA16(ail, bih[NI], accN[P][NI]);                  \
  accI[P][NI] = MFMA16(arh, bih[NI], accI[P][NI]);                  \
  accI[P][NI] = MFMA16(arh, bil[NI], accI[P][NI]);                  \
  accI[P][NI] = MFMA16(arl, bih[NI], accI[P][NI]);                  \
  accI[P][NI] = MFMA16(aih, brh[NI], accI[P][NI]);                  \
  accI[P][NI] = MFMA16(aih, brl[NI], accI[P][NI]);                  \
  accI[P][NI] = MFMA16(ail, brh[NI], accI[P][NI]);

#define PHASE(P, I) {                                               \
    short8 arh, arl, aih, ail;                                      \
    {                                                               \
      const char* b_ = &lds[cur][aoff[P]];                          \
      arh = *(const short8*)(b_);                                   \
      arl = *(const short8*)(b_ + 8192);                            \
      aih = *(const short8*)(b_ + 16384);                           \
      ail = *(const short8*)(b_ + 24576);                           \
    }                                                               \
    STG(I)                                                          \
    __builtin_amdgcn_s_setprio(1);                                  \
    MFS(P, 0) MFS(P, 1) MFS(P, 2)                                   \
    __builtin_amdgcn_s_setprio(0);                                  \
  }

#pragma unroll 1
  for (int ks = 0; ks < 18; ++ks) {
    const int cur = ks & 1;
    const int k1 = (ks + 1) * 32;
    asm volatile("s_waitcnt vmcnt(0)" ::: "memory");   // tile ks landed (issued last kstep)
    __builtin_amdgcn_sched_barrier(0);
    __builtin_amdgcn_s_barrier();                      // prev kstep reads done; buf cur valid
    __builtin_amdgcn_sched_barrier(0);

    short8 brh[3], brl[3], bih[3], bil[3];
#pragma unroll
    for (int ni = 0; ni < 3; ++ni) {
      const char* base = &lds[cur][boff[ni]];
      brh[ni] = *(const short8*)(base);
      brl[ni] = *(const short8*)(base + 12288);
      bih[ni] = *(const short8*)(base + 24576);
      bil[ni] = *(const short8*)(base + 36864);
    }
    if (wm == 0) {
      PHASE(0, 0) PHASE(1, 1) PHASE(2, 2) PHASE(3, 3)
    } else {
      PHASE(2, 0) PHASE(3, 1) PHASE(0, 2) PHASE(1, 3)
    }
    __builtin_amdgcn_sched_barrier(0);   // keep this kstep's LDS reads above next barrier
  }

  __hip_bfloat16* Dp = D + chOff;
  __hip_bfloat16* Tp = DT + chOff;
#pragma unroll
  for (int mi = 0; mi < 4; ++mi)
#pragma unroll
    for (int ni = 0; ni < 3; ++ni) {
      int rb = rowBase + wm * 64 + mi * 16 + (lane >> 4) * 4;
      int cc = colBase + wn * 48 + ni * 16 + (lane & 15);
      if (rb >= NK) continue;   // cols always < 576; rb quad fully valid when rb < 576
      short hR[4], lR[4], hI[4], lI[4];
#pragma unroll
      for (int j = 0; j < 4; ++j) {
        float vR = alpha * (accP[mi][ni][j] - accN[mi][ni][j]) + ((rb + j == cc) ? delta : 0.f);
        float vI = alpha * accI[mi][ni][j];
        __hip_bfloat16 h, l;
        bsplit(vR, h, l); hR[j] = braw(h); lR[j] = braw(l);
        bsplit(vI, h, l); hI[j] = braw(h); lI[j] = braw(l);
      }
      if (wf & 1) {
#pragma unroll
        for (int j = 0; j < 4; ++j) {
          size_t o = (size_t)(rb + j) * NK + cc;
          *(short*)&Dp[o] = hR[j];
          *(short*)&Dp[PLN + o] = lR[j];
          *(short*)&Dp[2 * PLN + o] = hI[j];
          *(short*)&Dp[3 * PLN + o] = lI[j];
        }
      }
      if (wf & 2) {
        size_t o = (size_t)cc * NK + rb;
        short4v vR4 = {hR[0], hR[1], hR[2], hR[3]};
        short4v vL4 = {lR[0], lR[1], lR[2], lR[3]};
        short4v vI4 = {hI[0], hI[1], hI[2], hI[3]};
        short4v vJ4 = {lI[0], lI[1], lI[2], lI[3]};
        *(short4v*)&Tp[o] = vR4;
        *(short4v*)&Tp[PLN + o] = vL4;
        *(short4v*)&Tp[2 * PLN + o] = vI4;
        *(short4v*)&Tp[3 * PLN + o] = vJ4;
      }
    }
}

// ---------------- Stage 4: slice + roll + separable DFTs (LDS twiddle tables) ----------------
__global__ void passA(const __hip_bfloat16* __restrict__ X, float2* __restrict__ P) {
  __shared__ float2 tw[20];
  if (threadIdx.x < 20) {
    float s, c;
    sincosf((TAU / 20.f) * (float)threadIdx.x, &s, &c);
    tw[threadIdx.x] = make_float2(c, s);
  }
  __syncthreads();
  int cl = blockIdx.y;
  int idx = blockIdx.x * 256 + threadIdx.x;
  int v = idx % 20, u = (idx / 20) % 20, q = (idx / 400) % 16, p = idx / 6400;
  int pp = (p + 7) % 16;
  int qq = (q + 7) % 16;
  int row = (pp + 5) * 24 + (qq + 5);
  int uu = (u + 9) % 20;
  int aa = uu + 3;
  const __hip_bfloat16* tb = X + (size_t)cl * SETSTR;
  float2 acc = make_float2(0.f, 0.f);
  for (int vp = 0; vp < 20; ++vp) {
    int vv = (vp + 9) % 20;
    int col = aa * 24 + (vv + 3);
    size_t o = (size_t)row * NK + col;
    float xr = __bfloat162float(tb[o]) + __bfloat162float(tb[PLN + o]);
    float xi = __bfloat162float(tb[2 * PLN + o]) + __bfloat162float(tb[3 * PLN + o]);
    float2 w = tw[(v * vp) % 20];
    acc.x += xr * w.x - xi * w.y;
    acc.y += xr * w.y + xi * w.x;
  }
  P[(size_t)cl * MAPSZ + idx] = acc;
}

__global__ void passB(const float2* __restrict__ Pin, float2* __restrict__ Pout) {
  __shared__ float2 tw[20];
  if (threadIdx.x < 20) {
    float s, c;
    sincosf((TAU / 20.f) * (float)threadIdx.x, &s, &c);
    tw[threadIdx.x] = make_float2(c, s);
  }
  __syncthreads();
  int cl = blockIdx.y;
  int idx = blockIdx.x * 256 + threadIdx.x;
  int v = idx % 20, u = (idx / 20) % 20, q = (idx / 400) % 16, p = idx / 6400;
  const float2* in = Pin + (size_t)cl * MAPSZ;
  float2 acc = make_float2(0.f, 0.f);
  for (int up = 0; up < 20; ++up) {
    float2 val = in[(p * 16 + q) * 400 + up * 20 + v];
    float2 w = tw[(u * up) % 20];
    acc.x += val.x * w.x - val.y * w.y;
    acc.y += val.x * w.y + val.y * w.x;
  }
  Pout[(size_t)cl * MAPSZ + idx] = acc;
}

__global__ void passC(const float2* __restrict__ Pin, float2* __restrict__ Pout) {
  __shared__ float2 tw[16];
  if (threadIdx.x < 16) {
    float s, c;
    sincosf(-(TAU / 16.f) * (float)threadIdx.x, &s, &c);
    tw[threadIdx.x] = make_float2(c, s);
  }
  __syncthreads();
  int cl = blockIdx.y;
  int idx = blockIdx.x * 256 + threadIdx.x;
  int v = idx % 20, u = (idx / 20) % 20, q = (idx / 400) % 16, p = idx / 6400;
  const float2* in = Pin + (size_t)cl * MAPSZ;
  float2 acc = make_float2(0.f, 0.f);
  for (int qp = 0; qp < 16; ++qp) {
    float2 val = in[(p * 16 + qp) * 400 + u * 20 + v];
    float2 w = tw[(q * qp) % 16];
    acc.x += val.x * w.x - val.y * w.y;
    acc.y += val.x * w.y + val.y * w.x;
  }
  Pout[(size_t)cl * MAPSZ + idx] = acc;
}

// passD: final DFT, write split-bf16 m directly into padded [n][KOUT] planes
__global__ void passD(const float2* __restrict__ Pin, __hip_bfloat16* __restrict__ ms, int c0) {
  __shared__ float2 tw[16];
  if (threadIdx.x < 16) {
    float s, c;
    sincosf(-(TAU / 16.f) * (float)threadIdx.x, &s, &c);
    tw[threadIdx.x] = make_float2(c, s);
  }
  __syncthreads();
  int cl = blockIdx.y;
  int c = c0 + cl;
  int idx = blockIdx.x * 256 + threadIdx.x;
  int v = idx % 20, u = (idx / 20) % 20, q = (idx / 400) % 16, p = idx / 6400;
  const float2* in = Pin + (size_t)cl * MAPSZ;
  float acc = 0.f;
  for (int pp = 0; pp < 16; ++pp) {
    float2 val = in[(pp * 16 + q) * 400 + u * 20 + v];
    float2 w = tw[(p * pp) % 16];
    acc += val.x * w.x - val.y * w.y;
  }
  acc *= (1.f / 400.f);
  int n = c * 256 + idx / 400;          // o = p*16+q
  int k = idx % 400;                    // k = u*20+v
  __hip_bfloat16 h, l;
  bsplit(acc, h, l);
  ms[(size_t)n * KOUT + k] = h;
  ms[MPL + (size_t)n * KOUT + k] = l;
}

// zero the k in [400,416) pad of the m planes
__global__ void pad_m(__hip_bfloat16* __restrict__ ms) {
  int idx = blockIdx.x * 256 + threadIdx.x;   // 4096*16*2
  int p = idx >> 16;
  int rem = idx & 65535;
  int n = rem >> 4;
  int k = 400 + (rem & 15);
  ms[(size_t)p * MPL + (size_t)n * KOUT + k] = __float2bfloat16(0.f);
}

// convert x (8192x400 f32) to bf16 padded [8192][KOUT] (hi only)
__global__ void prep_x(const float* __restrict__ x, __hip_bfloat16* __restrict__ xs) {
  int idx = blockIdx.x * 256 + threadIdx.x;   // 8192*52
  if (idx >= 8192 * 52) return;
  int b = idx / 52, c8 = idx % 52;
  int k = c8 * 8;
  short8 hh = {};
  if (k < 400) {
    const float4* xp = (const float4*)(x + (size_t)b * 400 + k);
    float4 v0 = xp[0], v1 = xp[1];
    float vals[8] = {v0.x, v0.y, v0.z, v0.w, v1.x, v1.y, v1.z, v1.w};
#pragma unroll
    for (int i = 0; i < 8; ++i) hh[i] = braw(__float2bfloat16(vals[i]));
  }
  *(short8*)(xs + (size_t)b * KOUT + k) = hh;
}

// ---------------- Stage 5: output GEMM, x bf16 x m split-bf16, 128x128 tile ----------------
// LDS per buf: A 8KB (1 plane) + B 16KB (2 planes) = 24KB; 48KB total -> 3 blocks/CU.
__global__ __launch_bounds__(512, 2) void out_mfma(
    const __hip_bfloat16* __restrict__ xs, const __hip_bfloat16* __restrict__ ms,
    float* __restrict__ Y) {
  __shared__ char lds[2][24576];   // A @0 (8192), B planes @8192 (2*8192)
  const int t = threadIdx.x;
  const int lane = t & 63;
  const int wid = t >> 6;
  const int wm = wid >> 2, wn = wid & 3;
  const int rowBase = blockIdx.y * 128, colBase = blockIdx.x * 128;

  size_t gA1, gB[2];
  int ldsA1, ldsB[2];
  {
    int cid = t;                          // 0..511 A chunks
    int r = (cid >> 2) & 127, cp = cid & 3;
    int cg = cp ^ ((r >> 1) & 3);
    gA1 = (size_t)(rowBase + r) * KOUT + cg * 8;
    ldsA1 = cid * 16;
  }
#pragma unroll
  for (int i = 0; i < 2; ++i) {
    int cid = i * 512 + t;                // 0..1023 B chunks
    int pp = cid >> 9, r = (cid >> 2) & 127, cp = cid & 3;
    int cg = cp ^ ((r >> 1) & 3);
    gB[i] = (size_t)pp * MPL + (size_t)(colBase + r) * KOUT + cg * 8;
    ldsB[i] = 8192 + cid * 16;
  }
  int aoff[4], boff[2];
#pragma unroll
  for (int mi = 0; mi < 4; ++mi) {
    int ra = wm * 64 + mi * 16 + (lane & 15);
    int ch = (lane >> 4) ^ ((ra >> 1) & 3);
    aoff[mi] = (ra * 4 + ch) * 16;
  }
#pragma unroll
  for (int ni = 0; ni < 2; ++ni) {
    int cb = wn * 32 + ni * 16 + (lane & 15);
    int ch = (lane >> 4) ^ ((cb >> 1) & 3);
    boff[ni] = 8192 + (cb * 4 + ch) * 16;
  }

  f32x4 acc[4][2] = {};

  // prologue
  gld16(xs + gA1, &lds[0][ldsA1]);
  gld16(ms + gB[0], &lds[0][ldsB[0]]);
  gld16(ms + gB[1], &lds[0][ldsB[1]]);

#pragma unroll 1
  for (int ks = 0; ks < 13; ++ks) {
    int cur = ks & 1;
    int k1 = (ks + 1) * 32;
    asm volatile("s_waitcnt vmcnt(0)" ::: "memory");
    __builtin_amdgcn_sched_barrier(0);
    __builtin_amdgcn_s_barrier();
    __builtin_amdgcn_sched_barrier(0);
    short8 bh[2], bl[2];
#pragma unroll
    for (int ni = 0; ni < 2; ++ni) {
      const char* base = &lds[cur][boff[ni]];
      bh[ni] = *(const short8*)(base);
      bl[ni] = *(const short8*)(base + 8192);
    }
#pragma unroll
    for (int mi = 0; mi < 4; ++mi) {
      short8 ah;
      {
        const char* base = &lds[cur][aoff[mi]];
        ah = *(const short8*)(base);
      }
      if (ks < 12) {
        if (mi == 0) gld16(xs + gA1 + k1, &lds[cur ^ 1][ldsA1]);
        else if (mi == 1) gld16(ms + gB[0] + k1, &lds[cur ^ 1][ldsB[0]]);
        else if (mi == 2) gld16(ms + gB[1] + k1, &lds[cur ^ 1][ldsB[1]]);
      }
      __builtin_amdgcn_s_setprio(1);
#pragma unroll
      for (int ni = 0; ni < 2; ++ni) {
        acc[mi][ni] = MFMA16(ah, bh[ni], acc[mi][ni]);
        acc[mi][ni] = MFMA16(ah, bl[ni], acc[mi][ni]);
      }
      __builtin_amdgcn_s_setprio(0);
    }
    __builtin_amdgcn_sched_barrier(0);
  }

#pragma unroll
  for (int mi = 0; mi < 4; ++mi)
#pragma unroll
    for (int ni = 0; ni < 2; ++ni) {
      int rb = rowBase + wm * 64 + mi * 16 + (lane >> 4) * 4;
      int cc = colBase + wn * 32 + ni * 16 + (lane & 15);
#pragma unroll
      for (int j = 0; j < 4; ++j)
        Y[(size_t)(rb + j) * 4096 + cc] = acc[mi][ni][j];
    }
}

// ---------------- Launcher ----------------
extern "C" void kernel_launch(void* const* d_in, const int* in_sizes, int n_in,
                              void* d_out, int out_size, void* d_ws, size_t ws_size,
                              hipStream_t stream) {
  const float* x = (const float*)d_in[0];     // (8192,1,20,20)
  const float* sig = (const float*)d_in[1];   // (16,2,24,24)
  float* out = (float*)d_out;                 // (8192,16,16,16)
  char* ws = (char*)d_ws;

  const size_t specBytes = 32ull * 576 * sizeof(float2);
  const size_t xsBytes = XPL * 2;                       // one bf16 plane
  const size_t msBytes = 2ull * MPL * 2;
  const size_t fixed = specBytes + xsBytes + msBytes;
  const size_t setB = SETSTR * 2;                       // bytes per split set
  const size_t perCh = 5 * setB + 2ull * MAPSZ * 8;     // B, X0, X0T, X1, X1T + P0/P1

  int cg = 1;
  if (ws_size > fixed) {
    size_t av = (ws_size - fixed) / perCh;
    cg = (av < 1) ? 1 : (av > 16 ? 16 : (int)av);
  }

  float2* spec = (float2*)ws;
  __hip_bfloat16* xs = (__hip_bfloat16*)(ws + specBytes);
  __hip_bfloat16* ms = (__hip_bfloat16*)(ws + specBytes + xsBytes);
  __hip_bfloat16* Bst = (__hip_bfloat16*)(ws + fixed);
  __hip_bfloat16* X0 = Bst + (size_t)cg * SETSTR;
  __hip_bfloat16* X0T = X0 + (size_t)cg * SETSTR;
  __hip_bfloat16* X1 = X0T + (size_t)cg * SETSTR;
  __hip_bfloat16* X1T = X1 + (size_t)cg * SETSTR;
  float2* P0 = (float2*)(X1T + (size_t)cg * SETSTR);
  float2* P1 = P0 + (size_t)cg * MAPSZ;

  spectrum_kernel<<<dim3(32), dim3(576), 0, stream>>>(sig, spec);
  prep_x<<<dim3((8192 * 52 + 255) / 256), dim3(256), 0, stream>>>(x, xs);
  pad_m<<<dim3(512), dim3(256), 0, stream>>>(ms);

  const float scale = 1.f / 64.f;  // s = 6 squarings
  for (int c0 = 0; c0 < 16; c0 += cg) {
    int g = (16 - c0 < cg) ? (16 - c0) : cg;
    buildBX<<<dim3(1296, g), dim3(256), 0, stream>>>(spec, Bst, X0, c0, scale);
    transpose4<<<dim3(9, 9, g), dim3(256), 0, stream>>>(X0, X0T);
    __hip_bfloat16 *xr = X0, *xt = X0T, *yr = X1, *yt = X1T;
    // Horner (Taylor order 3): X <- I + (B*X)/k, k=2..1. Only DT consumed until k=1.
    for (int k = 2; k >= 1; --k) {
      int wf = (k == 1) ? 3 : 2;
      cgemm_mfma<<<dim3(15 * g), dim3(512), 0, stream>>>(Bst, xt, yr, yt,
                                                         1.f / (float)k, 1.f, wf);
      __hip_bfloat16* tmp;
      tmp = xr; xr = yr; yr = tmp;
      tmp = xt; xt = yt; yt = tmp;
    }
    // 6 squarings; last one only needs row-major output (feeds passA)
    for (int t8 = 0; t8 < 6; ++t8) {
      int wf = (t8 == 5) ? 1 : 3;
      cgemm_mfma<<<dim3(15 * g), dim3(512), 0, stream>>>(xr, xt, yr, yt, 1.f, 0.f, wf);
      __hip_bfloat16* tmp;
      tmp = xr; xr = yr; yr = tmp;
      tmp = xt; xt = yt; yt = tmp;
    }
    passA<<<dim3(400, g), dim3(256), 0, stream>>>(xr, P0);
    passB<<<dim3(400, g), dim3(256), 0, stream>>>(P0, P1);
    passC<<<dim3(400, g), dim3(256), 0, stream>>>(P1, P0);
    passD<<<dim3(400, g), dim3(256), 0, stream>>>(P0, ms, c0);
  }

  out_mfma<<<dim3(32, 64), dim3(512), 0, stream>>>(xs, ms, out);
}

// Round 12
// 843.039 us; speedup vs baseline: 7.8566x; 1.0030x over previous
//
#include <hip/hip_runtime.h>
#include <hip/hip_bf16.h>
#include <math.h>

#define TAU 6.283185307179586f
#define NK 576                    // matrix dimension (K always exact: 18*32)
#define NPAD 640                  // padded row count for 128-row tiles
#define PLN ((size_t)NPAD * NK)   // elems per padded plane = 368640
#define SETSTR ((size_t)4 * PLN)  // elems per 4-plane split set
#define MAPSZ 102400              // 16*16*20*20
#define KOUT 416                  // padded K for output gemm (13*32)
#define XPL ((size_t)8192 * KOUT)
#define MPL ((size_t)4096 * KOUT)

typedef __attribute__((ext_vector_type(8))) short short8;
typedef __attribute__((ext_vector_type(4))) short short4v;
typedef __attribute__((ext_vector_type(4))) float f32x4;

__device__ inline void bsplit(float v, __hip_bfloat16& h, __hip_bfloat16& l) {
  h = __float2bfloat16(v);
  l = __float2bfloat16(v - __bfloat162float(h));
}
__device__ inline short braw(__hip_bfloat16 b) { return *reinterpret_cast<short*>(&b); }

__device__ inline void gld16(const void* g, const void* l) {
  __builtin_amdgcn_global_load_lds((const __attribute__((address_space(1))) unsigned*)g,
                                   (__attribute__((address_space(3))) unsigned*)l, 16, 0, 0);
}

#define MFMA16(a, b, c) __builtin_amdgcn_mfma_f32_16x16x32_bf16(a, b, c, 0, 0, 0)

// ---------------- Stage 1: signal -> spectrum ----------------
__device__ inline void dft24(const float2* in, float2* out, int t, float sgn, bool firstAxis) {
  int r = t / 24, c = t % 24;
  int kk = firstAxis ? r : c;
  float2 acc = make_float2(0.f, 0.f);
  for (int n = 0; n < 24; ++n) {
    float ang = sgn * (TAU / 24.f) * (float)((kk * n) % 24);
    float s, co;
    sincosf(ang, &s, &co);
    float2 v = firstAxis ? in[n * 24 + c] : in[r * 24 + n];
    acc.x += v.x * co - v.y * s;
    acc.y += v.x * s + v.y * co;
  }
  out[t] = acc;
}

__global__ void spectrum_kernel(const float* __restrict__ sig, float2* __restrict__ spec) {
  __shared__ float2 b0[576];
  __shared__ float2 b1[576];
  int f = blockIdx.x;
  int t = threadIdx.x;
  int r = t / 24, c = t % 24;
  b0[t] = make_float2(sig[f * 576 + t], 0.f);
  __syncthreads();
  dft24(b0, b1, t, -1.f, false); __syncthreads();
  dft24(b1, b0, t, -1.f, true);  __syncthreads();
  {
    int p2 = (r + 12) % 24 - 11;
    int q2 = (c + 12) % 24 - 11;
    float rr = (float)(1 + p2 * p2 + q2 * q2) * 5.f;
    float2 v = b0[t];
    b0[t] = make_float2(v.x / rr, v.y / rr);
  }
  __syncthreads();
  dft24(b0, b1, t, +1.f, false); __syncthreads();
  dft24(b1, b0, t, +1.f, true);  __syncthreads();
  {
    float winr = 0.5f * (1.f - cosf(TAU * (float)r / 24.f));
    float winc = 0.5f * (1.f - cosf(TAU * (float)c / 24.f));
    float w = winr * winc * (1.f / 576.f);
    float2 v = b0[t];
    b0[t] = make_float2(v.x * w, v.y * w);
  }
  __syncthreads();
  dft24(b0, b1, t, -1.f, false); __syncthreads();
  dft24(b1, b0, t, -1.f, true);  __syncthreads();
  int p = (r + 12) % 24, q = (c + 12) % 24;
  spec[f * 576 + p * 24 + q] = b0[t];
}

// ---------------- Stage 2: build split B and X0 = I + B/3 ----------------
__global__ void buildBX(const float2* __restrict__ spec, __hip_bfloat16* __restrict__ B,
                        __hip_bfloat16* __restrict__ X0, int c0, float scale) {
  int idx = blockIdx.x * 256 + threadIdx.x;   // 0..331775 (row*576+col, row<576)
  int cl = blockIdx.y;
  int c = c0 + cl;
  int row = idx / NK, col = idx % NK;
  int i = row / 24, j = row % 24, a = col / 24, b = col % 24;
  int u = 11 - i + a, v = 11 - j + b;
  float br = 0.f, bi = 0.f;
  if (u >= 0 && u < 24 && v >= 0 && v < 24) {
    float2 s0 = spec[(c * 2 + 0) * 576 + u * 24 + v];
    float2 s1 = spec[(c * 2 + 1) * 576 + u * 24 + v];
    float kx = (float)(a - 11), ky = (float)(b - 11);
    float xr = s0.x * kx + s1.x * ky;
    float xi = s0.y * kx + s1.y * ky;
    br = xi * scale;
    bi = -xr * scale;
  }
  size_t off = (size_t)cl * SETSTR + idx;
  __hip_bfloat16 h, l;
  bsplit(br, h, l); B[off] = h; B[off + PLN] = l;
  bsplit(bi, h, l); B[off + 2 * PLN] = h; B[off + 3 * PLN] = l;
  float d = (row == col) ? 1.f : 0.f;
  bsplit(br * (1.f / 3.f) + d, h, l); X0[off] = h; X0[off + PLN] = l;
  bsplit(bi * (1.f / 3.f), h, l);     X0[off + 2 * PLN] = h; X0[off + 3 * PLN] = l;
}

// ---------------- transpose the 4 split planes ----------------
__global__ __launch_bounds__(256) void transpose4(const __hip_bfloat16* __restrict__ src,
                                                  __hip_bfloat16* __restrict__ dst) {
  __shared__ __hip_bfloat16 tile[64][65];
  int cl = blockIdx.z;
  size_t off = (size_t)cl * SETSTR;
  int rB = blockIdx.y * 64, cB = blockIdx.x * 64;
  int tx = threadIdx.x & 63, ty = threadIdx.x >> 6;
  for (int p = 0; p < 4; ++p) {
    for (int li = 0; li < 16; ++li) {
      int r = ty * 16 + li;
      tile[r][tx] = src[off + (size_t)p * PLN + (size_t)(rB + r) * NK + cB + tx];
    }
    __syncthreads();
    for (int li = 0; li < 16; ++li) {
      int r = ty * 16 + li;
      dst[off + (size_t)p * PLN + (size_t)(cB + r) * NK + rB + tx] = tile[tx][r];
    }
    __syncthreads();
  }
}

// ---------------- Stage 3: batched split-complex MFMA GEMM, 128x96 tile ----------------
// D = alpha*(A*B) + delta*I.  A row-major [m][k] split planes; B given as BT [n][k].
// wf bit0: write D (row-major); bit1: write DT (transposed).
// 256-thread blocks (4 waves, 2x2, wave tile 64x48). 30 tiles/channel -> 480 blocks
// -> 2 independent blocks per CU (cross-block TLP hides barrier/drain stalls).
// LDS 80KB/block: A single-buffered (32KB, re-staged after mid-kstep barrier),
// B double-buffered (2 x 24KB, staged progressively in phases 0-2).
__global__ __launch_bounds__(256, 2) void cgemm_mfma(
    const __hip_bfloat16* __restrict__ A, const __hip_bfloat16* __restrict__ BT,
    __hip_bfloat16* __restrict__ D, __hip_bfloat16* __restrict__ DT,
    float alpha, float delta, int wf) {
  __shared__ char lds[81920];   // A @0 (4*8192), B bufs @32768 (2 x 4*6144)
  const int t = threadIdx.x;
  const int lane = t & 63;
  const int wid = t >> 6;                      // 0..3
  const int wm = wid >> 1, wn = wid & 1;       // 2 x 2 waves, wave tile 64x48
  // block remap: XCD-local channels when full 16-channel group (480 % 8 == 0, bijective)
  int p0 = blockIdx.x;
  int cl, tile;
  if (gridDim.x == 480) {
    int idx = p0 >> 3;
    cl = (p0 & 7) + 8 * (idx / 30);
    tile = idx % 30;
  } else {
    cl = p0 / 30;
    tile = p0 % 30;
  }
  const int rowBase = (tile / 6) * 128, colBase = (tile % 6) * 96;
  const size_t chOff = (size_t)cl * SETSTR;
  const __hip_bfloat16* Ab = A + chOff;
  const __hip_bfloat16* Bb = BT + chOff;

  // staging: A 2048 chunks (8/thread), B 1536 chunks (6/thread)
  size_t gA[8], gB[6];
  int ldsA[8], ldsB[6];
#pragma unroll
  for (int i = 0; i < 8; ++i) {
    int cid = i * 256 + t;                 // 0..2047
    int pp = cid >> 9, r = (cid >> 2) & 127, cp = cid & 3;
    int cg = cp ^ ((r >> 1) & 3);
    gA[i] = (size_t)pp * PLN + (size_t)(rowBase + r) * NK + cg * 8;
    ldsA[i] = cid * 16;
  }
#pragma unroll
  for (int i = 0; i < 6; ++i) {
    int cid = i * 256 + t;                 // 0..1535
    int pp = cid / 384, rem = cid % 384;
    int r = rem >> 2, cp = rem & 3;
    int cg = cp ^ ((r >> 1) & 3);
    gB[i] = (size_t)pp * PLN + (size_t)(colBase + r) * NK + cg * 8;
    ldsB[i] = cid * 16;
  }
  // fragment read offsets
  int aoff[4], boff[3];
#pragma unroll
  for (int mi = 0; mi < 4; ++mi) {
    int ra = wm * 64 + mi * 16 + (lane & 15);
    int ch = (lane >> 4) ^ ((ra >> 1) & 3);
    aoff[mi] = (ra * 4 + ch) * 16;
  }
#pragma unroll
  for (int ni = 0; ni < 3; ++ni) {
    int cb = wn * 48 + ni * 16 + (lane & 15);
    int ch = (lane >> 4) ^ ((cb >> 1) & 3);
    boff[ni] = (cb * 4 + ch) * 16;
  }

  f32x4 accP[4][3] = {}, accN[4][3] = {}, accI[4][3] = {};

  // prologue: tile 0 (A buf + B buf 0)
#pragma unroll
  for (int i = 0; i < 8; ++i) gld16(Ab + gA[i], &lds[ldsA[i]]);
#pragma unroll
  for (int i = 0; i < 6; ++i) gld16(Bb + gB[i], &lds[32768 + ldsB[i]]);

#define STGB(I)                                                              \
  if (ks < 17) {                                                             \
    gld16(Bb + gB[2 * (I)] + k1, &lds[32768 + (cur ^ 1) * 24576 + ldsB[2 * (I)]]); \
    gld16(Bb + gB[2 * (I) + 1] + k1, &lds[32768 + (cur ^ 1) * 24576 + ldsB[2 * (I) + 1]]); \
  }

#define MFS(P, NI)                                                  \
  accP[P][NI] = MFMA16(arh, brh[NI], accP[P][NI]);                  \
  accP[P][NI] = MFMA16(arh, brl[NI], accP[P][NI]);                  \
  accP[P][NI] = MFMA16(arl, brh[NI], accP[P][NI]);                  \
  accN[P][NI] = MFMA16(aih, bih[NI], accN[P][NI]);                  \
  accN[P][NI] = MFMA16(aih, bil[NI], accN[P][NI]);                  \
  accN[P][NI] = MFMA16(ail, bih[NI], accN[P][NI]);                  \
  accI[P][NI] = MFMA16(arh, bih[NI], accI[P][NI]);                  \
  accI[P][NI] = MFMA16(arh, bil[NI], accI[P][NI]);                  \
  accI[P][NI] = MFMA16(arl, bih[NI], accI[P][NI]);                  \
  accI[P][NI] = MFMA16(aih, brh[NI], accI[P][NI]);                  \
  accI[P][NI] = MFMA16(aih, brl[NI], accI[P][NI]);                  \
  accI[P][NI] = MFMA16(ail, brh[NI], accI[P][NI]);

#define PHASE(P) {                                                  \
    short8 arh, arl, aih, ail;                                      \
    {                                                               \
      const char* b_ = &lds[aoff[P]];                               \
      arh = *(const short8*)(b_);                                   \
      arl = *(const short8*)(b_ + 8192);                            \
      aih = *(const short8*)(b_ + 16384);                           \
      ail = *(const short8*)(b_ + 24576);                           \
    }                                                               \
    STGB(P)                                                         \
    __builtin_amdgcn_s_setprio(1);                                  \
    MFS(P, 0) MFS(P, 1) MFS(P, 2)                                   \
    __builtin_amdgcn_s_setprio(0);                                  \
  }

#pragma unroll 1
  for (int ks = 0; ks < 18; ++ks) {
    const int cur = ks & 1;
    const int k1 = (ks + 1) * 32;
    asm volatile("s_waitcnt vmcnt(0)" ::: "memory");   // A+B staging landed
    __builtin_amdgcn_sched_barrier(0);
    __builtin_amdgcn_s_barrier();                      // all waves' staging landed
    __builtin_amdgcn_sched_barrier(0);

    short8 brh[3], brl[3], bih[3], bil[3];
    {
      const char* bb = &lds[32768 + cur * 24576];
#pragma unroll
      for (int ni = 0; ni < 3; ++ni) {
        const char* base = bb + boff[ni];
        brh[ni] = *(const short8*)(base);
        brl[ni] = *(const short8*)(base + 6144);
        bih[ni] = *(const short8*)(base + 12288);
        bil[ni] = *(const short8*)(base + 18432);
      }
    }
    PHASE(0) PHASE(1) PHASE(2)
    // phase 3: read A3, then mid-barrier (all reads of A-buf done), then re-stage A
    {
      short8 arh, arl, aih, ail;
      {
        const char* b_ = &lds[aoff[3]];
        arh = *(const short8*)(b_);
        arl = *(const short8*)(b_ + 8192);
        aih = *(const short8*)(b_ + 16384);
        ail = *(const short8*)(b_ + 24576);
      }
      asm volatile("s_waitcnt lgkmcnt(0)" ::: "memory");
      __builtin_amdgcn_sched_barrier(0);
      __builtin_amdgcn_s_barrier();                    // all waves done reading A-buf
      __builtin_amdgcn_sched_barrier(0);
      if (ks < 17) {
#pragma unroll
        for (int i = 0; i < 8; ++i) gld16(Ab + gA[i] + k1, &lds[ldsA[i]]);
      }
      __builtin_amdgcn_s_setprio(1);
      MFS(3, 0) MFS(3, 1) MFS(3, 2)
      __builtin_amdgcn_s_setprio(0);
    }
    __builtin_amdgcn_sched_barrier(0);
  }
#undef PHASE
#undef MFS
#undef STGB

  __hip_bfloat16* Dp = D + chOff;
  __hip_bfloat16* Tp = DT + chOff;
#pragma unroll
  for (int mi = 0; mi < 4; ++mi)
#pragma unroll
    for (int ni = 0; ni < 3; ++ni) {
      int rb = rowBase + wm * 64 + mi * 16 + (lane >> 4) * 4;
      int cc = colBase + wn * 48 + ni * 16 + (lane & 15);
      if (rb >= NK) continue;   // cols always < 576; rb quad fully valid when rb < 576
      short hR[4], lR[4], hI[4], lI[4];
#pragma unroll
      for (int j = 0; j < 4; ++j) {
        float vR = alpha * (accP[mi][ni][j] - accN[mi][ni][j]) + ((rb + j == cc) ? delta : 0.f);
        float vI = alpha * accI[mi][ni][j];
        __hip_bfloat16 h, l;
        bsplit(vR, h, l); hR[j] = braw(h); lR[j] = braw(l);
        bsplit(vI, h, l); hI[j] = braw(h); lI[j] = braw(l);
      }
      if (wf & 1) {
#pragma unroll
        for (int j = 0; j < 4; ++j) {
          size_t o = (size_t)(rb + j) * NK + cc;
          *(short*)&Dp[o] = hR[j];
          *(short*)&Dp[PLN + o] = lR[j];
          *(short*)&Dp[2 * PLN + o] = hI[j];
          *(short*)&Dp[3 * PLN + o] = lI[j];
        }
      }
      if (wf & 2) {
        size_t o = (size_t)cc * NK + rb;
        short4v vR4 = {hR[0], hR[1], hR[2], hR[3]};
        short4v vL4 = {lR[0], lR[1], lR[2], lR[3]};
        short4v vI4 = {hI[0], hI[1], hI[2], hI[3]};
        short4v vJ4 = {lI[0], lI[1], lI[2], lI[3]};
        *(short4v*)&Tp[o] = vR4;
        *(short4v*)&Tp[PLN + o] = vL4;
        *(short4v*)&Tp[2 * PLN + o] = vI4;
        *(short4v*)&Tp[3 * PLN + o] = vJ4;
      }
    }
}

// ---------------- Stage 4: slice + roll + separable DFTs (LDS twiddle tables) ----------------
__global__ void passA(const __hip_bfloat16* __restrict__ X, float2* __restrict__ P) {
  __shared__ float2 tw[20];
  if (threadIdx.x < 20) {
    float s, c;
    sincosf((TAU / 20.f) * (float)threadIdx.x, &s, &c);
    tw[threadIdx.x] = make_float2(c, s);
  }
  __syncthreads();
  int cl = blockIdx.y;
  int idx = blockIdx.x * 256 + threadIdx.x;
  int v = idx % 20, u = (idx / 20) % 20, q = (idx / 400) % 16, p = idx / 6400;
  int pp = (p + 7) % 16;
  int qq = (q + 7) % 16;
  int row = (pp + 5) * 24 + (qq + 5);
  int uu = (u + 9) % 20;
  int aa = uu + 3;
  const __hip_bfloat16* tb = X + (size_t)cl * SETSTR;
  float2 acc = make_float2(0.f, 0.f);
  for (int vp = 0; vp < 20; ++vp) {
    int vv = (vp + 9) % 20;
    int col = aa * 24 + (vv + 3);
    size_t o = (size_t)row * NK + col;
    float xr = __bfloat162float(tb[o]) + __bfloat162float(tb[PLN + o]);
    float xi = __bfloat162float(tb[2 * PLN + o]) + __bfloat162float(tb[3 * PLN + o]);
    float2 w = tw[(v * vp) % 20];
    acc.x += xr * w.x - xi * w.y;
    acc.y += xr * w.y + xi * w.x;
  }
  P[(size_t)cl * MAPSZ + idx] = acc;
}

__global__ void passB(const float2* __restrict__ Pin, float2* __restrict__ Pout) {
  __shared__ float2 tw[20];
  if (threadIdx.x < 20) {
    float s, c;
    sincosf((TAU / 20.f) * (float)threadIdx.x, &s, &c);
    tw[threadIdx.x] = make_float2(c, s);
  }
  __syncthreads();
  int cl = blockIdx.y;
  int idx = blockIdx.x * 256 + threadIdx.x;
  int v = idx % 20, u = (idx / 20) % 20, q = (idx / 400) % 16, p = idx / 6400;
  const float2* in = Pin + (size_t)cl * MAPSZ;
  float2 acc = make_float2(0.f, 0.f);
  for (int up = 0; up < 20; ++up) {
    float2 val = in[(p * 16 + q) * 400 + up * 20 + v];
    float2 w = tw[(u * up) % 20];
    acc.x += val.x * w.x - val.y * w.y;
    acc.y += val.x * w.y + val.y * w.x;
  }
  Pout[(size_t)cl * MAPSZ + idx] = acc;
}

__global__ void passC(const float2* __restrict__ Pin, float2* __restrict__ Pout) {
  __shared__ float2 tw[16];
  if (threadIdx.x < 16) {
    float s, c;
    sincosf(-(TAU / 16.f) * (float)threadIdx.x, &s, &c);
    tw[threadIdx.x] = make_float2(c, s);
  }
  __syncthreads();
  int cl = blockIdx.y;
  int idx = blockIdx.x * 256 + threadIdx.x;
  int v = idx % 20, u = (idx / 20) % 20, q = (idx / 400) % 16, p = idx / 6400;
  const float2* in = Pin + (size_t)cl * MAPSZ;
  float2 acc = make_float2(0.f, 0.f);
  for (int qp = 0; qp < 16; ++qp) {
    float2 val = in[(p * 16 + qp) * 400 + u * 20 + v];
    float2 w = tw[(q * qp) % 16];
    acc.x += val.x * w.x - val.y * w.y;
    acc.y += val.x * w.y + val.y * w.x;
  }
  Pout[(size_t)cl * MAPSZ + idx] = acc;
}

// passD: final DFT, write split-bf16 m directly into padded [n][KOUT] planes
__global__ void passD(const float2* __restrict__ Pin, __hip_bfloat16* __restrict__ ms, int c0) {
  __shared__ float2 tw[16];
  if (threadIdx.x < 16) {
    float s, c;
    sincosf(-(TAU / 16.f) * (float)threadIdx.x, &s, &c);
    tw[threadIdx.x] = make_float2(c, s);
  }
  __syncthreads();
  int cl = blockIdx.y;
  int c = c0 + cl;
  int idx = blockIdx.x * 256 + threadIdx.x;
  int v = idx % 20, u = (idx / 20) % 20, q = (idx / 400) % 16, p = idx / 6400;
  const float2* in = Pin + (size_t)cl * MAPSZ;
  float acc = 0.f;
  for (int pp = 0; pp < 16; ++pp) {
    float2 val = in[(pp * 16 + q) * 400 + u * 20 + v];
    float2 w = tw[(p * pp) % 16];
    acc += val.x * w.x - val.y * w.y;
  }
  acc *= (1.f / 400.f);
  int n = c * 256 + idx / 400;          // o = p*16+q
  int k = idx % 400;                    // k = u*20+v
  __hip_bfloat16 h, l;
  bsplit(acc, h, l);
  ms[(size_t)n * KOUT + k] = h;
  ms[MPL + (size_t)n * KOUT + k] = l;
}

// zero the k in [400,416) pad of the m planes
__global__ void pad_m(__hip_bfloat16* __restrict__ ms) {
  int idx = blockIdx.x * 256 + threadIdx.x;   // 4096*16*2
  int p = idx >> 16;
  int rem = idx & 65535;
  int n = rem >> 4;
  int k = 400 + (rem & 15);
  ms[(size_t)p * MPL + (size_t)n * KOUT + k] = __float2bfloat16(0.f);
}

// convert x (8192x400 f32) to bf16 padded [8192][KOUT] (hi only)
__global__ void prep_x(const float* __restrict__ x, __hip_bfloat16* __restrict__ xs) {
  int idx = blockIdx.x * 256 + threadIdx.x;   // 8192*52
  if (idx >= 8192 * 52) return;
  int b = idx / 52, c8 = idx % 52;
  int k = c8 * 8;
  short8 hh = {};
  if (k < 400) {
    const float4* xp = (const float4*)(x + (size_t)b * 400 + k);
    float4 v0 = xp[0], v1 = xp[1];
    float vals[8] = {v0.x, v0.y, v0.z, v0.w, v1.x, v1.y, v1.z, v1.w};
#pragma unroll
    for (int i = 0; i < 8; ++i) hh[i] = braw(__float2bfloat16(vals[i]));
  }
  *(short8*)(xs + (size_t)b * KOUT + k) = hh;
}

// ---------------- Stage 5: output GEMM, x bf16 x m split-bf16, 128x128 tile ----------------
// LDS per buf: A 8KB (1 plane) + B 16KB (2 planes) = 24KB; 48KB total -> 3 blocks/CU.
__global__ __launch_bounds__(512, 2) void out_mfma(
    const __hip_bfloat16* __restrict__ xs, const __hip_bfloat16* __restrict__ ms,
    float* __restrict__ Y) {
  __shared__ char lds[2][24576];   // A @0 (8192), B planes @8192 (2*8192)
  const int t = threadIdx.x;
  const int lane = t & 63;
  const int wid = t >> 6;
  const int wm = wid >> 2, wn = wid & 3;
  const int rowBase = blockIdx.y * 128, colBase = blockIdx.x * 128;

  size_t gA1, gB[2];
  int ldsA1, ldsB[2];
  {
    int cid = t;                          // 0..511 A chunks
    int r = (cid >> 2) & 127, cp = cid & 3;
    int cg = cp ^ ((r >> 1) & 3);
    gA1 = (size_t)(rowBase + r) * KOUT + cg * 8;
    ldsA1 = cid * 16;
  }
#pragma unroll
  for (int i = 0; i < 2; ++i) {
    int cid = i * 512 + t;                // 0..1023 B chunks
    int pp = cid >> 9, r = (cid >> 2) & 127, cp = cid & 3;
    int cg = cp ^ ((r >> 1) & 3);
    gB[i] = (size_t)pp * MPL + (size_t)(colBase + r) * KOUT + cg * 8;
    ldsB[i] = 8192 + cid * 16;
  }
  int aoff[4], boff[2];
#pragma unroll
  for (int mi = 0; mi < 4; ++mi) {
    int ra = wm * 64 + mi * 16 + (lane & 15);
    int ch = (lane >> 4) ^ ((ra >> 1) & 3);
    aoff[mi] = (ra * 4 + ch) * 16;
  }
#pragma unroll
  for (int ni = 0; ni < 2; ++ni) {
    int cb = wn * 32 + ni * 16 + (lane & 15);
    int ch = (lane >> 4) ^ ((cb >> 1) & 3);
    boff[ni] = 8192 + (cb * 4 + ch) * 16;
  }

  f32x4 acc[4][2] = {};

  // prologue
  gld16(xs + gA1, &lds[0][ldsA1]);
  gld16(ms + gB[0], &lds[0][ldsB[0]]);
  gld16(ms + gB[1], &lds[0][ldsB[1]]);

#pragma unroll 1
  for (int ks = 0; ks < 13; ++ks) {
    int cur = ks & 1;
    int k1 = (ks + 1) * 32;
    asm volatile("s_waitcnt vmcnt(0)" ::: "memory");
    __builtin_amdgcn_sched_barrier(0);
    __builtin_amdgcn_s_barrier();
    __builtin_amdgcn_sched_barrier(0);
    short8 bh[2], bl[2];
#pragma unroll
    for (int ni = 0; ni < 2; ++ni) {
      const char* base = &lds[cur][boff[ni]];
      bh[ni] = *(const short8*)(base);
      bl[ni] = *(const short8*)(base + 8192);
    }
#pragma unroll
    for (int mi = 0; mi < 4; ++mi) {
      short8 ah;
      {
        const char* base = &lds[cur][aoff[mi]];
        ah = *(const short8*)(base);
      }
      if (ks < 12) {
        if (mi == 0) gld16(xs + gA1 + k1, &lds[cur ^ 1][ldsA1]);
        else if (mi == 1) gld16(ms + gB[0] + k1, &lds[cur ^ 1][ldsB[0]]);
        else if (mi == 2) gld16(ms + gB[1] + k1, &lds[cur ^ 1][ldsB[1]]);
      }
      __builtin_amdgcn_s_setprio(1);
#pragma unroll
      for (int ni = 0; ni < 2; ++ni) {
        acc[mi][ni] = MFMA16(ah, bh[ni], acc[mi][ni]);
        acc[mi][ni] = MFMA16(ah, bl[ni], acc[mi][ni]);
      }
      __builtin_amdgcn_s_setprio(0);
    }
    __builtin_amdgcn_sched_barrier(0);
  }

#pragma unroll
  for (int mi = 0; mi < 4; ++mi)
#pragma unroll
    for (int ni = 0; ni < 2; ++ni) {
      int rb = rowBase + wm * 64 + mi * 16 + (lane >> 4) * 4;
      int cc = colBase + wn * 32 + ni * 16 + (lane & 15);
#pragma unroll
      for (int j = 0; j < 4; ++j)
        Y[(size_t)(rb + j) * 4096 + cc] = acc[mi][ni][j];
    }
}

// ---------------- Launcher ----------------
extern "C" void kernel_launch(void* const* d_in, const int* in_sizes, int n_in,
                              void* d_out, int out_size, void* d_ws, size_t ws_size,
                              hipStream_t stream) {
  const float* x = (const float*)d_in[0];     // (8192,1,20,20)
  const float* sig = (const float*)d_in[1];   // (16,2,24,24)
  float* out = (float*)d_out;                 // (8192,16,16,16)
  char* ws = (char*)d_ws;

  const size_t specBytes = 32ull * 576 * sizeof(float2);
  const size_t xsBytes = XPL * 2;                       // one bf16 plane
  const size_t msBytes = 2ull * MPL * 2;
  const size_t fixed = specBytes + xsBytes + msBytes;
  const size_t setB = SETSTR * 2;                       // bytes per split set
  const size_t perCh = 5 * setB + 2ull * MAPSZ * 8;     // B, X0, X0T, X1, X1T + P0/P1

  int cg = 1;
  if (ws_size > fixed) {
    size_t av = (ws_size - fixed) / perCh;
    cg = (av < 1) ? 1 : (av > 16 ? 16 : (int)av);
  }

  float2* spec = (float2*)ws;
  __hip_bfloat16* xs = (__hip_bfloat16*)(ws + specBytes);
  __hip_bfloat16* ms = (__hip_bfloat16*)(ws + specBytes + xsBytes);
  __hip_bfloat16* Bst = (__hip_bfloat16*)(ws + fixed);
  __hip_bfloat16* X0 = Bst + (size_t)cg * SETSTR;
  __hip_bfloat16* X0T = X0 + (size_t)cg * SETSTR;
  __hip_bfloat16* X1 = X0T + (size_t)cg * SETSTR;
  __hip_bfloat16* X1T = X1 + (size_t)cg * SETSTR;
  float2* P0 = (float2*)(X1T + (size_t)cg * SETSTR);
  float2* P1 = P0 + (size_t)cg * MAPSZ;

  spectrum_kernel<<<dim3(32), dim3(576), 0, stream>>>(sig, spec);
  prep_x<<<dim3((8192 * 52 + 255) / 256), dim3(256), 0, stream>>>(x, xs);
  pad_m<<<dim3(512), dim3(256), 0, stream>>>(ms);

  const float scale = 1.f / 64.f;  // s = 6 squarings
  for (int c0 = 0; c0 < 16; c0 += cg) {
    int g = (16 - c0 < cg) ? (16 - c0) : cg;
    buildBX<<<dim3(1296, g), dim3(256), 0, stream>>>(spec, Bst, X0, c0, scale);
    transpose4<<<dim3(9, 9, g), dim3(256), 0, stream>>>(X0, X0T);
    __hip_bfloat16 *xr = X0, *xt = X0T, *yr = X1, *yt = X1T;
    // Horner (Taylor order 3): X <- I + (B*X)/k, k=2..1. Only DT consumed until k=1.
    for (int k = 2; k >= 1; --k) {
      int wf = (k == 1) ? 3 : 2;
      cgemm_mfma<<<dim3(30 * g), dim3(256), 0, stream>>>(Bst, xt, yr, yt,
                                                         1.f / (float)k, 1.f, wf);
      __hip_bfloat16* tmp;
      tmp = xr; xr = yr; yr = tmp;
      tmp = xt; xt = yt; yt = tmp;
    }
    // 6 squarings; last one only needs row-major output (feeds passA)
    for (int t8 = 0; t8 < 6; ++t8) {
      int wf = (t8 == 5) ? 1 : 3;
      cgemm_mfma<<<dim3(30 * g), dim3(256), 0, stream>>>(xr, xt, yr, yt, 1.f, 0.f, wf);
      __hip_bfloat16* tmp;
      tmp = xr; xr = yr; yr = tmp;
      tmp = xt; xt = yt; yt = tmp;
    }
    passA<<<dim3(400, g), dim3(256), 0, stream>>>(xr, P0);
    passB<<<dim3(400, g), dim3(256), 0, stream>>>(P0, P1);
    passC<<<dim3(400, g), dim3(256), 0, stream>>>(P1, P0);
    passD<<<dim3(400, g), dim3(256), 0, stream>>>(P0, ms, c0);
  }

  out_mfma<<<dim3(32, 64), dim3(512), 0, stream>>>(xs, ms, out);
}